// Round 1
// baseline (2078.895 us; speedup 1.0000x reference)
//
#include <hip/hip_runtime.h>
#include <cstdint>
#include <cstddef>

// Problem constants (match reference)
constexpr int NB = 2048;            // batch
constexpr int NM = 64;              // neighbors M
constexpr int ND = 64;              // dim
constexpr int NBM = NB * NM;        // 131072 (one layer of an index tensor)
constexpr int NROWS = 3 * NB;       // 6144 rows per stack (L+1 = 3)
constexpr int STACK = 3 * NB * ND;  // 393216 floats per stack

__device__ __forceinline__ float wsum(float v) {
#pragma unroll
  for (int o = 32; o > 0; o >>= 1) v += __shfl_xor(v, o, 64);
  return v;
}

__device__ __forceinline__ float wmax(float v) {
#pragma unroll
  for (int o = 32; o > 0; o >>= 1) v = fmaxf(v, __shfl_xor(v, o, 64));
  return v;
}

// artanh(clip(x, -1+1e-5, 1-1e-5))
__device__ __forceinline__ float artanh_clip(float x) {
  x = fminf(fmaxf(x, -1.f + 1e-5f), 1.f - 1e-5f);
  return 0.5f * logf((1.f + x) / (1.f - x));
}

// ---------------- layer-0 init ----------------
__global__ __launch_bounds__(64) void init_mean_kernel(
    const float* __restrict__ E, const int* __restrict__ idx, float* __restrict__ out) {
  int b = blockIdx.x, lane = threadIdx.x;
  float s = 0.f;
  for (int m = 0; m < NM; ++m) s += E[(size_t)idx[b * NM + m] * ND + lane];
  out[(size_t)b * ND + lane] = s * (1.f / 64.f);
}

__global__ __launch_bounds__(64) void init_item_kernel(
    const float* __restrict__ E, const int* __restrict__ idx, float* __restrict__ out) {
  int b = blockIdx.x, lane = threadIdx.x;
  out[(size_t)b * ND + lane] = E[(size_t)idx[b] * ND + lane];
}

// ---------------- Euclidean attention agg (ucf / ikg) ----------------
// block = one batch row b; 4 waves; wave handles m = wave, wave+4, ...
__global__ __launch_bounds__(256) void ed_agg_kernel(
    const float* __restrict__ E, const float* __restrict__ R,
    const int* __restrict__ h_idx, const int* __restrict__ r_idx,
    const int* __restrict__ t_idx, int layer,
    const float* __restrict__ w1, const float* __restrict__ w2,
    float* __restrict__ out) {
  __shared__ float xt[64][132];   // [m][concat(h,path)] pad->132 (16B aligned rows)
  __shared__ float red[64][17];
  __shared__ float a_s[64];
  __shared__ float w_s[64];
  __shared__ float part[4][64];

  const int b = blockIdx.x;
  const int tid = threadIdx.x;
  const int wave = tid >> 6, lane = tid & 63;

  // phase A: gather x = [h, path] rows
  for (int m = wave; m < NM; m += 4) {
    float hd = E[(size_t)h_idx[b * NM + m] * ND + lane];
    float pd = R[(size_t)r_idx[b * NM + m] * ND + lane];
    if (layer) {
      hd += E[(size_t)h_idx[NBM + b * NM + m] * ND + lane];
      pd *= R[(size_t)r_idx[NBM + b * NM + m] * ND + lane];
    }
    xt[m][lane] = hd;
    xt[m][64 + lane] = pd;
  }
  __syncthreads();

  // phase B: a[m] = sigmoid( relu(x @ w1) @ w2 ), 4x4 micro-tiles
  const int tx = tid & 15, ty = tid >> 4;
  float acc[4][4] = {};
  for (int kc = 0; kc < 32; ++kc) {
    float4 wv[4];
#pragma unroll
    for (int kk = 0; kk < 4; ++kk)
      wv[kk] = *(const float4*)&w1[(kc * 4 + kk) * ND + tx * 4];
#pragma unroll
    for (int i = 0; i < 4; ++i) {
      float4 xv = *(const float4*)&xt[ty * 4 + i][kc * 4];
      acc[i][0] = fmaf(xv.x, wv[0].x, fmaf(xv.y, wv[1].x, fmaf(xv.z, wv[2].x, fmaf(xv.w, wv[3].x, acc[i][0]))));
      acc[i][1] = fmaf(xv.x, wv[0].y, fmaf(xv.y, wv[1].y, fmaf(xv.z, wv[2].y, fmaf(xv.w, wv[3].y, acc[i][1]))));
      acc[i][2] = fmaf(xv.x, wv[0].z, fmaf(xv.y, wv[1].z, fmaf(xv.z, wv[2].z, fmaf(xv.w, wv[3].z, acc[i][2]))));
      acc[i][3] = fmaf(xv.x, wv[0].w, fmaf(xv.y, wv[1].w, fmaf(xv.z, wv[2].w, fmaf(xv.w, wv[3].w, acc[i][3]))));
    }
  }
  {
    float4 w2v = *(const float4*)&w2[tx * 4];
#pragma unroll
    for (int i = 0; i < 4; ++i) {
      float s = fmaxf(acc[i][0], 0.f) * w2v.x + fmaxf(acc[i][1], 0.f) * w2v.y +
                fmaxf(acc[i][2], 0.f) * w2v.z + fmaxf(acc[i][3], 0.f) * w2v.w;
      red[ty * 4 + i][tx] = s;
    }
  }
  __syncthreads();
  if (tid < 64) {
    float s = 0.f;
#pragma unroll
    for (int j = 0; j < 16; ++j) s += red[tid][j];
    a_s[tid] = 1.f / (1.f + __expf(-s));
  }
  __syncthreads();
  // softmax over m (wave 0)
  if (wave == 0) {
    float v = a_s[lane];
    float mx = wmax(v);
    float e = __expf(v - mx);
    float ssum = wsum(e);
    w_s[lane] = e / ssum;
  }
  __syncthreads();
  // phase C: out = sum_m w[m] * E[t_idx[layer][b][m]]
  float o = 0.f;
  for (int m = wave; m < NM; m += 4)
    o = fmaf(w_s[m], E[(size_t)t_idx[(size_t)layer * NBM + b * NM + m] * ND + lane], o);
  part[wave][lane] = o;
  __syncthreads();
  if (wave == 0)
    out[(size_t)b * ND + lane] = part[0][lane] + part[1][lane] + part[2][lane] + part[3][lane];
}

// ---------------- Hyperbolic attention agg (ukg / icf) ----------------
__global__ __launch_bounds__(256) void hyper_agg_kernel(
    const float* __restrict__ E, const float* __restrict__ R,
    const int* __restrict__ h_idx, const int* __restrict__ r_idx,
    const int* __restrict__ t_idx, int layer,
    const float* __restrict__ w1, const float* __restrict__ b1,
    const float* __restrict__ w2, const float* __restrict__ b2,
    const float* __restrict__ curv, float* __restrict__ out) {
  __shared__ float xt[64][132];    // tang rows (128 used)
  __shared__ float ht_s[64][64];
  __shared__ float hh_s[64][64];
  __shared__ float red[64][17];
  __shared__ float a_s[64];
  __shared__ float w_s[64];
  __shared__ float part[4][64];
  __shared__ float meanpt[64];
  __shared__ float scal;

  const int b = blockIdx.x;
  const int tid = threadIdx.x;
  const int wave = tid >> 6, lane = tid & 63;
  const float cabs = fabsf(*curv);

  // phase A: per-m hyperbolic geometry
  for (int m = wave; m < NM; m += 4) {
    float hd = E[(size_t)h_idx[b * NM + m] * ND + lane];
    float pd = R[(size_t)r_idx[b * NM + m] * ND + lane];
    if (layer) {
      hd += E[(size_t)h_idx[NBM + b * NM + m] * ND + lane];
      pd *= R[(size_t)r_idx[NBM + b * NM + m] * ND + lane];
    }
    float td = E[(size_t)t_idx[(size_t)layer * NBM + b * NM + m] * ND + lane];
    // l2 normalize (x / max(||x||, 1e-12))
    float s;
    s = wsum(hd * hd); hd *= 1.f / fmaxf(sqrtf(s), 1e-12f);
    s = wsum(pd * pd); pd *= 1.f / fmaxf(sqrtf(s), 1e-12f);
    s = wsum(td * td); td *= 1.f / fmaxf(sqrtf(s), 1e-12f);
    // hh = expmap0(h) * |c|
    float nh = sqrtf(fmaxf(wsum(hd * hd), 1e-15f));
    float hhd = tanhf(nh) / nh * hd * cabs;
    float p2 = wsum(hhd * hhd);
    float lam = 2.f / fmaxf(1.f - p2, 1e-15f);
    // ht = expmap(t, hh) = mobius_add(hh, tanh(lam*|t|/2) * t/|t|)
    float nt = sqrtf(fmaxf(wsum(td * td), 1e-15f));
    float yd = tanhf(0.5f * lam * nt) / nt * td;
    float y2 = wsum(yd * yd);
    float xy = wsum(hhd * yd);
    float htd = ((1.f + 2.f * xy + y2) * hhd + (1.f - p2) * yd) /
                fmaxf(1.f + 2.f * xy + p2 * y2, 1e-15f);
    // hr = expmap(path, hh)
    float npn = sqrtf(fmaxf(wsum(pd * pd), 1e-15f));
    float zd = tanhf(0.5f * lam * npn) / npn * pd;
    float z2 = wsum(zd * zd);
    float xz = wsum(hhd * zd);
    float hrd = ((1.f + 2.f * xz + z2) * hhd + (1.f - p2) * zd) /
                fmaxf(1.f + 2.f * xz + p2 * z2, 1e-15f);
    // tang = logmap0(concat(hh, hr))  (norm over 128 dims!)
    float n128 = sqrtf(fmaxf(wsum(hhd * hhd + hrd * hrd), 1e-15f));
    float f = artanh_clip(n128) / n128;
    xt[m][lane] = f * hhd;
    xt[m][64 + lane] = f * hrd;
    ht_s[m][lane] = htd;
    hh_s[m][lane] = hhd;
  }
  __syncthreads();

  // phase B: a[m] = tanh( relu(tang @ w1 + b1) @ w2 + b2 )
  const int tx = tid & 15, ty = tid >> 4;
  float acc[4][4];
  {
    float4 b1v = *(const float4*)&b1[tx * 4];
#pragma unroll
    for (int i = 0; i < 4; ++i) {
      acc[i][0] = b1v.x; acc[i][1] = b1v.y; acc[i][2] = b1v.z; acc[i][3] = b1v.w;
    }
  }
  for (int kc = 0; kc < 32; ++kc) {
    float4 wv[4];
#pragma unroll
    for (int kk = 0; kk < 4; ++kk)
      wv[kk] = *(const float4*)&w1[(kc * 4 + kk) * ND + tx * 4];
#pragma unroll
    for (int i = 0; i < 4; ++i) {
      float4 xv = *(const float4*)&xt[ty * 4 + i][kc * 4];
      acc[i][0] = fmaf(xv.x, wv[0].x, fmaf(xv.y, wv[1].x, fmaf(xv.z, wv[2].x, fmaf(xv.w, wv[3].x, acc[i][0]))));
      acc[i][1] = fmaf(xv.x, wv[0].y, fmaf(xv.y, wv[1].y, fmaf(xv.z, wv[2].y, fmaf(xv.w, wv[3].y, acc[i][1]))));
      acc[i][2] = fmaf(xv.x, wv[0].z, fmaf(xv.y, wv[1].z, fmaf(xv.z, wv[2].z, fmaf(xv.w, wv[3].z, acc[i][2]))));
      acc[i][3] = fmaf(xv.x, wv[0].w, fmaf(xv.y, wv[1].w, fmaf(xv.z, wv[2].w, fmaf(xv.w, wv[3].w, acc[i][3]))));
    }
  }
  {
    float4 w2v = *(const float4*)&w2[tx * 4];
#pragma unroll
    for (int i = 0; i < 4; ++i) {
      float s = fmaxf(acc[i][0], 0.f) * w2v.x + fmaxf(acc[i][1], 0.f) * w2v.y +
                fmaxf(acc[i][2], 0.f) * w2v.z + fmaxf(acc[i][3], 0.f) * w2v.w;
      red[ty * 4 + i][tx] = s;
    }
  }
  __syncthreads();
  if (tid < 64) {
    float s = 0.f;
#pragma unroll
    for (int j = 0; j < 16; ++j) s += red[tid][j];
    a_s[tid] = tanhf(s + b2[0]);
  }
  __syncthreads();
  if (wave == 0) {
    float v = a_s[lane];
    float mx = wmax(v);
    float e = __expf(v - mx);
    float ssum = wsum(e);
    w_s[lane] = e / ssum;
  }
  __syncthreads();
  // mean_pt = sum_m w[m] * hh[m]
  float mp = 0.f;
  for (int m = wave; m < NM; m += 4) mp = fmaf(w_s[m], hh_s[m][lane], mp);
  part[wave][lane] = mp;
  __syncthreads();
  if (wave == 0) {
    float v = part[0][lane] + part[1][lane] + part[2][lane] + part[3][lane];
    meanpt[lane] = v;
    float p2m = wsum(v * v);
    if (lane == 0) scal = p2m;
  }
  __syncthreads();
  const float p2m = scal;
  const float pd_ = meanpt[lane];
  const float two_over_lam = fmaxf(1.f - p2m, 1e-15f);  // (2/lam_p)
  // phase C: out = sum_m w[m] * logmap(w[m]*ht[m], mean_pt)
  float oacc = 0.f;
  for (int m = wave; m < NM; m += 4) {
    float wm = w_s[m];
    float xd = wm * ht_s[m][lane];
    float y2 = wsum(xd * xd);
    float xy = wsum(-pd_ * xd);
    float num = (1.f + 2.f * xy + y2) * (-pd_) + (1.f - p2m) * xd;
    float den = fmaxf(1.f + 2.f * xy + p2m * y2, 1e-15f);
    float md = num / den;
    float n = sqrtf(fmaxf(wsum(md * md), 1e-15f));
    float e = two_over_lam * artanh_clip(n) / n * md;
    oacc = fmaf(wm, e, oacc);
  }
  part[wave][lane] = oacc;
  __syncthreads();
  if (wave == 0)
    out[(size_t)b * ND + lane] = part[0][lane] + part[1][lane] + part[2][lane] + part[3][lane];
}

// ---------------- l2 normalize all 4 stacks ----------------
__global__ __launch_bounds__(256) void l2norm_kernel(
    const float* __restrict__ in, float* __restrict__ out) {
  int row = blockIdx.x * 4 + (threadIdx.x >> 6);
  int lane = threadIdx.x & 63;
  size_t off = (size_t)blockIdx.y * STACK + (size_t)row * ND + lane;
  float v = in[off];
  float s = wsum(v * v);
  out[off] = v / fmaxf(sqrtf(s), 1e-12f);
}

// ---------------- positive-pair dots ----------------
__global__ __launch_bounds__(256) void pos_kernel(
    const float* __restrict__ nstacks, float* __restrict__ pos) {
  int row = blockIdx.x * 4 + (threadIdx.x >> 6);
  int lane = threadIdx.x & 63;
  int sa = blockIdx.y;            // pair0: (0,2)=(ucf,ukg); pair1: (1,3)=(ikg,icf)
  int sb = sa + 2;
  float a = nstacks[(size_t)sa * STACK + (size_t)row * ND + lane];
  float c = nstacks[(size_t)sb * STACK + (size_t)row * ND + lane];
  float d = wsum(a * c);
  if (lane == 0) pos[blockIdx.y * NROWS + row] = d;
}

// ---------------- contrastive denominators: S[i] = sum_j exp(X_i . Y_j / T) ----------------
__global__ __launch_bounds__(256) void lse_kernel(
    const float* __restrict__ nstacks, float* __restrict__ S) {
  __shared__ float xs[64][65];
  __shared__ float ys[64][65];
  __shared__ float red[64][17];
  const int tid = threadIdx.x;
  const int pair = blockIdx.y;  // 0: ucf->ukg, 1: ukg->ucf, 2: ikg->icf, 3: icf->ikg
  int xi = (pair & 2) ? ((pair & 1) ? 3 : 1) : ((pair & 1) ? 2 : 0);
  int yi = xi ^ 2;
  const float* X = nstacks + (size_t)xi * STACK;
  const float* Y = nstacks + (size_t)yi * STACK;
  const int r0 = blockIdx.x * 64;

  for (int i = tid; i < 4096; i += 256) xs[i >> 6][i & 63] = X[(size_t)r0 * 64 + i];
  __syncthreads();

  const int tx = tid & 15, ty = tid >> 4;
  float racc[4] = {0.f, 0.f, 0.f, 0.f};
  for (int jt = 0; jt < 96; ++jt) {
    __syncthreads();
    for (int i = tid; i < 4096; i += 256) ys[i >> 6][i & 63] = Y[(size_t)jt * 4096 + i];
    __syncthreads();
    float dot[4][4] = {};
    for (int k = 0; k < 64; ++k) {
      float xv[4], yv[4];
#pragma unroll
      for (int i = 0; i < 4; ++i) xv[i] = xs[ty * 4 + i][k];
#pragma unroll
      for (int j = 0; j < 4; ++j) yv[j] = ys[tx * 4 + j][k];
#pragma unroll
      for (int i = 0; i < 4; ++i)
#pragma unroll
        for (int j = 0; j < 4; ++j) dot[i][j] = fmaf(xv[i], yv[j], dot[i][j]);
    }
#pragma unroll
    for (int i = 0; i < 4; ++i)
      racc[i] += __expf(dot[i][0] * 5.f) + __expf(dot[i][1] * 5.f) +
                 __expf(dot[i][2] * 5.f) + __expf(dot[i][3] * 5.f);
  }
#pragma unroll
  for (int i = 0; i < 4; ++i) red[ty * 4 + i][tx] = racc[i];
  __syncthreads();
  if (tid < 64) {
    float s = 0.f;
#pragma unroll
    for (int j = 0; j < 16; ++j) s += red[tid][j];
    S[(size_t)pair * NROWS + r0 + tid] = s;
  }
}

// ---------------- scores ----------------
__global__ __launch_bounds__(256) void scores_kernel(
    const float* __restrict__ stacks, float* __restrict__ out) {
  int b = blockIdx.x * 4 + (threadIdx.x >> 6);
  int lane = threadIdx.x & 63;
  float s = 0.f;
#pragma unroll
  for (int l = 0; l < 3; ++l) {
    size_t o = (size_t)l * NB * ND + (size_t)b * ND + lane;
    s += stacks[0 * (size_t)STACK + o] * stacks[3 * (size_t)STACK + o]   // ucf . icf
       + stacks[2 * (size_t)STACK + o] * stacks[1 * (size_t)STACK + o];  // ukg . ikg
  }
  s = wsum(s);
  if (lane == 0) out[b] = 1.f / (1.f + __expf(-s));
}

// ---------------- final loss ----------------
__global__ __launch_bounds__(256) void loss_kernel(
    const float* __restrict__ S, const float* __restrict__ pos, float* __restrict__ out) {
  __shared__ double red[256];
  double acc = 0.0;
  for (int i = threadIdx.x; i < 4 * NROWS; i += 256) acc += (double)logf(S[i]);
  for (int i = threadIdx.x; i < 2 * NROWS; i += 256) acc -= 10.0 * (double)pos[i];
  red[threadIdx.x] = acc;
  __syncthreads();
  for (int s = 128; s > 0; s >>= 1) {
    if (threadIdx.x < s) red[threadIdx.x] += red[threadIdx.x + s];
    __syncthreads();
  }
  if (threadIdx.x == 0) out[NB] = (float)(1e-6 * red[0]);
}

extern "C" void kernel_launch(void* const* d_in, const int* in_sizes, int n_in,
                              void* d_out, int out_size, void* d_ws, size_t ws_size,
                              hipStream_t stream) {
  const int* items = (const int*)d_in[0];
  const int* ucf_h = (const int*)d_in[1];
  const int* ucf_r = (const int*)d_in[2];
  const int* ucf_t = (const int*)d_in[3];
  const int* ikg_h = (const int*)d_in[4];
  const int* ikg_r = (const int*)d_in[5];
  const int* ikg_t = (const int*)d_in[6];
  const int* ukg_h = (const int*)d_in[7];
  const int* ukg_r = (const int*)d_in[8];
  const int* ukg_t = (const int*)d_in[9];
  const int* icf_h = (const int*)d_in[10];
  const int* icf_r = (const int*)d_in[11];
  const int* icf_t = (const int*)d_in[12];
  const float* E = (const float*)d_in[13];
  const float* R = (const float*)d_in[14];
  const float* att_w1 = (const float*)d_in[15];
  const float* att_w2 = (const float*)d_in[16];
  const float* a2_w1 = (const float*)d_in[17];
  const float* a2_b1 = (const float*)d_in[18];
  const float* a2_w2 = (const float*)d_in[19];
  const float* a2_b2 = (const float*)d_in[20];
  const float* curv = (const float*)d_in[21];
  float* outp = (float*)d_out;

  float* ws = (float*)d_ws;
  float* stacks = ws;                              // 4 * STACK   (ucf, ikg, ukg, icf)
  float* nstacks = stacks + 4 * (size_t)STACK;     // 4 * STACK   (l2-normalized)
  float* Sarr = nstacks + 4 * (size_t)STACK;       // 4 * NROWS
  float* posarr = Sarr + 4 * (size_t)NROWS;        // 2 * NROWS

  float* ucf = stacks + 0 * (size_t)STACK;
  float* ikg = stacks + 1 * (size_t)STACK;
  float* ukg = stacks + 2 * (size_t)STACK;
  float* icf = stacks + 3 * (size_t)STACK;

  const size_t L = (size_t)NB * ND;

  // layer-0 (init) embeddings
  init_mean_kernel<<<NB, 64, 0, stream>>>(E, ucf_h, ucf);
  init_item_kernel<<<NB, 64, 0, stream>>>(E, items, ikg);
  init_mean_kernel<<<NB, 64, 0, stream>>>(E, ukg_h, ukg);
  init_mean_kernel<<<NB, 64, 0, stream>>>(E, icf_h, icf);

  // Euclidean builds
  ed_agg_kernel<<<NB, 256, 0, stream>>>(E, R, ucf_h, ucf_r, ucf_t, 0, att_w1, att_w2, ucf + 1 * L);
  ed_agg_kernel<<<NB, 256, 0, stream>>>(E, R, ucf_h, ucf_r, ucf_t, 1, att_w1, att_w2, ucf + 2 * L);
  ed_agg_kernel<<<NB, 256, 0, stream>>>(E, R, ikg_h, ikg_r, ikg_t, 0, att_w1, att_w2, ikg + 1 * L);
  ed_agg_kernel<<<NB, 256, 0, stream>>>(E, R, ikg_h, ikg_r, ikg_t, 1, att_w1, att_w2, ikg + 2 * L);
  // Hyperbolic builds
  hyper_agg_kernel<<<NB, 256, 0, stream>>>(E, R, ukg_h, ukg_r, ukg_t, 0, a2_w1, a2_b1, a2_w2, a2_b2, curv, ukg + 1 * L);
  hyper_agg_kernel<<<NB, 256, 0, stream>>>(E, R, ukg_h, ukg_r, ukg_t, 1, a2_w1, a2_b1, a2_w2, a2_b2, curv, ukg + 2 * L);
  hyper_agg_kernel<<<NB, 256, 0, stream>>>(E, R, icf_h, icf_r, icf_t, 0, a2_w1, a2_b1, a2_w2, a2_b2, curv, icf + 1 * L);
  hyper_agg_kernel<<<NB, 256, 0, stream>>>(E, R, icf_h, icf_r, icf_t, 1, a2_w1, a2_b1, a2_w2, a2_b2, curv, icf + 2 * L);

  // contrastive loss pipeline
  l2norm_kernel<<<dim3(NROWS / 4, 4), 256, 0, stream>>>(stacks, nstacks);
  pos_kernel<<<dim3(NROWS / 4, 2), 256, 0, stream>>>(nstacks, posarr);
  lse_kernel<<<dim3(96, 4), 256, 0, stream>>>(nstacks, Sarr);

  // outputs
  scores_kernel<<<NB / 4, 256, 0, stream>>>(stacks, outp);
  loss_kernel<<<1, 256, 0, stream>>>(Sarr, posarr, outp);
}

// Round 2
// 1519.168 us; speedup vs baseline: 1.3684x; 1.3684x over previous
//
#include <hip/hip_runtime.h>
#include <hip/hip_bf16.h>
#include <cstdint>
#include <cstddef>

// Problem constants (match reference)
constexpr int NB = 2048;            // batch
constexpr int NM = 64;              // neighbors M
constexpr int ND = 64;              // dim
constexpr int NBM = NB * NM;        // 131072 (one layer of an index tensor)
constexpr int NROWS = 3 * NB;       // 6144 rows per stack (L+1 = 3)
constexpr int STACK = 3 * NB * ND;  // 393216 floats per stack

typedef __attribute__((ext_vector_type(8))) short short8;
typedef __attribute__((ext_vector_type(4))) float float4v;

__device__ __forceinline__ float wsum(float v) {
#pragma unroll
  for (int o = 32; o > 0; o >>= 1) v += __shfl_xor(v, o, 64);
  return v;
}

__device__ __forceinline__ float wmax(float v) {
#pragma unroll
  for (int o = 32; o > 0; o >>= 1) v = fmaxf(v, __shfl_xor(v, o, 64));
  return v;
}

// tanh via exp2-based __expf (tanh(x) = (e^2x - 1)/(e^2x + 1)); |x| small in this model
__device__ __forceinline__ float fast_tanh(float x) {
  float t = __expf(2.f * x);
  return (t - 1.f) / (t + 1.f);
}

// artanh(clip(x, -1+1e-5, 1-1e-5))
__device__ __forceinline__ float artanh_clip(float x) {
  x = fminf(fmaxf(x, -1.f + 1e-5f), 1.f - 1e-5f);
  return 0.5f * __logf((1.f + x) / (1.f - x));
}

// ---------------- layer-0 init ----------------
__global__ __launch_bounds__(64) void init_mean_kernel(
    const float* __restrict__ E, const int* __restrict__ idx, float* __restrict__ out) {
  int b = blockIdx.x, lane = threadIdx.x;
  float s = 0.f;
  for (int m = 0; m < NM; ++m) s += E[(size_t)idx[b * NM + m] * ND + lane];
  out[(size_t)b * ND + lane] = s * (1.f / 64.f);
}

__global__ __launch_bounds__(64) void init_item_kernel(
    const float* __restrict__ E, const int* __restrict__ idx, float* __restrict__ out) {
  int b = blockIdx.x, lane = threadIdx.x;
  out[(size_t)b * ND + lane] = E[(size_t)idx[b] * ND + lane];
}

// ---------------- Euclidean attention agg (ucf / ikg) ----------------
__global__ __launch_bounds__(256) void ed_agg_kernel(
    const float* __restrict__ E, const float* __restrict__ R,
    const int* __restrict__ h_idx, const int* __restrict__ r_idx,
    const int* __restrict__ t_idx, int layer,
    const float* __restrict__ w1, const float* __restrict__ w2,
    float* __restrict__ out) {
  __shared__ float xt[64][132];   // [m][concat(h,path)] pad->132
  __shared__ float red[64][17];
  __shared__ float a_s[64];
  __shared__ float w_s[64];
  __shared__ float part[4][64];

  const int b = blockIdx.x;
  const int tid = threadIdx.x;
  const int wave = tid >> 6, lane = tid & 63;

  for (int m = wave; m < NM; m += 4) {
    float hd = E[(size_t)h_idx[b * NM + m] * ND + lane];
    float pd = R[(size_t)r_idx[b * NM + m] * ND + lane];
    if (layer) {
      hd += E[(size_t)h_idx[NBM + b * NM + m] * ND + lane];
      pd *= R[(size_t)r_idx[NBM + b * NM + m] * ND + lane];
    }
    xt[m][lane] = hd;
    xt[m][64 + lane] = pd;
  }
  __syncthreads();

  const int tx = tid & 15, ty = tid >> 4;
  float acc[4][4] = {};
  for (int kc = 0; kc < 32; ++kc) {
    float4 wv[4];
#pragma unroll
    for (int kk = 0; kk < 4; ++kk)
      wv[kk] = *(const float4*)&w1[(kc * 4 + kk) * ND + tx * 4];
#pragma unroll
    for (int i = 0; i < 4; ++i) {
      float4 xv = *(const float4*)&xt[ty * 4 + i][kc * 4];
      acc[i][0] = fmaf(xv.x, wv[0].x, fmaf(xv.y, wv[1].x, fmaf(xv.z, wv[2].x, fmaf(xv.w, wv[3].x, acc[i][0]))));
      acc[i][1] = fmaf(xv.x, wv[0].y, fmaf(xv.y, wv[1].y, fmaf(xv.z, wv[2].y, fmaf(xv.w, wv[3].y, acc[i][1]))));
      acc[i][2] = fmaf(xv.x, wv[0].z, fmaf(xv.y, wv[1].z, fmaf(xv.z, wv[2].z, fmaf(xv.w, wv[3].z, acc[i][2]))));
      acc[i][3] = fmaf(xv.x, wv[0].w, fmaf(xv.y, wv[1].w, fmaf(xv.z, wv[2].w, fmaf(xv.w, wv[3].w, acc[i][3]))));
    }
  }
  {
    float4 w2v = *(const float4*)&w2[tx * 4];
#pragma unroll
    for (int i = 0; i < 4; ++i) {
      float s = fmaxf(acc[i][0], 0.f) * w2v.x + fmaxf(acc[i][1], 0.f) * w2v.y +
                fmaxf(acc[i][2], 0.f) * w2v.z + fmaxf(acc[i][3], 0.f) * w2v.w;
      red[ty * 4 + i][tx] = s;
    }
  }
  __syncthreads();
  if (tid < 64) {
    float s = 0.f;
#pragma unroll
    for (int j = 0; j < 16; ++j) s += red[tid][j];
    a_s[tid] = 1.f / (1.f + __expf(-s));
  }
  __syncthreads();
  if (wave == 0) {
    float v = a_s[lane];
    float mx = wmax(v);
    float e = __expf(v - mx);
    float ssum = wsum(e);
    w_s[lane] = e / ssum;
  }
  __syncthreads();
  float o = 0.f;
  for (int m = wave; m < NM; m += 4)
    o = fmaf(w_s[m], E[(size_t)t_idx[(size_t)layer * NBM + b * NM + m] * ND + lane], o);
  part[wave][lane] = o;
  __syncthreads();
  if (wave == 0)
    out[(size_t)b * ND + lane] = part[0][lane] + part[1][lane] + part[2][lane] + part[3][lane];
}

// ---------------- Hyperbolic attention agg (ukg / icf) ----------------
// LDS ~40KB -> 4 blocks/CU. ht in registers; hh recovered from xt via finv.
__global__ __launch_bounds__(256) void hyper_agg_kernel(
    const float* __restrict__ E, const float* __restrict__ R,
    const int* __restrict__ h_idx, const int* __restrict__ r_idx,
    const int* __restrict__ t_idx, int layer,
    const float* __restrict__ w1, const float* __restrict__ b1,
    const float* __restrict__ w2, const float* __restrict__ b2,
    const float* __restrict__ curv, float* __restrict__ out) {
  __shared__ float xt[64][132];    // tang rows (128 used)
  __shared__ float red[64][17];
  __shared__ float a_s[64];
  __shared__ float w_s[64];
  __shared__ float finv_s[64];
  __shared__ float meanpt[64];
  __shared__ float part[4][64];
  __shared__ float scal;

  const int b = blockIdx.x;
  const int tid = threadIdx.x;
  const int wave = tid >> 6, lane = tid & 63;
  const float cabs = fabsf(*curv);

  float ht_r[16];

#pragma unroll
  for (int mi = 0; mi < 16; ++mi) {
    const int m = wave + mi * 4;
    float hd = E[(size_t)h_idx[b * NM + m] * ND + lane];
    float pd = R[(size_t)r_idx[b * NM + m] * ND + lane];
    if (layer) {
      hd += E[(size_t)h_idx[NBM + b * NM + m] * ND + lane];
      pd *= R[(size_t)r_idx[NBM + b * NM + m] * ND + lane];
    }
    float td = E[(size_t)t_idx[(size_t)layer * NBM + b * NM + m] * ND + lane];
    // l2 normalize; post-norm norms are scalar-recoverable (no extra wsum)
    float sh = wsum(hd * hd), sp = wsum(pd * pd), st = wsum(td * td);
    float rih = 1.f / fmaxf(sqrtf(sh), 1e-12f);
    float rip = 1.f / fmaxf(sqrtf(sp), 1e-12f);
    float rit = 1.f / fmaxf(sqrtf(st), 1e-12f);
    hd *= rih; pd *= rip; td *= rit;
    float nh2 = fmaxf(sh * rih * rih, 1e-15f);
    float nt2 = fmaxf(st * rit * rit, 1e-15f);
    float np2 = fmaxf(sp * rip * rip, 1e-15f);
    float nh = sqrtf(nh2), nt = sqrtf(nt2), npn = sqrtf(np2);
    // hh = expmap0(h)*|c| = kh*h
    float kh = fast_tanh(nh) / nh * cabs;
    float hhd = kh * hd;
    float p2 = kh * kh * nh2;
    float lam = 2.f / fmaxf(1.f - p2, 1e-15f);
    // ht = mobius_add(hh, gt*t)
    float gt = fast_tanh(0.5f * lam * nt) / nt;
    float yd = gt * td;
    float y2 = gt * gt * nt2;
    float xy = wsum(hhd * yd);
    float htd = ((1.f + 2.f * xy + y2) * hhd + (1.f - p2) * yd) /
                fmaxf(1.f + 2.f * xy + p2 * y2, 1e-15f);
    // hr = mobius_add(hh, gp*path)
    float gp = fast_tanh(0.5f * lam * npn) / npn;
    float zd = gp * pd;
    float z2 = gp * gp * np2;
    float xz = wsum(hhd * zd);
    float hrd = ((1.f + 2.f * xz + z2) * hhd + (1.f - p2) * zd) /
                fmaxf(1.f + 2.f * xz + p2 * z2, 1e-15f);
    // tang = logmap0(concat(hh,hr)); ||concat||^2 = p2 + ||hr||^2
    float sr = wsum(hrd * hrd);
    float n128 = sqrtf(fmaxf(p2 + sr, 1e-15f));
    float f = artanh_clip(n128) / n128;
    xt[m][lane] = f * hhd;
    xt[m][64 + lane] = f * hrd;
    if (lane == 0) finv_s[m] = 1.f / f;
    ht_r[mi] = htd;
  }
  __syncthreads();

  const int tx = tid & 15, ty = tid >> 4;
  float acc[4][4];
  {
    float4 b1v = *(const float4*)&b1[tx * 4];
#pragma unroll
    for (int i = 0; i < 4; ++i) {
      acc[i][0] = b1v.x; acc[i][1] = b1v.y; acc[i][2] = b1v.z; acc[i][3] = b1v.w;
    }
  }
  for (int kc = 0; kc < 32; ++kc) {
    float4 wv[4];
#pragma unroll
    for (int kk = 0; kk < 4; ++kk)
      wv[kk] = *(const float4*)&w1[(kc * 4 + kk) * ND + tx * 4];
#pragma unroll
    for (int i = 0; i < 4; ++i) {
      float4 xv = *(const float4*)&xt[ty * 4 + i][kc * 4];
      acc[i][0] = fmaf(xv.x, wv[0].x, fmaf(xv.y, wv[1].x, fmaf(xv.z, wv[2].x, fmaf(xv.w, wv[3].x, acc[i][0]))));
      acc[i][1] = fmaf(xv.x, wv[0].y, fmaf(xv.y, wv[1].y, fmaf(xv.z, wv[2].y, fmaf(xv.w, wv[3].y, acc[i][1]))));
      acc[i][2] = fmaf(xv.x, wv[0].z, fmaf(xv.y, wv[1].z, fmaf(xv.z, wv[2].z, fmaf(xv.w, wv[3].z, acc[i][2]))));
      acc[i][3] = fmaf(xv.x, wv[0].w, fmaf(xv.y, wv[1].w, fmaf(xv.z, wv[2].w, fmaf(xv.w, wv[3].w, acc[i][3]))));
    }
  }
  {
    float4 w2v = *(const float4*)&w2[tx * 4];
#pragma unroll
    for (int i = 0; i < 4; ++i) {
      float s = fmaxf(acc[i][0], 0.f) * w2v.x + fmaxf(acc[i][1], 0.f) * w2v.y +
                fmaxf(acc[i][2], 0.f) * w2v.z + fmaxf(acc[i][3], 0.f) * w2v.w;
      red[ty * 4 + i][tx] = s;
    }
  }
  __syncthreads();
  if (tid < 64) {
    float s = 0.f;
#pragma unroll
    for (int j = 0; j < 16; ++j) s += red[tid][j];
    a_s[tid] = fast_tanh(s + b2[0]);
  }
  __syncthreads();
  if (wave == 0) {
    float v = a_s[lane];
    float mx = wmax(v);
    float e = __expf(v - mx);
    float ssum = wsum(e);
    w_s[lane] = e / ssum;
  }
  __syncthreads();
  // mean_pt = sum_m w[m]*hh[m];  hh[m] = xt[m][:64] * finv[m]
  float mp = 0.f;
#pragma unroll
  for (int mi = 0; mi < 16; ++mi) {
    int m = wave + mi * 4;
    mp = fmaf(w_s[m] * finv_s[m], xt[m][lane], mp);
  }
  part[wave][lane] = mp;
  __syncthreads();
  if (wave == 0) {
    float v = part[0][lane] + part[1][lane] + part[2][lane] + part[3][lane];
    meanpt[lane] = v;
    float p2m = wsum(v * v);
    if (lane == 0) scal = p2m;
  }
  __syncthreads();
  const float p2m = scal;
  const float pd_ = meanpt[lane];
  const float two_over_lam = fmaxf(1.f - p2m, 1e-15f);
  float oacc = 0.f;
#pragma unroll
  for (int mi = 0; mi < 16; ++mi) {
    int m = wave + mi * 4;
    float wm = w_s[m];
    float xd = wm * ht_r[mi];
    float y2 = wsum(xd * xd);
    float xy = wsum(-pd_ * xd);
    float num = (1.f + 2.f * xy + y2) * (-pd_) + (1.f - p2m) * xd;
    float den = fmaxf(1.f + 2.f * xy + p2m * y2, 1e-15f);
    float md = num / den;
    float n = sqrtf(fmaxf(wsum(md * md), 1e-15f));
    float e = two_over_lam * artanh_clip(n) / n * md;
    oacc = fmaf(wm, e, oacc);
  }
  part[wave][lane] = oacc;
  __syncthreads();
  if (wave == 0)
    out[(size_t)b * ND + lane] = part[0][lane] + part[1][lane] + part[2][lane] + part[3][lane];
}

// ---------------- l2-normalize + bf16 cast (for MFMA lse) ----------------
__global__ __launch_bounds__(256) void l2bf_kernel(
    const float* __restrict__ in, __hip_bfloat16* __restrict__ out) {
  int row = blockIdx.x * 4 + (threadIdx.x >> 6);
  int lane = threadIdx.x & 63;
  size_t off = (size_t)blockIdx.y * STACK + (size_t)row * ND + lane;
  float v = in[off];
  float s = wsum(v * v);
  out[off] = __float2bfloat16(v / fmaxf(sqrtf(s), 1e-12f));
}

// ---------------- positive-pair dots (inline-normalized, fp32) ----------------
__global__ __launch_bounds__(256) void pos_kernel(
    const float* __restrict__ stacks, float* __restrict__ pos) {
  int row = blockIdx.x * 4 + (threadIdx.x >> 6);
  int lane = threadIdx.x & 63;
  int sa = blockIdx.y;            // pair0: (0,2)=(ucf,ukg); pair1: (1,3)=(ikg,icf)
  int sb = sa + 2;
  float a = stacks[(size_t)sa * STACK + (size_t)row * ND + lane];
  float c = stacks[(size_t)sb * STACK + (size_t)row * ND + lane];
  float na = wsum(a * a), nc = wsum(c * c), d = wsum(a * c);
  if (lane == 0)
    pos[blockIdx.y * NROWS + row] =
        d / (fmaxf(sqrtf(na), 1e-12f) * fmaxf(sqrtf(nc), 1e-12f));
}

// ---------------- contrastive denominators via MFMA ----------------
// Spart[half][pair][row] = sum over half the cols of exp(X_row . Y_col / T)
__global__ __launch_bounds__(256) void lse_mfma_kernel(
    const ushort* __restrict__ nbf, float* __restrict__ Spart) {
  const int tid = threadIdx.x;
  const int wave = tid >> 6, lane = tid & 63;
  const int pair = blockIdx.y;
  const int half = blockIdx.z;
  int xi = (pair & 2) ? ((pair & 1) ? 3 : 1) : ((pair & 1) ? 2 : 0);
  int yi = xi ^ 2;
  const ushort* X = nbf + (size_t)xi * STACK;
  const ushort* Y = nbf + (size_t)yi * STACK;
  const int r0 = blockIdx.x * 64 + wave * 16;   // this wave's 16 rows
  const int row = lane & 15, quad = lane >> 4;

  // A-frag: A[m=lane&15][k=quad*8+j]; X row-major [6144][64] -> 16B loads
  short8 a0 = *(const short8*)&X[(size_t)(r0 + row) * 64 + quad * 8];
  short8 a1 = *(const short8*)&X[(size_t)(r0 + row) * 64 + 32 + quad * 8];

  float rsum[4] = {0.f, 0.f, 0.f, 0.f};
  const int c0 = half * 3072;
  for (int ct = 0; ct < 48; ++ct) {
    const int cbase = c0 + ct * 64;
#pragma unroll
    for (int nt = 0; nt < 4; ++nt) {
      const ushort* yrow = &Y[(size_t)(cbase + nt * 16 + row) * 64 + quad * 8];
      short8 b0 = *(const short8*)yrow;
      short8 b1 = *(const short8*)(yrow + 32);
      float4v c = {0.f, 0.f, 0.f, 0.f};
      c = __builtin_amdgcn_mfma_f32_16x16x32_bf16(a0, b0, c, 0, 0, 0);
      c = __builtin_amdgcn_mfma_f32_16x16x32_bf16(a1, b1, c, 0, 0, 0);
#pragma unroll
      for (int i = 0; i < 4; ++i) rsum[i] += __expf(c[i] * 5.f);
    }
  }
  // C layout: col=lane&15, row=quad*4+reg -> reduce across the 16 col-lanes
#pragma unroll
  for (int i = 0; i < 4; ++i) {
    float v = rsum[i];
    v += __shfl_xor(v, 1, 64);
    v += __shfl_xor(v, 2, 64);
    v += __shfl_xor(v, 4, 64);
    v += __shfl_xor(v, 8, 64);
    if (row == 0)
      Spart[((size_t)half * 4 + pair) * NROWS + r0 + quad * 4 + i] = v;
  }
}

// ---------------- scores ----------------
__global__ __launch_bounds__(256) void scores_kernel(
    const float* __restrict__ stacks, float* __restrict__ out) {
  int b = blockIdx.x * 4 + (threadIdx.x >> 6);
  int lane = threadIdx.x & 63;
  float s = 0.f;
#pragma unroll
  for (int l = 0; l < 3; ++l) {
    size_t o = (size_t)l * NB * ND + (size_t)b * ND + lane;
    s += stacks[0 * (size_t)STACK + o] * stacks[3 * (size_t)STACK + o]
       + stacks[2 * (size_t)STACK + o] * stacks[1 * (size_t)STACK + o];
  }
  s = wsum(s);
  if (lane == 0) out[b] = 1.f / (1.f + __expf(-s));
}

// ---------------- final loss ----------------
__global__ __launch_bounds__(256) void loss_kernel(
    const float* __restrict__ Spart, const float* __restrict__ pos,
    float* __restrict__ out) {
  __shared__ double red[256];
  double acc = 0.0;
  for (int i = threadIdx.x; i < 4 * NROWS; i += 256)
    acc += (double)logf(Spart[i] + Spart[4 * NROWS + i]);
  for (int i = threadIdx.x; i < 2 * NROWS; i += 256) acc -= 10.0 * (double)pos[i];
  red[threadIdx.x] = acc;
  __syncthreads();
  for (int s = 128; s > 0; s >>= 1) {
    if (threadIdx.x < s) red[threadIdx.x] += red[threadIdx.x + s];
    __syncthreads();
  }
  if (threadIdx.x == 0) out[NB] = (float)(1e-6 * red[0]);
}

extern "C" void kernel_launch(void* const* d_in, const int* in_sizes, int n_in,
                              void* d_out, int out_size, void* d_ws, size_t ws_size,
                              hipStream_t stream) {
  const int* items = (const int*)d_in[0];
  const int* ucf_h = (const int*)d_in[1];
  const int* ucf_r = (const int*)d_in[2];
  const int* ucf_t = (const int*)d_in[3];
  const int* ikg_h = (const int*)d_in[4];
  const int* ikg_r = (const int*)d_in[5];
  const int* ikg_t = (const int*)d_in[6];
  const int* ukg_h = (const int*)d_in[7];
  const int* ukg_r = (const int*)d_in[8];
  const int* ukg_t = (const int*)d_in[9];
  const int* icf_h = (const int*)d_in[10];
  const int* icf_r = (const int*)d_in[11];
  const int* icf_t = (const int*)d_in[12];
  const float* E = (const float*)d_in[13];
  const float* R = (const float*)d_in[14];
  const float* att_w1 = (const float*)d_in[15];
  const float* att_w2 = (const float*)d_in[16];
  const float* a2_w1 = (const float*)d_in[17];
  const float* a2_b1 = (const float*)d_in[18];
  const float* a2_w2 = (const float*)d_in[19];
  const float* a2_b2 = (const float*)d_in[20];
  const float* curv = (const float*)d_in[21];
  float* outp = (float*)d_out;

  float* ws = (float*)d_ws;
  float* stacks = ws;                                   // 4*STACK
  float* Spart = stacks + 4 * (size_t)STACK;            // 2*4*NROWS
  float* posarr = Spart + 8 * (size_t)NROWS;            // 2*NROWS
  __hip_bfloat16* nbf = (__hip_bfloat16*)(posarr + 2 * (size_t)NROWS);  // 4*STACK bf16

  float* ucf = stacks + 0 * (size_t)STACK;
  float* ikg = stacks + 1 * (size_t)STACK;
  float* ukg = stacks + 2 * (size_t)STACK;
  float* icf = stacks + 3 * (size_t)STACK;

  const size_t L = (size_t)NB * ND;

  init_mean_kernel<<<NB, 64, 0, stream>>>(E, ucf_h, ucf);
  init_item_kernel<<<NB, 64, 0, stream>>>(E, items, ikg);
  init_mean_kernel<<<NB, 64, 0, stream>>>(E, ukg_h, ukg);
  init_mean_kernel<<<NB, 64, 0, stream>>>(E, icf_h, icf);

  ed_agg_kernel<<<NB, 256, 0, stream>>>(E, R, ucf_h, ucf_r, ucf_t, 0, att_w1, att_w2, ucf + 1 * L);
  ed_agg_kernel<<<NB, 256, 0, stream>>>(E, R, ucf_h, ucf_r, ucf_t, 1, att_w1, att_w2, ucf + 2 * L);
  ed_agg_kernel<<<NB, 256, 0, stream>>>(E, R, ikg_h, ikg_r, ikg_t, 0, att_w1, att_w2, ikg + 1 * L);
  ed_agg_kernel<<<NB, 256, 0, stream>>>(E, R, ikg_h, ikg_r, ikg_t, 1, att_w1, att_w2, ikg + 2 * L);
  hyper_agg_kernel<<<NB, 256, 0, stream>>>(E, R, ukg_h, ukg_r, ukg_t, 0, a2_w1, a2_b1, a2_w2, a2_b2, curv, ukg + 1 * L);
  hyper_agg_kernel<<<NB, 256, 0, stream>>>(E, R, ukg_h, ukg_r, ukg_t, 1, a2_w1, a2_b1, a2_w2, a2_b2, curv, ukg + 2 * L);
  hyper_agg_kernel<<<NB, 256, 0, stream>>>(E, R, icf_h, icf_r, icf_t, 0, a2_w1, a2_b1, a2_w2, a2_b2, curv, icf + 1 * L);
  hyper_agg_kernel<<<NB, 256, 0, stream>>>(E, R, icf_h, icf_r, icf_t, 1, a2_w1, a2_b1, a2_w2, a2_b2, curv, icf + 2 * L);

  l2bf_kernel<<<dim3(NROWS / 4, 4), 256, 0, stream>>>(stacks, nbf);
  pos_kernel<<<dim3(NROWS / 4, 2), 256, 0, stream>>>(stacks, posarr);
  lse_mfma_kernel<<<dim3(NROWS / 64, 4, 2), 256, 0, stream>>>((const ushort*)nbf, Spart);

  scores_kernel<<<NB / 4, 256, 0, stream>>>(stacks, outp);
  loss_kernel<<<1, 256, 0, stream>>>(Spart, posarr, outp);
}

// Round 3
// 1021.530 us; speedup vs baseline: 2.0351x; 1.4871x over previous
//
#include <hip/hip_runtime.h>
#include <hip/hip_bf16.h>
#include <cstdint>
#include <cstddef>

// Problem constants (match reference)
constexpr int NB = 2048;            // batch
constexpr int NM = 64;              // neighbors M
constexpr int ND = 64;              // dim
constexpr int NBM = NB * NM;        // 131072 (one layer of an index tensor)
constexpr int NROWS = 3 * NB;       // 6144 rows per stack (L+1 = 3)
constexpr int STACK = 3 * NB * ND;  // 393216 floats per stack

typedef __attribute__((ext_vector_type(8))) short short8;
typedef __attribute__((ext_vector_type(4))) float float4v;

__device__ __forceinline__ float wsum(float v) {
#pragma unroll
  for (int o = 32; o > 0; o >>= 1) v += __shfl_xor(v, o, 64);
  return v;
}

__device__ __forceinline__ float wmax(float v) {
#pragma unroll
  for (int o = 32; o > 0; o >>= 1) v = fmaxf(v, __shfl_xor(v, o, 64));
  return v;
}

__device__ __forceinline__ float fast_tanh(float x) {
  float t = __expf(2.f * x);
  return (t - 1.f) / (t + 1.f);
}

// artanh(clip(x, -1+1e-5, 1-1e-5))
__device__ __forceinline__ float artanh_clip(float x) {
  x = fminf(fmaxf(x, -1.f + 1e-5f), 1.f - 1e-5f);
  return 0.5f * __logf((1.f + x) / (1.f - x));
}

// ---------------- W1 pre-pack into MFMA B-fragment layout ----------------
// out[kt][nt][lane][j] = bf16( w1[(kt*32 + (lane>>4)*8 + j) * 64 + nt*16 + (lane&15)] )
__global__ __launch_bounds__(256) void pack_w1_kernel(
    const float* __restrict__ w1, ushort* __restrict__ out) {
  int e = blockIdx.x * 256 + threadIdx.x;   // 8192 elements, grid 32
  if (e >= 8192) return;
  int j = e & 7, ln = (e >> 3) & 63, nt = (e >> 9) & 3, kt = e >> 11;
  int n = nt * 16 + (ln & 15), k = kt * 32 + ((ln >> 4) << 3) + j;
  __hip_bfloat16 b = __float2bfloat16(w1[k * 64 + n]);
  out[e] = *(ushort*)&b;
}

// ---------------- layer-0 init ----------------
__global__ __launch_bounds__(64) void init_mean_kernel(
    const float* __restrict__ E, const int* __restrict__ idx, float* __restrict__ out) {
  int b = blockIdx.x, lane = threadIdx.x;
  float s = 0.f;
  for (int m = 0; m < NM; ++m) s += E[(size_t)idx[b * NM + m] * ND + lane];
  out[(size_t)b * ND + lane] = s * (1.f / 64.f);
}

__global__ __launch_bounds__(64) void init_item_kernel(
    const float* __restrict__ E, const int* __restrict__ idx, float* __restrict__ out) {
  int b = blockIdx.x, lane = threadIdx.x;
  out[(size_t)b * ND + lane] = E[(size_t)idx[b] * ND + lane];
}

// ---------------- Euclidean attention agg (ucf / ikg) ----------------
__global__ __launch_bounds__(256) void ed_agg_kernel(
    const float* __restrict__ E, const float* __restrict__ R,
    const int* __restrict__ h_idx, const int* __restrict__ r_idx,
    const int* __restrict__ t_idx, int layer,
    const ushort* __restrict__ w1p, const float* __restrict__ w2,
    float* __restrict__ out) {
  __shared__ __align__(16) __hip_bfloat16 xt[64][136];  // tang rows bf16 (128 used)
  __shared__ float a_s[64];
  __shared__ float w_s[64];
  __shared__ float part[4][64];

  const int b = blockIdx.x;
  const int tid = threadIdx.x;
  const int wave = tid >> 6, lane = tid & 63;

  // phase A: gather x = [h, path]
  for (int m = wave; m < NM; m += 4) {
    float hd = E[(size_t)h_idx[b * NM + m] * ND + lane];
    float pd = R[(size_t)r_idx[b * NM + m] * ND + lane];
    if (layer) {
      hd += E[(size_t)h_idx[NBM + b * NM + m] * ND + lane];
      pd *= R[(size_t)r_idx[NBM + b * NM + m] * ND + lane];
    }
    xt[m][lane] = __float2bfloat16(hd);
    xt[m][64 + lane] = __float2bfloat16(pd);
  }
  __syncthreads();

  // phase B: MFMA MLP, wave handles rows wave*16..+15
  const int colq = lane & 15, quad = lane >> 4;
  short8 afr[4];
#pragma unroll
  for (int kt = 0; kt < 4; ++kt)
    afr[kt] = *(const short8*)&xt[wave * 16 + colq][kt * 32 + quad * 8];
  float w2v[4];
#pragma unroll
  for (int nt = 0; nt < 4; ++nt) w2v[nt] = w2[nt * 16 + colq];
  float cc[4][4];
#pragma unroll
  for (int nt = 0; nt < 4; ++nt) {
    float4v c = {0.f, 0.f, 0.f, 0.f};
#pragma unroll
    for (int kt = 0; kt < 4; ++kt) {
      short8 bfr = *(const short8*)&w1p[(((kt << 2) | nt) * 64 + lane) * 8];
      c = __builtin_amdgcn_mfma_f32_16x16x32_bf16(afr[kt], bfr, c, 0, 0, 0);
    }
#pragma unroll
    for (int i = 0; i < 4; ++i) cc[nt][i] = c[i];
  }
  float sred[4];
#pragma unroll
  for (int i = 0; i < 4; ++i)
    sred[i] = fmaxf(cc[0][i], 0.f) * w2v[0] + fmaxf(cc[1][i], 0.f) * w2v[1] +
              fmaxf(cc[2][i], 0.f) * w2v[2] + fmaxf(cc[3][i], 0.f) * w2v[3];
#pragma unroll
  for (int o = 8; o > 0; o >>= 1) {
#pragma unroll
    for (int i = 0; i < 4; ++i) sred[i] += __shfl_xor(sred[i], o, 64);
  }
  if (colq == 0) {
#pragma unroll
    for (int i = 0; i < 4; ++i)
      a_s[wave * 16 + quad * 4 + i] = 1.f / (1.f + __expf(-sred[i]));
  }
  __syncthreads();
  if (wave == 0) {
    float v = a_s[lane];
    float mx = wmax(v);
    float e = __expf(v - mx);
    float ssum = wsum(e);
    w_s[lane] = e / ssum;
  }
  __syncthreads();
  float o = 0.f;
  for (int m = wave; m < NM; m += 4)
    o = fmaf(w_s[m], E[(size_t)t_idx[(size_t)layer * NBM + b * NM + m] * ND + lane], o);
  part[wave][lane] = o;
  __syncthreads();
  if (wave == 0)
    out[(size_t)b * ND + lane] = part[0][lane] + part[1][lane] + part[2][lane] + part[3][lane];
}

// ---------------- Hyperbolic attention agg (ukg / icf) ----------------
// Phase A: ONE batched 5-dot reduction per m; all geometry scalar-recovered.
__global__ __launch_bounds__(256) void hyper_agg_kernel(
    const float* __restrict__ E, const float* __restrict__ R,
    const int* __restrict__ h_idx, const int* __restrict__ r_idx,
    const int* __restrict__ t_idx, int layer,
    const ushort* __restrict__ w1p, const float* __restrict__ b1,
    const float* __restrict__ w2, const float* __restrict__ b2,
    const float* __restrict__ curv, float* __restrict__ out) {
  __shared__ __align__(16) __hip_bfloat16 xt[64][136];
  __shared__ float a_s[64];
  __shared__ float w_s[64];
  __shared__ float finv_s[64];
  __shared__ float hts2_s[64];
  __shared__ float meanpt[64];
  __shared__ float part[4][64];
  __shared__ float scal;

  const int b = blockIdx.x;
  const int tid = threadIdx.x;
  const int wave = tid >> 6, lane = tid & 63;
  const float cabs = fabsf(*curv);

  float ht_r[16];

#pragma unroll
  for (int mi = 0; mi < 16; ++mi) {
    const int m = wave + mi * 4;
    float hv = E[(size_t)h_idx[b * NM + m] * ND + lane];
    float pv = R[(size_t)r_idx[b * NM + m] * ND + lane];
    if (layer) {
      hv += E[(size_t)h_idx[NBM + b * NM + m] * ND + lane];
      pv *= R[(size_t)r_idx[NBM + b * NM + m] * ND + lane];
    }
    float tv = E[(size_t)t_idx[(size_t)layer * NBM + b * NM + m] * ND + lane];
    // one batched 5-dot butterfly (ILP 5)
    float q0 = hv * hv, q1 = pv * pv, q2 = tv * tv, q3 = hv * tv, q4 = hv * pv;
#pragma unroll
    for (int o = 32; o > 0; o >>= 1) {
      q0 += __shfl_xor(q0, o, 64);
      q1 += __shfl_xor(q1, o, 64);
      q2 += __shfl_xor(q2, o, 64);
      q3 += __shfl_xor(q3, o, 64);
      q4 += __shfl_xor(q4, o, 64);
    }
    const float sh = q0, sp = q1, st = q2, sht = q3, shp = q4;
    // scalar geometry (identical in all lanes)
    float rih = 1.f / fmaxf(sqrtf(sh), 1e-12f);
    float rip = 1.f / fmaxf(sqrtf(sp), 1e-12f);
    float rit = 1.f / fmaxf(sqrtf(st), 1e-12f);
    float shd2 = sh * rih * rih;
    float nh = sqrtf(fmaxf(shd2, 1e-15f));
    float ch = fast_tanh(nh) / nh * rih * cabs;      // hh = ch*h
    float p2 = ch * ch * sh;
    float lam = 2.f / fmaxf(1.f - p2, 1e-15f);
    // ht = e1*h + e2*t
    float std2 = st * rit * rit;
    float ntn = sqrtf(fmaxf(std2, 1e-15f));
    float ct = fast_tanh(0.5f * lam * ntn) / ntn * rit;
    float y2 = ct * ct * st;
    float xy = ch * ct * sht;
    float At = 1.f + 2.f * xy + y2, Bt = 1.f - p2;
    float dent = fmaxf(1.f + 2.f * xy + p2 * y2, 1e-15f);
    float e1 = At * ch / dent, e2 = Bt * ct / dent;
    ht_r[mi] = e1 * hv + e2 * tv;
    float hts2 = e1 * e1 * sh + 2.f * e1 * e2 * sht + e2 * e2 * st;
    // hr = f1*h + f2*p
    float spd2 = sp * rip * rip;
    float npn = sqrtf(fmaxf(spd2, 1e-15f));
    float cp = fast_tanh(0.5f * lam * npn) / npn * rip;
    float z2 = cp * cp * sp;
    float xz = ch * cp * shp;
    float Ar = 1.f + 2.f * xz + z2, Br = 1.f - p2;
    float denr = fmaxf(1.f + 2.f * xz + p2 * z2, 1e-15f);
    float f1 = Ar * ch / denr, f2 = Br * cp / denr;
    float hr2 = f1 * f1 * sh + 2.f * f1 * f2 * shp + f2 * f2 * sp;
    // tang = fq * [hh, hr]
    float n128 = sqrtf(fmaxf(p2 + hr2, 1e-15f));
    float fq = artanh_clip(n128) / n128;
    xt[m][lane] = __float2bfloat16(fq * ch * hv);
    xt[m][64 + lane] = __float2bfloat16(fq * (f1 * hv + f2 * pv));
    if (lane == 0) {
      finv_s[m] = 1.f / fq;
      hts2_s[m] = hts2;
    }
  }
  __syncthreads();

  // phase B: MFMA MLP
  const int colq = lane & 15, quad = lane >> 4;
  {
    short8 afr[4];
#pragma unroll
    for (int kt = 0; kt < 4; ++kt)
      afr[kt] = *(const short8*)&xt[wave * 16 + colq][kt * 32 + quad * 8];
    float b1v[4], w2v[4];
#pragma unroll
    for (int nt = 0; nt < 4; ++nt) {
      b1v[nt] = b1[nt * 16 + colq];
      w2v[nt] = w2[nt * 16 + colq];
    }
    float cc[4][4];
#pragma unroll
    for (int nt = 0; nt < 4; ++nt) {
      float4v c = {0.f, 0.f, 0.f, 0.f};
#pragma unroll
      for (int kt = 0; kt < 4; ++kt) {
        short8 bfr = *(const short8*)&w1p[(((kt << 2) | nt) * 64 + lane) * 8];
        c = __builtin_amdgcn_mfma_f32_16x16x32_bf16(afr[kt], bfr, c, 0, 0, 0);
      }
#pragma unroll
      for (int i = 0; i < 4; ++i) cc[nt][i] = c[i];
    }
    float b2v = b2[0];
    float sred[4];
#pragma unroll
    for (int i = 0; i < 4; ++i)
      sred[i] = fmaxf(cc[0][i] + b1v[0], 0.f) * w2v[0] +
                fmaxf(cc[1][i] + b1v[1], 0.f) * w2v[1] +
                fmaxf(cc[2][i] + b1v[2], 0.f) * w2v[2] +
                fmaxf(cc[3][i] + b1v[3], 0.f) * w2v[3];
#pragma unroll
    for (int o = 8; o > 0; o >>= 1) {
#pragma unroll
      for (int i = 0; i < 4; ++i) sred[i] += __shfl_xor(sred[i], o, 64);
    }
    if (colq == 0) {
#pragma unroll
      for (int i = 0; i < 4; ++i)
        a_s[wave * 16 + quad * 4 + i] = fast_tanh(sred[i] + b2v);
    }
  }
  __syncthreads();
  if (wave == 0) {
    float v = a_s[lane];
    float mx = wmax(v);
    float e = __expf(v - mx);
    float ssum = wsum(e);
    w_s[lane] = e / ssum;
  }
  __syncthreads();
  // mean_pt = sum_m w[m]*hh[m];  hh[m] = xt[m][:64] * finv[m]
  float mp = 0.f;
#pragma unroll
  for (int mi = 0; mi < 16; ++mi) {
    int m = wave + mi * 4;
    mp = fmaf(w_s[m] * finv_s[m], (float)xt[m][lane], mp);
  }
  part[wave][lane] = mp;
  __syncthreads();
  if (wave == 0) {
    float v = part[0][lane] + part[1][lane] + part[2][lane] + part[3][lane];
    meanpt[lane] = v;
    float p2m = wsum(v * v);
    if (lane == 0) scal = p2m;
  }
  __syncthreads();
  const float p2m = scal;
  const float pd_ = meanpt[lane];
  const float two_over_lam = fmaxf(1.f - p2m, 1e-15f);
  // phase C: 16 batched dots meanpt.ht_m (ILP 16), then all-scalar logmap
  float dp[16];
#pragma unroll
  for (int mi = 0; mi < 16; ++mi) dp[mi] = pd_ * ht_r[mi];
#pragma unroll
  for (int o = 32; o > 0; o >>= 1) {
#pragma unroll
    for (int mi = 0; mi < 16; ++mi) dp[mi] += __shfl_xor(dp[mi], o, 64);
  }
  float coefA = 0.f, ovec = 0.f;
#pragma unroll
  for (int mi = 0; mi < 16; ++mi) {
    int m = wave + mi * 4;
    float wm = w_s[m];
    float y2 = wm * wm * hts2_s[m];
    float xy = -wm * dp[mi];
    float al = 1.f + 2.f * xy + y2, be = 1.f - p2m;
    float den = fmaxf(1.f + 2.f * xy + p2m * y2, 1e-15f);
    float md2 = (al * al * p2m - 2.f * al * be * wm * dp[mi] + be * be * y2) / (den * den);
    float n = sqrtf(fmaxf(md2, 1e-15f));
    float sm = two_over_lam * artanh_clip(n) / n / den;
    coefA = fmaf(wm * sm, al, coefA);
    ovec = fmaf(wm * wm * sm * be, ht_r[mi], ovec);
  }
  part[wave][lane] = ovec - coefA * pd_;
  __syncthreads();
  if (wave == 0)
    out[(size_t)b * ND + lane] = part[0][lane] + part[1][lane] + part[2][lane] + part[3][lane];
}

// ---------------- l2-normalize + bf16 cast (for MFMA lse) ----------------
__global__ __launch_bounds__(256) void l2bf_kernel(
    const float* __restrict__ in, __hip_bfloat16* __restrict__ out) {
  int row = blockIdx.x * 4 + (threadIdx.x >> 6);
  int lane = threadIdx.x & 63;
  size_t off = (size_t)blockIdx.y * STACK + (size_t)row * ND + lane;
  float v = in[off];
  float s = wsum(v * v);
  out[off] = __float2bfloat16(v / fmaxf(sqrtf(s), 1e-12f));
}

// ---------------- positive-pair dots (inline-normalized, fp32) ----------------
__global__ __launch_bounds__(256) void pos_kernel(
    const float* __restrict__ stacks, float* __restrict__ pos) {
  int row = blockIdx.x * 4 + (threadIdx.x >> 6);
  int lane = threadIdx.x & 63;
  int sa = blockIdx.y;
  int sb = sa + 2;
  float a = stacks[(size_t)sa * STACK + (size_t)row * ND + lane];
  float c = stacks[(size_t)sb * STACK + (size_t)row * ND + lane];
  float q0 = a * a, q1 = c * c, q2 = a * c;
#pragma unroll
  for (int o = 32; o > 0; o >>= 1) {
    q0 += __shfl_xor(q0, o, 64);
    q1 += __shfl_xor(q1, o, 64);
    q2 += __shfl_xor(q2, o, 64);
  }
  if (lane == 0)
    pos[blockIdx.y * NROWS + row] =
        q2 / (fmaxf(sqrtf(q0), 1e-12f) * fmaxf(sqrtf(q1), 1e-12f));
}

// ---------------- contrastive denominators via MFMA ----------------
__global__ __launch_bounds__(256) void lse_mfma_kernel(
    const ushort* __restrict__ nbf, float* __restrict__ Spart) {
  const int tid = threadIdx.x;
  const int wave = tid >> 6, lane = tid & 63;
  const int pair = blockIdx.y;
  const int half = blockIdx.z;
  int xi = (pair & 2) ? ((pair & 1) ? 3 : 1) : ((pair & 1) ? 2 : 0);
  int yi = xi ^ 2;
  const ushort* X = nbf + (size_t)xi * STACK;
  const ushort* Y = nbf + (size_t)yi * STACK;
  const int r0 = blockIdx.x * 64 + wave * 16;
  const int row = lane & 15, quad = lane >> 4;

  short8 a0 = *(const short8*)&X[(size_t)(r0 + row) * 64 + quad * 8];
  short8 a1 = *(const short8*)&X[(size_t)(r0 + row) * 64 + 32 + quad * 8];

  float rsum[4] = {0.f, 0.f, 0.f, 0.f};
  const int c0 = half * 3072;
  for (int ct = 0; ct < 48; ++ct) {
    const int cbase = c0 + ct * 64;
#pragma unroll
    for (int nt = 0; nt < 4; ++nt) {
      const ushort* yrow = &Y[(size_t)(cbase + nt * 16 + row) * 64 + quad * 8];
      short8 b0 = *(const short8*)yrow;
      short8 b1 = *(const short8*)(yrow + 32);
      float4v c = {0.f, 0.f, 0.f, 0.f};
      c = __builtin_amdgcn_mfma_f32_16x16x32_bf16(a0, b0, c, 0, 0, 0);
      c = __builtin_amdgcn_mfma_f32_16x16x32_bf16(a1, b1, c, 0, 0, 0);
#pragma unroll
      for (int i = 0; i < 4; ++i) rsum[i] += __expf(c[i] * 5.f);
    }
  }
#pragma unroll
  for (int i = 0; i < 4; ++i) {
    float v = rsum[i];
    v += __shfl_xor(v, 1, 64);
    v += __shfl_xor(v, 2, 64);
    v += __shfl_xor(v, 4, 64);
    v += __shfl_xor(v, 8, 64);
    if (row == 0)
      Spart[((size_t)half * 4 + pair) * NROWS + r0 + quad * 4 + i] = v;
  }
}

// ---------------- scores ----------------
__global__ __launch_bounds__(256) void scores_kernel(
    const float* __restrict__ stacks, float* __restrict__ out) {
  int b = blockIdx.x * 4 + (threadIdx.x >> 6);
  int lane = threadIdx.x & 63;
  float s = 0.f;
#pragma unroll
  for (int l = 0; l < 3; ++l) {
    size_t o = (size_t)l * NB * ND + (size_t)b * ND + lane;
    s += stacks[0 * (size_t)STACK + o] * stacks[3 * (size_t)STACK + o]
       + stacks[2 * (size_t)STACK + o] * stacks[1 * (size_t)STACK + o];
  }
  s = wsum(s);
  if (lane == 0) out[b] = 1.f / (1.f + __expf(-s));
}

// ---------------- final loss ----------------
__global__ __launch_bounds__(256) void loss_kernel(
    const float* __restrict__ Spart, const float* __restrict__ pos,
    float* __restrict__ out) {
  __shared__ double red[256];
  double acc = 0.0;
  for (int i = threadIdx.x; i < 4 * NROWS; i += 256)
    acc += (double)logf(Spart[i] + Spart[4 * NROWS + i]);
  for (int i = threadIdx.x; i < 2 * NROWS; i += 256) acc -= 10.0 * (double)pos[i];
  red[threadIdx.x] = acc;
  __syncthreads();
  for (int s = 128; s > 0; s >>= 1) {
    if (threadIdx.x < s) red[threadIdx.x] += red[threadIdx.x + s];
    __syncthreads();
  }
  if (threadIdx.x == 0) out[NB] = (float)(1e-6 * red[0]);
}

extern "C" void kernel_launch(void* const* d_in, const int* in_sizes, int n_in,
                              void* d_out, int out_size, void* d_ws, size_t ws_size,
                              hipStream_t stream) {
  const int* items = (const int*)d_in[0];
  const int* ucf_h = (const int*)d_in[1];
  const int* ucf_r = (const int*)d_in[2];
  const int* ucf_t = (const int*)d_in[3];
  const int* ikg_h = (const int*)d_in[4];
  const int* ikg_r = (const int*)d_in[5];
  const int* ikg_t = (const int*)d_in[6];
  const int* ukg_h = (const int*)d_in[7];
  const int* ukg_r = (const int*)d_in[8];
  const int* ukg_t = (const int*)d_in[9];
  const int* icf_h = (const int*)d_in[10];
  const int* icf_r = (const int*)d_in[11];
  const int* icf_t = (const int*)d_in[12];
  const float* E = (const float*)d_in[13];
  const float* R = (const float*)d_in[14];
  const float* att_w1 = (const float*)d_in[15];
  const float* att_w2 = (const float*)d_in[16];
  const float* a2_w1 = (const float*)d_in[17];
  const float* a2_b1 = (const float*)d_in[18];
  const float* a2_w2 = (const float*)d_in[19];
  const float* a2_b2 = (const float*)d_in[20];
  const float* curv = (const float*)d_in[21];
  float* outp = (float*)d_out;

  float* ws = (float*)d_ws;
  float* stacks = ws;                                   // 4*STACK f32
  float* Spart = stacks + 4 * (size_t)STACK;            // 8*NROWS f32
  float* posarr = Spart + 8 * (size_t)NROWS;            // 2*NROWS f32
  __hip_bfloat16* nbf = (__hip_bfloat16*)(posarr + 2 * (size_t)NROWS);  // 4*STACK bf16
  ushort* w1p_ed = (ushort*)(nbf + 4 * (size_t)STACK);  // 8192 ushort
  ushort* w1p_hy = w1p_ed + 8192;                       // 8192 ushort

  float* ucf = stacks + 0 * (size_t)STACK;
  float* ikg = stacks + 1 * (size_t)STACK;
  float* ukg = stacks + 2 * (size_t)STACK;
  float* icf = stacks + 3 * (size_t)STACK;

  const size_t L = (size_t)NB * ND;

  pack_w1_kernel<<<32, 256, 0, stream>>>(att_w1, w1p_ed);
  pack_w1_kernel<<<32, 256, 0, stream>>>(a2_w1, w1p_hy);

  init_mean_kernel<<<NB, 64, 0, stream>>>(E, ucf_h, ucf);
  init_item_kernel<<<NB, 64, 0, stream>>>(E, items, ikg);
  init_mean_kernel<<<NB, 64, 0, stream>>>(E, ukg_h, ukg);
  init_mean_kernel<<<NB, 64, 0, stream>>>(E, icf_h, icf);

  ed_agg_kernel<<<NB, 256, 0, stream>>>(E, R, ucf_h, ucf_r, ucf_t, 0, w1p_ed, att_w2, ucf + 1 * L);
  ed_agg_kernel<<<NB, 256, 0, stream>>>(E, R, ucf_h, ucf_r, ucf_t, 1, w1p_ed, att_w2, ucf + 2 * L);
  ed_agg_kernel<<<NB, 256, 0, stream>>>(E, R, ikg_h, ikg_r, ikg_t, 0, w1p_ed, att_w2, ikg + 1 * L);
  ed_agg_kernel<<<NB, 256, 0, stream>>>(E, R, ikg_h, ikg_r, ikg_t, 1, w1p_ed, att_w2, ikg + 2 * L);
  hyper_agg_kernel<<<NB, 256, 0, stream>>>(E, R, ukg_h, ukg_r, ukg_t, 0, w1p_hy, a2_b1, a2_w2, a2_b2, curv, ukg + 1 * L);
  hyper_agg_kernel<<<NB, 256, 0, stream>>>(E, R, ukg_h, ukg_r, ukg_t, 1, w1p_hy, a2_b1, a2_w2, a2_b2, curv, ukg + 2 * L);
  hyper_agg_kernel<<<NB, 256, 0, stream>>>(E, R, icf_h, icf_r, icf_t, 0, w1p_hy, a2_b1, a2_w2, a2_b2, curv, icf + 1 * L);
  hyper_agg_kernel<<<NB, 256, 0, stream>>>(E, R, icf_h, icf_r, icf_t, 1, w1p_hy, a2_b1, a2_w2, a2_b2, curv, icf + 2 * L);

  l2bf_kernel<<<dim3(NROWS / 4, 4), 256, 0, stream>>>(stacks, nbf);
  pos_kernel<<<dim3(NROWS / 4, 2), 256, 0, stream>>>(stacks, posarr);
  lse_mfma_kernel<<<dim3(NROWS / 64, 4, 2), 256, 0, stream>>>((const ushort*)nbf, Spart);

  scores_kernel<<<NB / 4, 256, 0, stream>>>(stacks, outp);
  loss_kernel<<<1, 256, 0, stream>>>(Spart, posarr, outp);
}

// Round 4
// 594.715 us; speedup vs baseline: 3.4956x; 1.7177x over previous
//
#include <hip/hip_runtime.h>
#include <hip/hip_bf16.h>
#include <cstdint>
#include <cstddef>

// Problem constants (match reference)
constexpr int NB = 2048;            // batch
constexpr int NM = 64;              // neighbors M
constexpr int ND = 64;              // dim
constexpr int NBM = NB * NM;        // 131072 (one layer of an index tensor)
constexpr int NROWS = 3 * NB;       // 6144 rows per stack (L+1 = 3)
constexpr int STACK = 3 * NB * ND;  // 393216 floats per stack

typedef __attribute__((ext_vector_type(8))) short short8;
typedef __attribute__((ext_vector_type(4))) float float4v;

__device__ __forceinline__ float wsum(float v) {
#pragma unroll
  for (int o = 32; o > 0; o >>= 1) v += __shfl_xor(v, o, 64);
  return v;
}

__device__ __forceinline__ float wmax(float v) {
#pragma unroll
  for (int o = 32; o > 0; o >>= 1) v = fmaxf(v, __shfl_xor(v, o, 64));
  return v;
}

__device__ __forceinline__ float rcpf(float x) { return __builtin_amdgcn_rcpf(x); }
__device__ __forceinline__ float sqf(float x) { return __builtin_amdgcn_sqrtf(x); }

__device__ __forceinline__ float fast_tanh(float x) {
  float t = __expf(2.f * x);
  return (t - 1.f) * rcpf(t + 1.f);
}

// artanh(clip(x, -1+1e-5, 1-1e-5))
__device__ __forceinline__ float artanh_clip(float x) {
  x = fminf(fmaxf(x, -1.f + 1e-5f), 1.f - 1e-5f);
  return 0.5f * __logf((1.f + x) * rcpf(1.f - x));
}

// fp32 -> bf16 (RNE), as raw ushort
__device__ __forceinline__ ushort f2bf(float f) {
  uint u = __float_as_uint(f);
  return (ushort)((u + 0x7FFFu + ((u >> 16) & 1u)) >> 16);
}

// broadcast a float from lane l (wave-uniform l)
__device__ __forceinline__ float readlane_f(float v, int l) {
  return __int_as_float(__builtin_amdgcn_readlane(__float_as_int(v), l));
}

// ---------------- W1 pre-pack into MFMA B-fragment layout ----------------
__global__ __launch_bounds__(256) void pack_w1_kernel(
    const float* __restrict__ w1, ushort* __restrict__ out) {
  int e = blockIdx.x * 256 + threadIdx.x;   // 8192 elements, grid 32
  if (e >= 8192) return;
  int j = e & 7, ln = (e >> 3) & 63, nt = (e >> 9) & 3, kt = e >> 11;
  int n = nt * 16 + (ln & 15), k = kt * 32 + ((ln >> 4) << 3) + j;
  out[e] = f2bf(w1[k * 64 + n]);
}

// ---------------- layer-0 init ----------------
__global__ __launch_bounds__(64) void init_mean_kernel(
    const float* __restrict__ E, const int* __restrict__ idx, float* __restrict__ out) {
  int b = blockIdx.x, lane = threadIdx.x;
  float s = 0.f;
  for (int m = 0; m < NM; ++m) s += E[(size_t)idx[b * NM + m] * ND + lane];
  out[(size_t)b * ND + lane] = s * (1.f / 64.f);
}

__global__ __launch_bounds__(64) void init_item_kernel(
    const float* __restrict__ E, const int* __restrict__ idx, float* __restrict__ out) {
  int b = blockIdx.x, lane = threadIdx.x;
  out[(size_t)b * ND + lane] = E[(size_t)idx[b] * ND + lane];
}

// ---------------- Euclidean attention agg (ucf / ikg) ----------------
__global__ __launch_bounds__(256) void ed_agg_kernel(
    const float* __restrict__ E, const float* __restrict__ R,
    const int* __restrict__ h_idx, const int* __restrict__ r_idx,
    const int* __restrict__ t_idx, int layer,
    const ushort* __restrict__ w1p, const float* __restrict__ w2,
    float* __restrict__ out) {
  __shared__ __align__(16) __hip_bfloat16 xt[64][136];
  __shared__ float a_s[64];
  __shared__ float w_s[64];
  __shared__ float part[4][64];

  const int b = blockIdx.x;
  const int tid = threadIdx.x;
  const int wave = tid >> 6, lane = tid & 63;

  for (int m = wave; m < NM; m += 4) {
    float hd = E[(size_t)h_idx[b * NM + m] * ND + lane];
    float pd = R[(size_t)r_idx[b * NM + m] * ND + lane];
    if (layer) {
      hd += E[(size_t)h_idx[NBM + b * NM + m] * ND + lane];
      pd *= R[(size_t)r_idx[NBM + b * NM + m] * ND + lane];
    }
    xt[m][lane] = __float2bfloat16(hd);
    xt[m][64 + lane] = __float2bfloat16(pd);
  }
  __syncthreads();

  const int colq = lane & 15, quad = lane >> 4;
  short8 afr[4];
#pragma unroll
  for (int kt = 0; kt < 4; ++kt)
    afr[kt] = *(const short8*)&xt[wave * 16 + colq][kt * 32 + quad * 8];
  float w2v[4];
#pragma unroll
  for (int nt = 0; nt < 4; ++nt) w2v[nt] = w2[nt * 16 + colq];
  float cc[4][4];
#pragma unroll
  for (int nt = 0; nt < 4; ++nt) {
    float4v c = {0.f, 0.f, 0.f, 0.f};
#pragma unroll
    for (int kt = 0; kt < 4; ++kt) {
      short8 bfr = *(const short8*)&w1p[(((kt << 2) | nt) * 64 + lane) * 8];
      c = __builtin_amdgcn_mfma_f32_16x16x32_bf16(afr[kt], bfr, c, 0, 0, 0);
    }
#pragma unroll
    for (int i = 0; i < 4; ++i) cc[nt][i] = c[i];
  }
  float sred[4];
#pragma unroll
  for (int i = 0; i < 4; ++i)
    sred[i] = fmaxf(cc[0][i], 0.f) * w2v[0] + fmaxf(cc[1][i], 0.f) * w2v[1] +
              fmaxf(cc[2][i], 0.f) * w2v[2] + fmaxf(cc[3][i], 0.f) * w2v[3];
#pragma unroll
  for (int o = 8; o > 0; o >>= 1) {
#pragma unroll
    for (int i = 0; i < 4; ++i) sred[i] += __shfl_xor(sred[i], o, 64);
  }
  if (colq == 0) {
#pragma unroll
    for (int i = 0; i < 4; ++i)
      a_s[wave * 16 + quad * 4 + i] = 1.f / (1.f + __expf(-sred[i]));
  }
  __syncthreads();
  if (wave == 0) {
    float v = a_s[lane];
    float mx = wmax(v);
    float e = __expf(v - mx);
    float ssum = wsum(e);
    w_s[lane] = e / ssum;
  }
  __syncthreads();
  float o = 0.f;
  for (int m = wave; m < NM; m += 4)
    o = fmaf(w_s[m], E[(size_t)t_idx[(size_t)layer * NBM + b * NM + m] * ND + lane], o);
  part[wave][lane] = o;
  __syncthreads();
  if (wave == 0)
    out[(size_t)b * ND + lane] = part[0][lane] + part[1][lane] + part[2][lane] + part[3][lane];
}

// ---------------- Hyperbolic attention agg (ukg / icf), v3 ----------------
// Dots via MFMA diagonals; geometry lane-parallel (lane=m); coef broadcast
// via v_readlane. Raw h/p/t in fp32 regs (VGPR 65..128 band = 4 waves/SIMD).
constexpr int RS = 72;                 // H/P/T/Hts row stride (bf16 elems)
constexpr int XS = 152;                // xt row stride
constexpr int OFF_P = 64 * RS;         // 4608
constexpr int OFF_T = 2 * 64 * RS;     // 9216
constexpr int OFF_HT = 64 * XS;        // 9728 (xt occupies [0, 9728))
constexpr int REGA_SZ = OFF_HT + 64 * RS;  // 14336 elems = 28672 B

__global__ __launch_bounds__(256) void hyper_agg_kernel(
    const float* __restrict__ E, const float* __restrict__ R,
    const int* __restrict__ h_idx, const int* __restrict__ r_idx,
    const int* __restrict__ t_idx, int layer,
    const ushort* __restrict__ w1p, const float* __restrict__ b1,
    const float* __restrict__ w2, const float* __restrict__ b2,
    const float* __restrict__ curv, float* __restrict__ out) {
  __shared__ __align__(16) ushort regA[REGA_SZ];
  __shared__ float dots_s[5][64];
  __shared__ float a_s[64];     // attention logits, later reused as dp_s
  __shared__ float w_s[64];
  __shared__ float meanpt_s[64];
  __shared__ float part[4][64];
  __shared__ float scal;

  const int b = blockIdx.x;
  const int tid = threadIdx.x;
  const int wave = tid >> 6, lane = tid & 63;
  const int wu = __builtin_amdgcn_readfirstlane(wave);
  const int m0 = wu * 16;
  const int colq = lane & 15, quad = lane >> 4;
  const float cabs = fabsf(*curv);

  float hv[16], pv[16], tv[16], ht_r[16];

  // P0: gather raw rows (fp32 regs) + stage bf16 copies for MFMA dots
#pragma unroll
  for (int mi = 0; mi < 16; ++mi) {
    const int m = m0 + mi;
    float hd = E[(size_t)h_idx[b * NM + m] * ND + lane];
    float pd = R[(size_t)r_idx[b * NM + m] * ND + lane];
    if (layer) {
      hd += E[(size_t)h_idx[NBM + b * NM + m] * ND + lane];
      pd *= R[(size_t)r_idx[NBM + b * NM + m] * ND + lane];
    }
    float td = E[(size_t)t_idx[(size_t)layer * NBM + b * NM + m] * ND + lane];
    hv[mi] = hd; pv[mi] = pd; tv[mi] = td;
    regA[m * RS + lane] = f2bf(hd);
    regA[OFF_P + m * RS + lane] = f2bf(pd);
    regA[OFF_T + m * RS + lane] = f2bf(td);
  }
  __syncthreads();

  // P1: 5 dot families for this wave's 16 m via MFMA diagonals
  {
    const int fr = m0 + colq;
    const ushort* pH = &regA[fr * RS + quad * 8];
    const ushort* pP = &regA[OFF_P + fr * RS + quad * 8];
    const ushort* pT = &regA[OFF_T + fr * RS + quad * 8];
    short8 h0 = *(const short8*)pH, h1 = *(const short8*)(pH + 32);
    short8 p0 = *(const short8*)pP, p1 = *(const short8*)(pP + 32);
    short8 t0 = *(const short8*)pT, t1 = *(const short8*)(pT + 32);
    const bool dsel = (quad == (colq >> 2));
    const int dr = colq & 3;
#define DIAG_DOT(q, A0, A1, B0, B1)                                         \
    {                                                                        \
      float4v c = {0.f, 0.f, 0.f, 0.f};                                      \
      c = __builtin_amdgcn_mfma_f32_16x16x32_bf16(A0, B0, c, 0, 0, 0);       \
      c = __builtin_amdgcn_mfma_f32_16x16x32_bf16(A1, B1, c, 0, 0, 0);       \
      float dv = (dr & 2) ? ((dr & 1) ? c[3] : c[2])                         \
                          : ((dr & 1) ? c[1] : c[0]);                        \
      if (dsel) dots_s[q][m0 + colq] = dv;                                   \
    }
    DIAG_DOT(0, h0, h1, h0, h1)
    DIAG_DOT(1, p0, p1, p0, p1)
    DIAG_DOT(2, t0, t1, t0, t1)
    DIAG_DOT(3, h0, h1, t0, t1)
    DIAG_DOT(4, h0, h1, p0, p1)
#undef DIAG_DOT
  }
  __syncthreads();

  // P2: geometry, lane-parallel (lane = m); coefs stay in own lane's regs
  float g_ch, g_e1, g_e2, g_gh, g_q1, g_q2, g_hts2;
  {
    const int mm = lane;
    float sh = dots_s[0][mm], sp = dots_s[1][mm], st = dots_s[2][mm];
    float sht = dots_s[3][mm], shp = dots_s[4][mm];
    float rih = rcpf(fmaxf(sqf(sh), 1e-12f));
    float rip = rcpf(fmaxf(sqf(sp), 1e-12f));
    float rit = rcpf(fmaxf(sqf(st), 1e-12f));
    float nh = sqf(fmaxf(sh * rih * rih, 1e-15f));
    float ch = fast_tanh(nh) * rcpf(nh) * rih * cabs;   // hh = ch*h_raw
    float p2 = ch * ch * sh;
    float lam = 2.f * rcpf(fmaxf(1.f - p2, 1e-15f));
    float ntn = sqf(fmaxf(st * rit * rit, 1e-15f));
    float ct = fast_tanh(0.5f * lam * ntn) * rcpf(ntn) * rit;
    float y2 = ct * ct * st, xy = ch * ct * sht;
    float At = 1.f + 2.f * xy + y2, Bt = 1.f - p2;
    float rdt = rcpf(fmaxf(1.f + 2.f * xy + p2 * y2, 1e-15f));
    g_e1 = At * ch * rdt;
    g_e2 = Bt * ct * rdt;
    g_hts2 = g_e1 * g_e1 * sh + 2.f * g_e1 * g_e2 * sht + g_e2 * g_e2 * st;
    float npn = sqf(fmaxf(sp * rip * rip, 1e-15f));
    float cp = fast_tanh(0.5f * lam * npn) * rcpf(npn) * rip;
    float z2 = cp * cp * sp, xz = ch * cp * shp;
    float Ar = 1.f + 2.f * xz + z2;
    float rdr = rcpf(fmaxf(1.f + 2.f * xz + p2 * z2, 1e-15f));
    float f1 = Ar * ch * rdr, f2 = Bt * cp * rdr;       // hr = f1*h + f2*p
    float hr2 = f1 * f1 * sh + 2.f * f1 * f2 * shp + f2 * f2 * sp;
    float n128 = sqf(fmaxf(p2 + hr2, 1e-15f));
    float fq = artanh_clip(n128) * rcpf(n128);
    g_ch = ch;
    g_gh = fq * ch;
    g_q1 = fq * f1;
    g_q2 = fq * f2;
  }

  // P3: rebuild tang rows (xt, bf16) + ht rows (regs + bf16 Hts)
#pragma unroll
  for (int mi = 0; mi < 16; ++mi) {
    const int m = m0 + mi;
    float ghm = readlane_f(g_gh, m);
    float q1m = readlane_f(g_q1, m);
    float q2m = readlane_f(g_q2, m);
    float e1m = readlane_f(g_e1, m);
    float e2m = readlane_f(g_e2, m);
    regA[m * XS + lane] = f2bf(ghm * hv[mi]);
    regA[m * XS + 64 + lane] = f2bf(q1m * hv[mi] + q2m * pv[mi]);
    float htd = e1m * hv[mi] + e2m * tv[mi];
    ht_r[mi] = htd;
    regA[OFF_HT + m * RS + lane] = f2bf(htd);
  }
  __syncthreads();

  // P4: MFMA attention MLP on xt
  {
    short8 afr[4];
#pragma unroll
    for (int kt = 0; kt < 4; ++kt)
      afr[kt] = *(const short8*)&regA[(m0 + colq) * XS + kt * 32 + quad * 8];
    float b1v[4], w2v[4];
#pragma unroll
    for (int nt = 0; nt < 4; ++nt) {
      b1v[nt] = b1[nt * 16 + colq];
      w2v[nt] = w2[nt * 16 + colq];
    }
    float cc[4][4];
#pragma unroll
    for (int nt = 0; nt < 4; ++nt) {
      float4v c = {0.f, 0.f, 0.f, 0.f};
#pragma unroll
      for (int kt = 0; kt < 4; ++kt) {
        short8 bfr = *(const short8*)&w1p[(((kt << 2) | nt) * 64 + lane) * 8];
        c = __builtin_amdgcn_mfma_f32_16x16x32_bf16(afr[kt], bfr, c, 0, 0, 0);
      }
#pragma unroll
      for (int i = 0; i < 4; ++i) cc[nt][i] = c[i];
    }
    float b2v = b2[0];
    float sred[4];
#pragma unroll
    for (int i = 0; i < 4; ++i)
      sred[i] = fmaxf(cc[0][i] + b1v[0], 0.f) * w2v[0] +
                fmaxf(cc[1][i] + b1v[1], 0.f) * w2v[1] +
                fmaxf(cc[2][i] + b1v[2], 0.f) * w2v[2] +
                fmaxf(cc[3][i] + b1v[3], 0.f) * w2v[3];
#pragma unroll
    for (int o = 8; o > 0; o >>= 1) {
#pragma unroll
      for (int i = 0; i < 4; ++i) sred[i] += __shfl_xor(sred[i], o, 64);
    }
    if (colq == 0) {
#pragma unroll
      for (int i = 0; i < 4; ++i)
        a_s[m0 + quad * 4 + i] = fast_tanh(sred[i] + b2v);
    }
  }
  __syncthreads();
  if (wave == 0) {
    float v = a_s[lane];
    float mx = wmax(v);
    float e = __expf(v - mx);
    float ssum = wsum(e);
    w_s[lane] = e / ssum;
  }
  __syncthreads();

  // P5: mean_pt = sum_m w[m]*ch[m]*h_raw[m]
  float mp = 0.f;
#pragma unroll
  for (int mi = 0; mi < 16; ++mi) {
    const int m = m0 + mi;
    mp = fmaf(w_s[m] * readlane_f(g_ch, m), hv[mi], mp);
  }
  part[wave][lane] = mp;
  __syncthreads();
  if (wave == 0) {
    float v = part[0][lane] + part[1][lane] + part[2][lane] + part[3][lane];
    meanpt_s[lane] = v;
    float p2m = wsum(v * v);
    if (lane == 0) scal = p2m;
  }
  __syncthreads();

  // P6: dp[m] = meanpt . ht[m] via MFMA (B = meanpt broadcast); write to a_s
  {
    const ushort* pA = &regA[OFF_HT + (m0 + colq) * RS + quad * 8];
    short8 a0 = *(const short8*)pA, a1 = *(const short8*)(pA + 32);
    short8 bm0, bm1;
#pragma unroll
    for (int j = 0; j < 8; ++j) {
      bm0[j] = (short)f2bf(meanpt_s[quad * 8 + j]);
      bm1[j] = (short)f2bf(meanpt_s[32 + quad * 8 + j]);
    }
    float4v c = {0.f, 0.f, 0.f, 0.f};
    c = __builtin_amdgcn_mfma_f32_16x16x32_bf16(a0, bm0, c, 0, 0, 0);
    c = __builtin_amdgcn_mfma_f32_16x16x32_bf16(a1, bm1, c, 0, 0, 0);
    if (colq == 0) {
#pragma unroll
      for (int i = 0; i < 4; ++i) a_s[m0 + quad * 4 + i] = c[i];
    }
  }
  __syncthreads();

  // P7: logmap scalars lane-parallel, then per-wave accumulation
  const float p2m = scal;
  const float be = fmaxf(1.f - p2m, 1e-15f);
  float g1, g2;
  {
    const int mm = lane;
    float dpm = a_s[mm];
    float wm = w_s[mm];
    float y2 = wm * wm * g_hts2;
    float xy = -wm * dpm;
    float al = 1.f + 2.f * xy + y2;
    float rd = rcpf(fmaxf(1.f + 2.f * xy + p2m * y2, 1e-15f));
    float md2 = (al * al * p2m - 2.f * al * be * wm * dpm + be * be * y2) * rd * rd;
    float n = sqf(fmaxf(md2, 1e-15f));
    float sm = be * artanh_clip(n) * rcpf(n) * rd;
    g1 = wm * wm * sm * be;
    g2 = wm * sm * al;
  }
  float ovec = 0.f, cA = 0.f;
#pragma unroll
  for (int mi = 0; mi < 16; ++mi) {
    const int m = m0 + mi;
    ovec = fmaf(readlane_f(g1, m), ht_r[mi], ovec);
    cA += readlane_f(g2, m);
  }
  part[wave][lane] = ovec - cA * meanpt_s[lane];
  __syncthreads();
  if (wave == 0)
    out[(size_t)b * ND + lane] = part[0][lane] + part[1][lane] + part[2][lane] + part[3][lane];
}

// ---------------- l2-normalize + bf16 cast (for MFMA lse) ----------------
__global__ __launch_bounds__(256) void l2bf_kernel(
    const float* __restrict__ in, __hip_bfloat16* __restrict__ out) {
  int row = blockIdx.x * 4 + (threadIdx.x >> 6);
  int lane = threadIdx.x & 63;
  size_t off = (size_t)blockIdx.y * STACK + (size_t)row * ND + lane;
  float v = in[off];
  float s = wsum(v * v);
  out[off] = __float2bfloat16(v / fmaxf(sqrtf(s), 1e-12f));
}

// ---------------- positive-pair dots (inline-normalized, fp32) ----------------
__global__ __launch_bounds__(256) void pos_kernel(
    const float* __restrict__ stacks, float* __restrict__ pos) {
  int row = blockIdx.x * 4 + (threadIdx.x >> 6);
  int lane = threadIdx.x & 63;
  int sa = blockIdx.y;
  int sb = sa + 2;
  float a = stacks[(size_t)sa * STACK + (size_t)row * ND + lane];
  float c = stacks[(size_t)sb * STACK + (size_t)row * ND + lane];
  float q0 = a * a, q1 = c * c, q2 = a * c;
#pragma unroll
  for (int o = 32; o > 0; o >>= 1) {
    q0 += __shfl_xor(q0, o, 64);
    q1 += __shfl_xor(q1, o, 64);
    q2 += __shfl_xor(q2, o, 64);
  }
  if (lane == 0)
    pos[blockIdx.y * NROWS + row] =
        q2 / (fmaxf(sqrtf(q0), 1e-12f) * fmaxf(sqrtf(q1), 1e-12f));
}

// ---------------- contrastive denominators via MFMA ----------------
__global__ __launch_bounds__(256) void lse_mfma_kernel(
    const ushort* __restrict__ nbf, float* __restrict__ Spart) {
  const int tid = threadIdx.x;
  const int wave = tid >> 6, lane = tid & 63;
  const int pair = blockIdx.y;
  const int half = blockIdx.z;
  int xi = (pair & 2) ? ((pair & 1) ? 3 : 1) : ((pair & 1) ? 2 : 0);
  int yi = xi ^ 2;
  const ushort* X = nbf + (size_t)xi * STACK;
  const ushort* Y = nbf + (size_t)yi * STACK;
  const int r0 = blockIdx.x * 64 + wave * 16;
  const int row = lane & 15, quad = lane >> 4;

  short8 a0 = *(const short8*)&X[(size_t)(r0 + row) * 64 + quad * 8];
  short8 a1 = *(const short8*)&X[(size_t)(r0 + row) * 64 + 32 + quad * 8];

  float rsum[4] = {0.f, 0.f, 0.f, 0.f};
  const int c0 = half * 3072;
  for (int ct = 0; ct < 48; ++ct) {
    const int cbase = c0 + ct * 64;
#pragma unroll
    for (int nt = 0; nt < 4; ++nt) {
      const ushort* yrow = &Y[(size_t)(cbase + nt * 16 + row) * 64 + quad * 8];
      short8 b0 = *(const short8*)yrow;
      short8 b1 = *(const short8*)(yrow + 32);
      float4v c = {0.f, 0.f, 0.f, 0.f};
      c = __builtin_amdgcn_mfma_f32_16x16x32_bf16(a0, b0, c, 0, 0, 0);
      c = __builtin_amdgcn_mfma_f32_16x16x32_bf16(a1, b1, c, 0, 0, 0);
#pragma unroll
      for (int i = 0; i < 4; ++i) rsum[i] += __expf(c[i] * 5.f);
    }
  }
#pragma unroll
  for (int i = 0; i < 4; ++i) {
    float v = rsum[i];
    v += __shfl_xor(v, 1, 64);
    v += __shfl_xor(v, 2, 64);
    v += __shfl_xor(v, 4, 64);
    v += __shfl_xor(v, 8, 64);
    if (row == 0)
      Spart[((size_t)half * 4 + pair) * NROWS + r0 + quad * 4 + i] = v;
  }
}

// ---------------- scores ----------------
__global__ __launch_bounds__(256) void scores_kernel(
    const float* __restrict__ stacks, float* __restrict__ out) {
  int b = blockIdx.x * 4 + (threadIdx.x >> 6);
  int lane = threadIdx.x & 63;
  float s = 0.f;
#pragma unroll
  for (int l = 0; l < 3; ++l) {
    size_t o = (size_t)l * NB * ND + (size_t)b * ND + lane;
    s += stacks[0 * (size_t)STACK + o] * stacks[3 * (size_t)STACK + o]
       + stacks[2 * (size_t)STACK + o] * stacks[1 * (size_t)STACK + o];
  }
  s = wsum(s);
  if (lane == 0) out[b] = 1.f / (1.f + __expf(-s));
}

// ---------------- final loss ----------------
__global__ __launch_bounds__(256) void loss_kernel(
    const float* __restrict__ Spart, const float* __restrict__ pos,
    float* __restrict__ out) {
  __shared__ double red[256];
  double acc = 0.0;
  for (int i = threadIdx.x; i < 4 * NROWS; i += 256)
    acc += (double)logf(Spart[i] + Spart[4 * NROWS + i]);
  for (int i = threadIdx.x; i < 2 * NROWS; i += 256) acc -= 10.0 * (double)pos[i];
  red[threadIdx.x] = acc;
  __syncthreads();
  for (int s = 128; s > 0; s >>= 1) {
    if (threadIdx.x < s) red[threadIdx.x] += red[threadIdx.x + s];
    __syncthreads();
  }
  if (threadIdx.x == 0) out[NB] = (float)(1e-6 * red[0]);
}

extern "C" void kernel_launch(void* const* d_in, const int* in_sizes, int n_in,
                              void* d_out, int out_size, void* d_ws, size_t ws_size,
                              hipStream_t stream) {
  const int* items = (const int*)d_in[0];
  const int* ucf_h = (const int*)d_in[1];
  const int* ucf_r = (const int*)d_in[2];
  const int* ucf_t = (const int*)d_in[3];
  const int* ikg_h = (const int*)d_in[4];
  const int* ikg_r = (const int*)d_in[5];
  const int* ikg_t = (const int*)d_in[6];
  const int* ukg_h = (const int*)d_in[7];
  const int* ukg_r = (const int*)d_in[8];
  const int* ukg_t = (const int*)d_in[9];
  const int* icf_h = (const int*)d_in[10];
  const int* icf_r = (const int*)d_in[11];
  const int* icf_t = (const int*)d_in[12];
  const float* E = (const float*)d_in[13];
  const float* R = (const float*)d_in[14];
  const float* att_w1 = (const float*)d_in[15];
  const float* att_w2 = (const float*)d_in[16];
  const float* a2_w1 = (const float*)d_in[17];
  const float* a2_b1 = (const float*)d_in[18];
  const float* a2_w2 = (const float*)d_in[19];
  const float* a2_b2 = (const float*)d_in[20];
  const float* curv = (const float*)d_in[21];
  float* outp = (float*)d_out;

  float* ws = (float*)d_ws;
  float* stacks = ws;                                   // 4*STACK f32
  float* Spart = stacks + 4 * (size_t)STACK;            // 8*NROWS f32
  float* posarr = Spart + 8 * (size_t)NROWS;            // 2*NROWS f32
  __hip_bfloat16* nbf = (__hip_bfloat16*)(posarr + 2 * (size_t)NROWS);  // 4*STACK bf16
  ushort* w1p_ed = (ushort*)(nbf + 4 * (size_t)STACK);  // 8192 ushort
  ushort* w1p_hy = w1p_ed + 8192;                       // 8192 ushort

  float* ucf = stacks + 0 * (size_t)STACK;
  float* ikg = stacks + 1 * (size_t)STACK;
  float* ukg = stacks + 2 * (size_t)STACK;
  float* icf = stacks + 3 * (size_t)STACK;

  const size_t L = (size_t)NB * ND;

  pack_w1_kernel<<<32, 256, 0, stream>>>(att_w1, w1p_ed);
  pack_w1_kernel<<<32, 256, 0, stream>>>(a2_w1, w1p_hy);

  init_mean_kernel<<<NB, 64, 0, stream>>>(E, ucf_h, ucf);
  init_item_kernel<<<NB, 64, 0, stream>>>(E, items, ikg);
  init_mean_kernel<<<NB, 64, 0, stream>>>(E, ukg_h, ukg);
  init_mean_kernel<<<NB, 64, 0, stream>>>(E, icf_h, icf);

  ed_agg_kernel<<<NB, 256, 0, stream>>>(E, R, ucf_h, ucf_r, ucf_t, 0, w1p_ed, att_w2, ucf + 1 * L);
  ed_agg_kernel<<<NB, 256, 0, stream>>>(E, R, ucf_h, ucf_r, ucf_t, 1, w1p_ed, att_w2, ucf + 2 * L);
  ed_agg_kernel<<<NB, 256, 0, stream>>>(E, R, ikg_h, ikg_r, ikg_t, 0, w1p_ed, att_w2, ikg + 1 * L);
  ed_agg_kernel<<<NB, 256, 0, stream>>>(E, R, ikg_h, ikg_r, ikg_t, 1, w1p_ed, att_w2, ikg + 2 * L);
  hyper_agg_kernel<<<NB, 256, 0, stream>>>(E, R, ukg_h, ukg_r, ukg_t, 0, w1p_hy, a2_b1, a2_w2, a2_b2, curv, ukg + 1 * L);
  hyper_agg_kernel<<<NB, 256, 0, stream>>>(E, R, ukg_h, ukg_r, ukg_t, 1, w1p_hy, a2_b1, a2_w2, a2_b2, curv, ukg + 2 * L);
  hyper_agg_kernel<<<NB, 256, 0, stream>>>(E, R, icf_h, icf_r, icf_t, 0, w1p_hy, a2_b1, a2_w2, a2_b2, curv, icf + 1 * L);
  hyper_agg_kernel<<<NB, 256, 0, stream>>>(E, R, icf_h, icf_r, icf_t, 1, w1p_hy, a2_b1, a2_w2, a2_b2, curv, icf + 2 * L);

  l2bf_kernel<<<dim3(NROWS / 4, 4), 256, 0, stream>>>(stacks, nbf);
  pos_kernel<<<dim3(NROWS / 4, 2), 256, 0, stream>>>(stacks, posarr);
  lse_mfma_kernel<<<dim3(NROWS / 64, 4, 2), 256, 0, stream>>>((const ushort*)nbf, Spart);

  scores_kernel<<<NB / 4, 256, 0, stream>>>(stacks, outp);
  loss_kernel<<<1, 256, 0, stream>>>(Spart, posarr, outp);
}

// Round 5
// 545.222 us; speedup vs baseline: 3.8129x; 1.0908x over previous
//
#include <hip/hip_runtime.h>
#include <hip/hip_bf16.h>
#include <cstdint>
#include <cstddef>

// Problem constants (match reference)
constexpr int NB = 2048;            // batch
constexpr int NM = 64;              // neighbors M
constexpr int ND = 64;              // dim
constexpr int NBM = NB * NM;        // 131072 (one layer of an index tensor)
constexpr int NROWS = 3 * NB;       // 6144 rows per stack (L+1 = 3)
constexpr int STACK = 3 * NB * ND;  // 393216 floats per stack
constexpr int NZ = 8;               // lse column splits

typedef __attribute__((ext_vector_type(8))) short short8;
typedef __attribute__((ext_vector_type(4))) float float4v;

__device__ __forceinline__ float wsum(float v) {
#pragma unroll
  for (int o = 32; o > 0; o >>= 1) v += __shfl_xor(v, o, 64);
  return v;
}

__device__ __forceinline__ float wmax(float v) {
#pragma unroll
  for (int o = 32; o > 0; o >>= 1) v = fmaxf(v, __shfl_xor(v, o, 64));
  return v;
}

__device__ __forceinline__ float rcpf(float x) { return __builtin_amdgcn_rcpf(x); }
__device__ __forceinline__ float sqf(float x) { return __builtin_amdgcn_sqrtf(x); }

__device__ __forceinline__ float fast_tanh(float x) {
  float t = __expf(2.f * x);
  return (t - 1.f) * rcpf(t + 1.f);
}

// artanh(clip(x, -1+1e-5, 1-1e-5))
__device__ __forceinline__ float artanh_clip(float x) {
  x = fminf(fmaxf(x, -1.f + 1e-5f), 1.f - 1e-5f);
  return 0.5f * __logf((1.f + x) * rcpf(1.f - x));
}

// fp32 -> bf16 (RNE), as raw ushort
__device__ __forceinline__ ushort f2bf(float f) {
  uint u = __float_as_uint(f);
  return (ushort)((u + 0x7FFFu + ((u >> 16) & 1u)) >> 16);
}
__device__ __forceinline__ float bf2f(ushort u) {
  return __uint_as_float((uint)u << 16);
}

// broadcast a float from lane l (wave-uniform l)
__device__ __forceinline__ float readlane_f(float v, int l) {
  return __int_as_float(__builtin_amdgcn_readlane(__float_as_int(v), l));
}

// ---------------- W1 pre-pack into MFMA B-fragment layout ----------------
__global__ __launch_bounds__(256) void pack_w1_kernel(
    const float* __restrict__ w1, ushort* __restrict__ out) {
  int e = blockIdx.x * 256 + threadIdx.x;   // 8192 elements, grid 32
  if (e >= 8192) return;
  int j = e & 7, ln = (e >> 3) & 63, nt = (e >> 9) & 3, kt = e >> 11;
  int n = nt * 16 + (ln & 15), k = kt * 32 + ((ln >> 4) << 3) + j;
  out[e] = f2bf(w1[k * 64 + n]);
}

// ---------------- layer-0 init (item rows only; means fused into aggs) ----
__global__ __launch_bounds__(64) void init_item_kernel(
    const float* __restrict__ E, const int* __restrict__ idx, float* __restrict__ out) {
  int b = blockIdx.x, lane = threadIdx.x;
  out[(size_t)b * ND + lane] = E[(size_t)idx[b] * ND + lane];
}

// ---------------- Euclidean attention agg (ucf / ikg) ----------------
// layer==0 launches may pass init_out to fuse the init-mean (mean over m of h).
__global__ __launch_bounds__(256) void ed_agg_kernel(
    const float* __restrict__ E, const float* __restrict__ R,
    const int* __restrict__ h_idx, const int* __restrict__ r_idx,
    const int* __restrict__ t_idx, int layer,
    const ushort* __restrict__ w1p, const float* __restrict__ w2,
    float* __restrict__ out, float* __restrict__ init_out) {
  __shared__ __align__(16) __hip_bfloat16 xt[64][136];
  __shared__ float a_s[64];
  __shared__ float w_s[64];
  __shared__ float part[4][64];

  const int b = blockIdx.x;
  const int tid = threadIdx.x;
  const int wave = tid >> 6, lane = tid & 63;

  float macc = 0.f;
  for (int m = wave; m < NM; m += 4) {
    float hd = E[(size_t)h_idx[b * NM + m] * ND + lane];
    float pd = R[(size_t)r_idx[b * NM + m] * ND + lane];
    if (layer) {
      hd += E[(size_t)h_idx[NBM + b * NM + m] * ND + lane];
      pd *= R[(size_t)r_idx[NBM + b * NM + m] * ND + lane];
    }
    if (init_out) macc += hd;
    xt[m][lane] = __float2bfloat16(hd);
    xt[m][64 + lane] = __float2bfloat16(pd);
  }
  if (init_out) part[wave][lane] = macc;
  __syncthreads();
  if (init_out && wave == 0)
    init_out[(size_t)b * ND + lane] =
        (part[0][lane] + part[1][lane] + part[2][lane] + part[3][lane]) * (1.f / 64.f);

  const int colq = lane & 15, quad = lane >> 4;
  short8 afr[4];
#pragma unroll
  for (int kt = 0; kt < 4; ++kt)
    afr[kt] = *(const short8*)&xt[wave * 16 + colq][kt * 32 + quad * 8];
  float w2v[4];
#pragma unroll
  for (int nt = 0; nt < 4; ++nt) w2v[nt] = w2[nt * 16 + colq];
  float cc[4][4];
#pragma unroll
  for (int nt = 0; nt < 4; ++nt) {
    float4v c = {0.f, 0.f, 0.f, 0.f};
#pragma unroll
    for (int kt = 0; kt < 4; ++kt) {
      short8 bfr = *(const short8*)&w1p[(((kt << 2) | nt) * 64 + lane) * 8];
      c = __builtin_amdgcn_mfma_f32_16x16x32_bf16(afr[kt], bfr, c, 0, 0, 0);
    }
#pragma unroll
    for (int i = 0; i < 4; ++i) cc[nt][i] = c[i];
  }
  float sred[4];
#pragma unroll
  for (int i = 0; i < 4; ++i)
    sred[i] = fmaxf(cc[0][i], 0.f) * w2v[0] + fmaxf(cc[1][i], 0.f) * w2v[1] +
              fmaxf(cc[2][i], 0.f) * w2v[2] + fmaxf(cc[3][i], 0.f) * w2v[3];
#pragma unroll
  for (int o = 8; o > 0; o >>= 1) {
#pragma unroll
    for (int i = 0; i < 4; ++i) sred[i] += __shfl_xor(sred[i], o, 64);
  }
  if (colq == 0) {
#pragma unroll
    for (int i = 0; i < 4; ++i)
      a_s[wave * 16 + quad * 4 + i] = 1.f / (1.f + __expf(-sred[i]));
  }
  __syncthreads();
  if (wave == 0) {
    float v = a_s[lane];
    float mx = wmax(v);
    float e = __expf(v - mx);
    float ssum = wsum(e);
    w_s[lane] = e / ssum;
  }
  __syncthreads();
  float o = 0.f;
  for (int m = wave; m < NM; m += 4)
    o = fmaf(w_s[m], E[(size_t)t_idx[(size_t)layer * NBM + b * NM + m] * ND + lane], o);
  part[wave][lane] = o;
  __syncthreads();
  if (wave == 0)
    out[(size_t)b * ND + lane] = part[0][lane] + part[1][lane] + part[2][lane] + part[3][lane];
}

// ---------------- Hyperbolic attention agg (ukg / icf), v4 ----------------
// LDS regions (ushort elems):
//   phases 0-3a: T [0,4608) s72 | P [4608,9216) s72 | H [9216,13824) s72
//   phases 3b+ : xt [0,9728) s152 | Hts [9728,14336) s72
// t/p re-read from LDS (packed regs) before xt overwrite; ht re-read in P7.
constexpr int OFF_T2 = 0;
constexpr int OFF_P2 = 64 * 72;        // 4608
constexpr int OFF_H2 = 2 * 64 * 72;    // 9216
constexpr int XS = 152;                // xt stride
constexpr int OFF_HTS = 64 * XS;       // 9728
constexpr int REGA_SZ = OFF_HTS + 64 * 72;  // 14336 elems = 28672 B

__global__ __launch_bounds__(256) void hyper_agg_kernel(
    const float* __restrict__ E, const float* __restrict__ R,
    const int* __restrict__ h_idx, const int* __restrict__ r_idx,
    const int* __restrict__ t_idx, int layer,
    const ushort* __restrict__ w1p, const float* __restrict__ b1,
    const float* __restrict__ w2, const float* __restrict__ b2,
    const float* __restrict__ curv, float* __restrict__ out,
    float* __restrict__ init_out) {
  __shared__ __align__(16) ushort regA[REGA_SZ];
  __shared__ float dots_s[5][64];
  __shared__ float a_s[64];
  __shared__ float w_s[64];
  __shared__ float meanpt_s[64];
  __shared__ float part[4][64];
  __shared__ float scal;

  const int b = blockIdx.x;
  const int tid = threadIdx.x;
  const int wave = tid >> 6, lane = tid & 63;
  const int wu = __builtin_amdgcn_readfirstlane(wave);
  const int m0 = wu * 16;
  const int colq = lane & 15, quad = lane >> 4;
  const float cabs = fabsf(*curv);

  float hv[16];

  // P0: gather rows; h kept fp32 in regs; bf16 copies staged for MFMA dots
  float macc = 0.f;
#pragma unroll
  for (int mi = 0; mi < 16; ++mi) {
    const int m = m0 + mi;
    float hd = E[(size_t)h_idx[b * NM + m] * ND + lane];
    float pd = R[(size_t)r_idx[b * NM + m] * ND + lane];
    if (layer) {
      hd += E[(size_t)h_idx[NBM + b * NM + m] * ND + lane];
      pd *= R[(size_t)r_idx[NBM + b * NM + m] * ND + lane];
    }
    float td = E[(size_t)t_idx[(size_t)layer * NBM + b * NM + m] * ND + lane];
    hv[mi] = hd;
    if (init_out) macc += hd;
    regA[OFF_H2 + m * 72 + lane] = f2bf(hd);
    regA[OFF_P2 + m * 72 + lane] = f2bf(pd);
    regA[OFF_T2 + m * 72 + lane] = f2bf(td);
  }
  if (init_out) part[wave][lane] = macc;
  __syncthreads();
  if (init_out && wave == 0)
    init_out[(size_t)b * ND + lane] =
        (part[0][lane] + part[1][lane] + part[2][lane] + part[3][lane]) * (1.f / 64.f);

  // P1: 5 dot families for this wave's 16 m via MFMA diagonals
  {
    const int fr = m0 + colq;
    const ushort* pH = &regA[OFF_H2 + fr * 72 + quad * 8];
    const ushort* pP = &regA[OFF_P2 + fr * 72 + quad * 8];
    const ushort* pT = &regA[OFF_T2 + fr * 72 + quad * 8];
    short8 h0 = *(const short8*)pH, h1 = *(const short8*)(pH + 32);
    short8 p0 = *(const short8*)pP, p1 = *(const short8*)(pP + 32);
    short8 t0 = *(const short8*)pT, t1 = *(const short8*)(pT + 32);
    const bool dsel = (quad == (colq >> 2));
    const int dr = colq & 3;
#define DIAG_DOT(q, A0, A1, B0, B1)                                         \
    {                                                                        \
      float4v c = {0.f, 0.f, 0.f, 0.f};                                      \
      c = __builtin_amdgcn_mfma_f32_16x16x32_bf16(A0, B0, c, 0, 0, 0);       \
      c = __builtin_amdgcn_mfma_f32_16x16x32_bf16(A1, B1, c, 0, 0, 0);       \
      float dv = (dr & 2) ? ((dr & 1) ? c[3] : c[2])                         \
                          : ((dr & 1) ? c[1] : c[0]);                        \
      if (dsel) dots_s[q][m0 + colq] = dv;                                   \
    }
    DIAG_DOT(0, h0, h1, h0, h1)
    DIAG_DOT(1, p0, p1, p0, p1)
    DIAG_DOT(2, t0, t1, t0, t1)
    DIAG_DOT(3, h0, h1, t0, t1)
    DIAG_DOT(4, h0, h1, p0, p1)
#undef DIAG_DOT
  }
  __syncthreads();

  // P2: geometry, lane-parallel (lane = m)
  float g_ch, g_e1, g_e2, g_gh, g_q1, g_q2, g_hts2;
  {
    const int mm = lane;
    float sh = dots_s[0][mm], sp = dots_s[1][mm], st = dots_s[2][mm];
    float sht = dots_s[3][mm], shp = dots_s[4][mm];
    float rih = rcpf(fmaxf(sqf(sh), 1e-12f));
    float rip = rcpf(fmaxf(sqf(sp), 1e-12f));
    float rit = rcpf(fmaxf(sqf(st), 1e-12f));
    float nh = sqf(fmaxf(sh * rih * rih, 1e-15f));
    float ch = fast_tanh(nh) * rcpf(nh) * rih * cabs;   // hh = ch*h_raw
    float p2 = ch * ch * sh;
    float lam = 2.f * rcpf(fmaxf(1.f - p2, 1e-15f));
    float ntn = sqf(fmaxf(st * rit * rit, 1e-15f));
    float ct = fast_tanh(0.5f * lam * ntn) * rcpf(ntn) * rit;
    float y2 = ct * ct * st, xy = ch * ct * sht;
    float At = 1.f + 2.f * xy + y2, Bt = 1.f - p2;
    float rdt = rcpf(fmaxf(1.f + 2.f * xy + p2 * y2, 1e-15f));
    g_e1 = At * ch * rdt;
    g_e2 = Bt * ct * rdt;
    g_hts2 = g_e1 * g_e1 * sh + 2.f * g_e1 * g_e2 * sht + g_e2 * g_e2 * st;
    float npn = sqf(fmaxf(sp * rip * rip, 1e-15f));
    float cp = fast_tanh(0.5f * lam * npn) * rcpf(npn) * rip;
    float z2 = cp * cp * sp, xz = ch * cp * shp;
    float Ar = 1.f + 2.f * xz + z2;
    float rdr = rcpf(fmaxf(1.f + 2.f * xz + p2 * z2, 1e-15f));
    float f1 = Ar * ch * rdr, f2 = Bt * cp * rdr;       // hr = f1*h + f2*p
    float hr2 = f1 * f1 * sh + 2.f * f1 * f2 * shp + f2 * f2 * sp;
    float n128 = sqf(fmaxf(p2 + hr2, 1e-15f));
    float fq = artanh_clip(n128) * rcpf(n128);
    g_ch = ch;
    g_gh = fq * ch;
    g_q1 = fq * f1;
    g_q2 = fq * f2;
  }

  // P3a: re-read own-wave t/p rows (bf16, packed) before xt overwrites them
  uint tp[16];
#pragma unroll
  for (int mi = 0; mi < 16; ++mi) {
    const int m = m0 + mi;
    uint t16 = regA[OFF_T2 + m * 72 + lane];
    uint p16 = regA[OFF_P2 + m * 72 + lane];
    tp[mi] = t16 | (p16 << 16);
  }
  __syncthreads();

  // P3b: write tang rows (xt) + ht rows (Hts)
#pragma unroll
  for (int mi = 0; mi < 16; ++mi) {
    const int m = m0 + mi;
    float tvf = __uint_as_float((tp[mi] & 0xFFFFu) << 16);
    float pvf = __uint_as_float((tp[mi] >> 16) << 16);
    float ghm = readlane_f(g_gh, m);
    float q1m = readlane_f(g_q1, m);
    float q2m = readlane_f(g_q2, m);
    float e1m = readlane_f(g_e1, m);
    float e2m = readlane_f(g_e2, m);
    regA[m * XS + lane] = f2bf(ghm * hv[mi]);
    regA[m * XS + 64 + lane] = f2bf(q1m * hv[mi] + q2m * pvf);
    regA[OFF_HTS + m * 72 + lane] = f2bf(e1m * hv[mi] + e2m * tvf);
  }
  __syncthreads();

  // P4: MFMA attention MLP on xt
  {
    short8 afr[4];
#pragma unroll
    for (int kt = 0; kt < 4; ++kt)
      afr[kt] = *(const short8*)&regA[(m0 + colq) * XS + kt * 32 + quad * 8];
    float b1v[4], w2v[4];
#pragma unroll
    for (int nt = 0; nt < 4; ++nt) {
      b1v[nt] = b1[nt * 16 + colq];
      w2v[nt] = w2[nt * 16 + colq];
    }
    float cc[4][4];
#pragma unroll
    for (int nt = 0; nt < 4; ++nt) {
      float4v c = {0.f, 0.f, 0.f, 0.f};
#pragma unroll
      for (int kt = 0; kt < 4; ++kt) {
        short8 bfr = *(const short8*)&w1p[(((kt << 2) | nt) * 64 + lane) * 8];
        c = __builtin_amdgcn_mfma_f32_16x16x32_bf16(afr[kt], bfr, c, 0, 0, 0);
      }
#pragma unroll
      for (int i = 0; i < 4; ++i) cc[nt][i] = c[i];
    }
    float b2v = b2[0];
    float sred[4];
#pragma unroll
    for (int i = 0; i < 4; ++i)
      sred[i] = fmaxf(cc[0][i] + b1v[0], 0.f) * w2v[0] +
                fmaxf(cc[1][i] + b1v[1], 0.f) * w2v[1] +
                fmaxf(cc[2][i] + b1v[2], 0.f) * w2v[2] +
                fmaxf(cc[3][i] + b1v[3], 0.f) * w2v[3];
#pragma unroll
    for (int o = 8; o > 0; o >>= 1) {
#pragma unroll
      for (int i = 0; i < 4; ++i) sred[i] += __shfl_xor(sred[i], o, 64);
    }
    if (colq == 0) {
#pragma unroll
      for (int i = 0; i < 4; ++i)
        a_s[m0 + quad * 4 + i] = fast_tanh(sred[i] + b2v);
    }
  }
  __syncthreads();
  if (wave == 0) {
    float v = a_s[lane];
    float mx = wmax(v);
    float e = __expf(v - mx);
    float ssum = wsum(e);
    w_s[lane] = e / ssum;
  }
  __syncthreads();

  // P5: mean_pt = sum_m w[m]*ch[m]*h_raw[m]
  float mp = 0.f;
#pragma unroll
  for (int mi = 0; mi < 16; ++mi) {
    const int m = m0 + mi;
    mp = fmaf(w_s[m] * readlane_f(g_ch, m), hv[mi], mp);
  }
  part[wave][lane] = mp;
  __syncthreads();
  if (wave == 0) {
    float v = part[0][lane] + part[1][lane] + part[2][lane] + part[3][lane];
    meanpt_s[lane] = v;
    float p2m = wsum(v * v);
    if (lane == 0) scal = p2m;
  }
  __syncthreads();

  // P6: dp[m] = meanpt . ht[m] via MFMA (B = meanpt broadcast); write to a_s
  {
    const ushort* pA = &regA[OFF_HTS + (m0 + colq) * 72 + quad * 8];
    short8 a0 = *(const short8*)pA, a1 = *(const short8*)(pA + 32);
    short8 bm0, bm1;
#pragma unroll
    for (int j = 0; j < 8; ++j) {
      bm0[j] = (short)f2bf(meanpt_s[quad * 8 + j]);
      bm1[j] = (short)f2bf(meanpt_s[32 + quad * 8 + j]);
    }
    float4v c = {0.f, 0.f, 0.f, 0.f};
    c = __builtin_amdgcn_mfma_f32_16x16x32_bf16(a0, bm0, c, 0, 0, 0);
    c = __builtin_amdgcn_mfma_f32_16x16x32_bf16(a1, bm1, c, 0, 0, 0);
    if (colq == 0) {
#pragma unroll
      for (int i = 0; i < 4; ++i) a_s[m0 + quad * 4 + i] = c[i];
    }
  }
  __syncthreads();

  // P7: logmap scalars lane-parallel, then per-wave accumulation
  const float p2m = scal;
  const float be = fmaxf(1.f - p2m, 1e-15f);
  float g1, g2;
  {
    const int mm = lane;
    float dpm = a_s[mm];
    float wm = w_s[mm];
    float y2 = wm * wm * g_hts2;
    float xy = -wm * dpm;
    float al = 1.f + 2.f * xy + y2;
    float rd = rcpf(fmaxf(1.f + 2.f * xy + p2m * y2, 1e-15f));
    float md2 = (al * al * p2m - 2.f * al * be * wm * dpm + be * be * y2) * rd * rd;
    float n = sqf(fmaxf(md2, 1e-15f));
    float sm = be * artanh_clip(n) * rcpf(n) * rd;
    g1 = wm * wm * sm * be;
    g2 = wm * sm * al;
  }
  float ovec = 0.f, cA = 0.f;
#pragma unroll
  for (int mi = 0; mi < 16; ++mi) {
    const int m = m0 + mi;
    float htf = bf2f(regA[OFF_HTS + m * 72 + lane]);
    ovec = fmaf(readlane_f(g1, m), htf, ovec);
    cA += readlane_f(g2, m);
  }
  part[wave][lane] = ovec - cA * meanpt_s[lane];
  __syncthreads();
  if (wave == 0)
    out[(size_t)b * ND + lane] = part[0][lane] + part[1][lane] + part[2][lane] + part[3][lane];
}

// ---------------- l2-normalize + bf16 cast (for MFMA lse) ----------------
__global__ __launch_bounds__(256) void l2bf_kernel(
    const float* __restrict__ in, __hip_bfloat16* __restrict__ out) {
  int row = blockIdx.x * 4 + (threadIdx.x >> 6);
  int lane = threadIdx.x & 63;
  size_t off = (size_t)blockIdx.y * STACK + (size_t)row * ND + lane;
  float v = in[off];
  float s = wsum(v * v);
  out[off] = __float2bfloat16(v / fmaxf(sqrtf(s), 1e-12f));
}

// ---------------- positive-pair dots (inline-normalized, fp32) ----------------
__global__ __launch_bounds__(256) void pos_kernel(
    const float* __restrict__ stacks, float* __restrict__ pos) {
  int row = blockIdx.x * 4 + (threadIdx.x >> 6);
  int lane = threadIdx.x & 63;
  int sa = blockIdx.y;
  int sb = sa + 2;
  float a = stacks[(size_t)sa * STACK + (size_t)row * ND + lane];
  float c = stacks[(size_t)sb * STACK + (size_t)row * ND + lane];
  float q0 = a * a, q1 = c * c, q2 = a * c;
#pragma unroll
  for (int o = 32; o > 0; o >>= 1) {
    q0 += __shfl_xor(q0, o, 64);
    q1 += __shfl_xor(q1, o, 64);
    q2 += __shfl_xor(q2, o, 64);
  }
  if (lane == 0)
    pos[blockIdx.y * NROWS + row] =
        q2 / (fmaxf(sqrtf(q0), 1e-12f) * fmaxf(sqrtf(q1), 1e-12f));
}

// ---------------- contrastive denominators via MFMA, z-split 8 ----------------
__global__ __launch_bounds__(256) void lse_mfma_kernel(
    const ushort* __restrict__ nbf, float* __restrict__ Spart) {
  const int tid = threadIdx.x;
  const int wave = tid >> 6, lane = tid & 63;
  const int pair = blockIdx.y;
  const int z = blockIdx.z;
  int xi = (pair & 2) ? ((pair & 1) ? 3 : 1) : ((pair & 1) ? 2 : 0);
  int yi = xi ^ 2;
  const ushort* X = nbf + (size_t)xi * STACK;
  const ushort* Y = nbf + (size_t)yi * STACK;
  const int r0 = blockIdx.x * 64 + wave * 16;
  const int row = lane & 15, quad = lane >> 4;

  short8 a0 = *(const short8*)&X[(size_t)(r0 + row) * 64 + quad * 8];
  short8 a1 = *(const short8*)&X[(size_t)(r0 + row) * 64 + 32 + quad * 8];

  float rsum[4] = {0.f, 0.f, 0.f, 0.f};
  const int c0 = z * (NROWS / NZ);
  for (int ct = 0; ct < (NROWS / NZ) / 64; ++ct) {
    const int cbase = c0 + ct * 64;
#pragma unroll
    for (int nt = 0; nt < 4; ++nt) {
      const ushort* yrow = &Y[(size_t)(cbase + nt * 16 + row) * 64 + quad * 8];
      short8 b0 = *(const short8*)yrow;
      short8 b1 = *(const short8*)(yrow + 32);
      float4v c = {0.f, 0.f, 0.f, 0.f};
      c = __builtin_amdgcn_mfma_f32_16x16x32_bf16(a0, b0, c, 0, 0, 0);
      c = __builtin_amdgcn_mfma_f32_16x16x32_bf16(a1, b1, c, 0, 0, 0);
#pragma unroll
      for (int i = 0; i < 4; ++i) rsum[i] += __expf(c[i] * 5.f);
    }
  }
#pragma unroll
  for (int i = 0; i < 4; ++i) {
    float v = rsum[i];
    v += __shfl_xor(v, 1, 64);
    v += __shfl_xor(v, 2, 64);
    v += __shfl_xor(v, 4, 64);
    v += __shfl_xor(v, 8, 64);
    if (row == 0)
      Spart[((size_t)z * 4 + pair) * NROWS + r0 + quad * 4 + i] = v;
  }
}

// ---------------- scores ----------------
__global__ __launch_bounds__(256) void scores_kernel(
    const float* __restrict__ stacks, float* __restrict__ out) {
  int b = blockIdx.x * 4 + (threadIdx.x >> 6);
  int lane = threadIdx.x & 63;
  float s = 0.f;
#pragma unroll
  for (int l = 0; l < 3; ++l) {
    size_t o = (size_t)l * NB * ND + (size_t)b * ND + lane;
    s += stacks[0 * (size_t)STACK + o] * stacks[3 * (size_t)STACK + o]
       + stacks[2 * (size_t)STACK + o] * stacks[1 * (size_t)STACK + o];
  }
  s = wsum(s);
  if (lane == 0) out[b] = 1.f / (1.f + __expf(-s));
}

// ---------------- loss: grid-parallel partials + final reduce ----------------
__global__ __launch_bounds__(256) void loss_part_kernel(
    const float* __restrict__ Spart, const float* __restrict__ pos,
    double* __restrict__ lossp) {
  __shared__ double red[256];
  const int t = threadIdx.x, blk = blockIdx.x;
  double acc = 0.0;
#pragma unroll
  for (int r = 0; r < 2; ++r) {
    int i = blk * 512 + r * 256 + t;   // i in [0, 4*NROWS)
    float s = 0.f;
#pragma unroll
    for (int zz = 0; zz < NZ; ++zz) s += Spart[i + zz * 4 * NROWS];
    acc += (double)__logf(s);
  }
  {
    int j = blk * 256 + t;             // j in [0, 2*NROWS)
    acc -= 10.0 * (double)pos[j];
  }
  red[t] = acc;
  __syncthreads();
  for (int s = 128; s > 0; s >>= 1) {
    if (t < s) red[t] += red[t + s];
    __syncthreads();
  }
  if (t == 0) lossp[blk] = red[0];
}

__global__ __launch_bounds__(64) void loss_final_kernel(
    const double* __restrict__ lossp, float* __restrict__ out) {
  int lane = threadIdx.x;
  double v = (lane < 48) ? lossp[lane] : 0.0;
#pragma unroll
  for (int o = 32; o > 0; o >>= 1) v += __shfl_xor(v, o, 64);
  if (lane == 0) out[NB] = (float)(1e-6 * v);
}

extern "C" void kernel_launch(void* const* d_in, const int* in_sizes, int n_in,
                              void* d_out, int out_size, void* d_ws, size_t ws_size,
                              hipStream_t stream) {
  const int* items = (const int*)d_in[0];
  const int* ucf_h = (const int*)d_in[1];
  const int* ucf_r = (const int*)d_in[2];
  const int* ucf_t = (const int*)d_in[3];
  const int* ikg_h = (const int*)d_in[4];
  const int* ikg_r = (const int*)d_in[5];
  const int* ikg_t = (const int*)d_in[6];
  const int* ukg_h = (const int*)d_in[7];
  const int* ukg_r = (const int*)d_in[8];
  const int* ukg_t = (const int*)d_in[9];
  const int* icf_h = (const int*)d_in[10];
  const int* icf_r = (const int*)d_in[11];
  const int* icf_t = (const int*)d_in[12];
  const float* E = (const float*)d_in[13];
  const float* R = (const float*)d_in[14];
  const float* att_w1 = (const float*)d_in[15];
  const float* att_w2 = (const float*)d_in[16];
  const float* a2_w1 = (const float*)d_in[17];
  const float* a2_b1 = (const float*)d_in[18];
  const float* a2_w2 = (const float*)d_in[19];
  const float* a2_b2 = (const float*)d_in[20];
  const float* curv = (const float*)d_in[21];
  float* outp = (float*)d_out;

  float* ws = (float*)d_ws;
  float* stacks = ws;                                    // 4*STACK f32
  float* Spart = stacks + 4 * (size_t)STACK;             // NZ*4*NROWS f32
  float* posarr = Spart + (size_t)NZ * 4 * NROWS;        // 2*NROWS f32
  __hip_bfloat16* nbf = (__hip_bfloat16*)(posarr + 2 * (size_t)NROWS);  // 4*STACK bf16
  ushort* w1p_ed = (ushort*)(nbf + 4 * (size_t)STACK);   // 8192 ushort
  ushort* w1p_hy = w1p_ed + 8192;                        // 8192 ushort
  double* lossp = (double*)(w1p_hy + 8192);              // 48 doubles

  float* ucf = stacks + 0 * (size_t)STACK;
  float* ikg = stacks + 1 * (size_t)STACK;
  float* ukg = stacks + 2 * (size_t)STACK;
  float* icf = stacks + 3 * (size_t)STACK;

  const size_t L = (size_t)NB * ND;

  pack_w1_kernel<<<32, 256, 0, stream>>>(att_w1, w1p_ed);
  pack_w1_kernel<<<32, 256, 0, stream>>>(a2_w1, w1p_hy);

  init_item_kernel<<<NB, 64, 0, stream>>>(E, items, ikg);

  ed_agg_kernel<<<NB, 256, 0, stream>>>(E, R, ucf_h, ucf_r, ucf_t, 0, w1p_ed, att_w2, ucf + 1 * L, ucf);
  ed_agg_kernel<<<NB, 256, 0, stream>>>(E, R, ucf_h, ucf_r, ucf_t, 1, w1p_ed, att_w2, ucf + 2 * L, nullptr);
  ed_agg_kernel<<<NB, 256, 0, stream>>>(E, R, ikg_h, ikg_r, ikg_t, 0, w1p_ed, att_w2, ikg + 1 * L, nullptr);
  ed_agg_kernel<<<NB, 256, 0, stream>>>(E, R, ikg_h, ikg_r, ikg_t, 1, w1p_ed, att_w2, ikg + 2 * L, nullptr);
  hyper_agg_kernel<<<NB, 256, 0, stream>>>(E, R, ukg_h, ukg_r, ukg_t, 0, w1p_hy, a2_b1, a2_w2, a2_b2, curv, ukg + 1 * L, ukg);
  hyper_agg_kernel<<<NB, 256, 0, stream>>>(E, R, ukg_h, ukg_r, ukg_t, 1, w1p_hy, a2_b1, a2_w2, a2_b2, curv, ukg + 2 * L, nullptr);
  hyper_agg_kernel<<<NB, 256, 0, stream>>>(E, R, icf_h, icf_r, icf_t, 0, w1p_hy, a2_b1, a2_w2, a2_b2, curv, icf + 1 * L, icf);
  hyper_agg_kernel<<<NB, 256, 0, stream>>>(E, R, icf_h, icf_r, icf_t, 1, w1p_hy, a2_b1, a2_w2, a2_b2, curv, icf + 2 * L, nullptr);

  l2bf_kernel<<<dim3(NROWS / 4, 4), 256, 0, stream>>>(stacks, nbf);
  pos_kernel<<<dim3(NROWS / 4, 2), 256, 0, stream>>>(stacks, posarr);
  lse_mfma_kernel<<<dim3(NROWS / 64, 4, NZ), 256, 0, stream>>>((const ushort*)nbf, Spart);

  scores_kernel<<<NB / 4, 256, 0, stream>>>(stacks, outp);
  loss_part_kernel<<<48, 256, 0, stream>>>(Spart, posarr, lossp);
  loss_final_kernel<<<1, 64, 0, stream>>>(lossp, outp);
}

// Round 6
// 459.788 us; speedup vs baseline: 4.5214x; 1.1858x over previous
//
#include <hip/hip_runtime.h>
#include <hip/hip_bf16.h>
#include <cstdint>
#include <cstddef>

// Problem constants (match reference)
constexpr int NB = 2048;            // batch
constexpr int NM = 64;              // neighbors M
constexpr int ND = 64;              // dim
constexpr int NBM = NB * NM;        // 131072 (one layer of an index tensor)
constexpr int NROWS = 3 * NB;       // 6144 rows per stack (L+1 = 3)
constexpr int STACK = 3 * NB * ND;  // 393216 floats per stack
constexpr int NZ = 8;               // lse column splits

typedef __attribute__((ext_vector_type(8))) short short8;
typedef __attribute__((ext_vector_type(4))) float float4v;

__device__ __forceinline__ float wsum(float v) {
#pragma unroll
  for (int o = 32; o > 0; o >>= 1) v += __shfl_xor(v, o, 64);
  return v;
}

__device__ __forceinline__ float wmax(float v) {
#pragma unroll
  for (int o = 32; o > 0; o >>= 1) v = fmaxf(v, __shfl_xor(v, o, 64));
  return v;
}

__device__ __forceinline__ float rcpf(float x) { return __builtin_amdgcn_rcpf(x); }
__device__ __forceinline__ float sqf(float x) { return __builtin_amdgcn_sqrtf(x); }

__device__ __forceinline__ float fast_tanh(float x) {
  float t = __expf(2.f * x);
  return (t - 1.f) * rcpf(t + 1.f);
}

// artanh(clip(x, -1+1e-5, 1-1e-5))
__device__ __forceinline__ float artanh_clip(float x) {
  x = fminf(fmaxf(x, -1.f + 1e-5f), 1.f - 1e-5f);
  return 0.5f * __logf((1.f + x) * rcpf(1.f - x));
}

// fp32 -> bf16 (RNE), as raw ushort
__device__ __forceinline__ ushort f2bf(float f) {
  uint u = __float_as_uint(f);
  return (ushort)((u + 0x7FFFu + ((u >> 16) & 1u)) >> 16);
}
__device__ __forceinline__ float bf2f(ushort u) {
  return __uint_as_float((uint)u << 16);
}

// broadcast a float from lane l (wave-uniform l)
__device__ __forceinline__ float readlane_f(float v, int l) {
  return __int_as_float(__builtin_amdgcn_readlane(__float_as_int(v), l));
}

// ---------------- W1 pre-pack into MFMA B-fragment layout ----------------
__global__ __launch_bounds__(256) void pack_w1_kernel(
    const float* __restrict__ w1, ushort* __restrict__ out) {
  int e = blockIdx.x * 256 + threadIdx.x;   // 8192 elements, grid 32
  if (e >= 8192) return;
  int j = e & 7, ln = (e >> 3) & 63, nt = (e >> 9) & 3, kt = e >> 11;
  int n = nt * 16 + (ln & 15), k = kt * 32 + ((ln >> 4) << 3) + j;
  out[e] = f2bf(w1[k * 64 + n]);
}

// ---------------- layer-0 init (item rows only; means fused into aggs) ----
__global__ __launch_bounds__(64) void init_item_kernel(
    const float* __restrict__ E, const int* __restrict__ idx, float* __restrict__ out) {
  int b = blockIdx.x, lane = threadIdx.x;
  out[(size_t)b * ND + lane] = E[(size_t)idx[b] * ND + lane];
}

// ---------------- Euclidean attention agg (ucf / ikg) ----------------
__global__ __launch_bounds__(256) void ed_agg_kernel(
    const float* __restrict__ E, const float* __restrict__ R,
    const int* __restrict__ h_idx, const int* __restrict__ r_idx,
    const int* __restrict__ t_idx, int layer,
    const ushort* __restrict__ w1p, const float* __restrict__ w2,
    float* __restrict__ out, float* __restrict__ init_out) {
  __shared__ __align__(16) __hip_bfloat16 xt[64][136];
  __shared__ float a_s[64];
  __shared__ float w_s[64];
  __shared__ float part[4][64];

  const int b = blockIdx.x;
  const int tid = threadIdx.x;
  const int wave = tid >> 6, lane = tid & 63;

  float macc = 0.f;
  for (int m = wave; m < NM; m += 4) {
    float hd = E[(size_t)h_idx[b * NM + m] * ND + lane];
    float pd = R[(size_t)r_idx[b * NM + m] * ND + lane];
    if (layer) {
      hd += E[(size_t)h_idx[NBM + b * NM + m] * ND + lane];
      pd *= R[(size_t)r_idx[NBM + b * NM + m] * ND + lane];
    }
    if (init_out) macc += hd;
    xt[m][lane] = __float2bfloat16(hd);
    xt[m][64 + lane] = __float2bfloat16(pd);
  }
  if (init_out) part[wave][lane] = macc;
  __syncthreads();
  if (init_out && wave == 0)
    init_out[(size_t)b * ND + lane] =
        (part[0][lane] + part[1][lane] + part[2][lane] + part[3][lane]) * (1.f / 64.f);

  const int colq = lane & 15, quad = lane >> 4;
  short8 afr[4];
#pragma unroll
  for (int kt = 0; kt < 4; ++kt)
    afr[kt] = *(const short8*)&xt[wave * 16 + colq][kt * 32 + quad * 8];
  float w2v[4];
#pragma unroll
  for (int nt = 0; nt < 4; ++nt) w2v[nt] = w2[nt * 16 + colq];
  float cc[4][4];
#pragma unroll
  for (int nt = 0; nt < 4; ++nt) {
    float4v c = {0.f, 0.f, 0.f, 0.f};
#pragma unroll
    for (int kt = 0; kt < 4; ++kt) {
      short8 bfr = *(const short8*)&w1p[(((kt << 2) | nt) * 64 + lane) * 8];
      c = __builtin_amdgcn_mfma_f32_16x16x32_bf16(afr[kt], bfr, c, 0, 0, 0);
    }
#pragma unroll
    for (int i = 0; i < 4; ++i) cc[nt][i] = c[i];
  }
  float sred[4];
#pragma unroll
  for (int i = 0; i < 4; ++i)
    sred[i] = fmaxf(cc[0][i], 0.f) * w2v[0] + fmaxf(cc[1][i], 0.f) * w2v[1] +
              fmaxf(cc[2][i], 0.f) * w2v[2] + fmaxf(cc[3][i], 0.f) * w2v[3];
#pragma unroll
  for (int o = 8; o > 0; o >>= 1) {
#pragma unroll
    for (int i = 0; i < 4; ++i) sred[i] += __shfl_xor(sred[i], o, 64);
  }
  if (colq == 0) {
#pragma unroll
    for (int i = 0; i < 4; ++i)
      a_s[wave * 16 + quad * 4 + i] = 1.f / (1.f + __expf(-sred[i]));
  }
  __syncthreads();
  if (wave == 0) {
    float v = a_s[lane];
    float mx = wmax(v);
    float e = __expf(v - mx);
    float ssum = wsum(e);
    w_s[lane] = e / ssum;
  }
  __syncthreads();
  float o = 0.f;
  for (int m = wave; m < NM; m += 4)
    o = fmaf(w_s[m], E[(size_t)t_idx[(size_t)layer * NBM + b * NM + m] * ND + lane], o);
  part[wave][lane] = o;
  __syncthreads();
  if (wave == 0)
    out[(size_t)b * ND + lane] = part[0][lane] + part[1][lane] + part[2][lane] + part[3][lane];
}

// ---------------- Hyperbolic attention agg (ukg / icf), v4 ----------------
constexpr int OFF_T2 = 0;
constexpr int OFF_P2 = 64 * 72;        // 4608
constexpr int OFF_H2 = 2 * 64 * 72;    // 9216
constexpr int XS = 152;                // xt stride
constexpr int OFF_HTS = 64 * XS;       // 9728
constexpr int REGA_SZ = OFF_HTS + 64 * 72;  // 14336 elems = 28672 B

__global__ __launch_bounds__(256) void hyper_agg_kernel(
    const float* __restrict__ E, const float* __restrict__ R,
    const int* __restrict__ h_idx, const int* __restrict__ r_idx,
    const int* __restrict__ t_idx, int layer,
    const ushort* __restrict__ w1p, const float* __restrict__ b1,
    const float* __restrict__ w2, const float* __restrict__ b2,
    const float* __restrict__ curv, float* __restrict__ out,
    float* __restrict__ init_out) {
  __shared__ __align__(16) ushort regA[REGA_SZ];
  __shared__ float dots_s[5][64];
  __shared__ float a_s[64];
  __shared__ float w_s[64];
  __shared__ float meanpt_s[64];
  __shared__ float part[4][64];
  __shared__ float scal;

  const int b = blockIdx.x;
  const int tid = threadIdx.x;
  const int wave = tid >> 6, lane = tid & 63;
  const int wu = __builtin_amdgcn_readfirstlane(wave);
  const int m0 = wu * 16;
  const int colq = lane & 15, quad = lane >> 4;
  const float cabs = fabsf(*curv);

  float hv[16];

  // P0: gather rows; h kept fp32 in regs; bf16 copies staged for MFMA dots
  float macc = 0.f;
#pragma unroll
  for (int mi = 0; mi < 16; ++mi) {
    const int m = m0 + mi;
    float hd = E[(size_t)h_idx[b * NM + m] * ND + lane];
    float pd = R[(size_t)r_idx[b * NM + m] * ND + lane];
    if (layer) {
      hd += E[(size_t)h_idx[NBM + b * NM + m] * ND + lane];
      pd *= R[(size_t)r_idx[NBM + b * NM + m] * ND + lane];
    }
    float td = E[(size_t)t_idx[(size_t)layer * NBM + b * NM + m] * ND + lane];
    hv[mi] = hd;
    if (init_out) macc += hd;
    regA[OFF_H2 + m * 72 + lane] = f2bf(hd);
    regA[OFF_P2 + m * 72 + lane] = f2bf(pd);
    regA[OFF_T2 + m * 72 + lane] = f2bf(td);
  }
  if (init_out) part[wave][lane] = macc;
  __syncthreads();
  if (init_out && wave == 0)
    init_out[(size_t)b * ND + lane] =
        (part[0][lane] + part[1][lane] + part[2][lane] + part[3][lane]) * (1.f / 64.f);

  // P1: 5 dot families for this wave's 16 m via MFMA diagonals
  {
    const int fr = m0 + colq;
    const ushort* pH = &regA[OFF_H2 + fr * 72 + quad * 8];
    const ushort* pP = &regA[OFF_P2 + fr * 72 + quad * 8];
    const ushort* pT = &regA[OFF_T2 + fr * 72 + quad * 8];
    short8 h0 = *(const short8*)pH, h1 = *(const short8*)(pH + 32);
    short8 p0 = *(const short8*)pP, p1 = *(const short8*)(pP + 32);
    short8 t0 = *(const short8*)pT, t1 = *(const short8*)(pT + 32);
    const bool dsel = (quad == (colq >> 2));
    const int dr = colq & 3;
#define DIAG_DOT(q, A0, A1, B0, B1)                                         \
    {                                                                        \
      float4v c = {0.f, 0.f, 0.f, 0.f};                                      \
      c = __builtin_amdgcn_mfma_f32_16x16x32_bf16(A0, B0, c, 0, 0, 0);       \
      c = __builtin_amdgcn_mfma_f32_16x16x32_bf16(A1, B1, c, 0, 0, 0);       \
      float dv = (dr & 2) ? ((dr & 1) ? c[3] : c[2])                         \
                          : ((dr & 1) ? c[1] : c[0]);                        \
      if (dsel) dots_s[q][m0 + colq] = dv;                                   \
    }
    DIAG_DOT(0, h0, h1, h0, h1)
    DIAG_DOT(1, p0, p1, p0, p1)
    DIAG_DOT(2, t0, t1, t0, t1)
    DIAG_DOT(3, h0, h1, t0, t1)
    DIAG_DOT(4, h0, h1, p0, p1)
#undef DIAG_DOT
  }
  __syncthreads();

  // P2: geometry, lane-parallel (lane = m)
  float g_ch, g_e1, g_e2, g_gh, g_q1, g_q2, g_hts2;
  {
    const int mm = lane;
    float sh = dots_s[0][mm], sp = dots_s[1][mm], st = dots_s[2][mm];
    float sht = dots_s[3][mm], shp = dots_s[4][mm];
    float rih = rcpf(fmaxf(sqf(sh), 1e-12f));
    float rip = rcpf(fmaxf(sqf(sp), 1e-12f));
    float rit = rcpf(fmaxf(sqf(st), 1e-12f));
    float nh = sqf(fmaxf(sh * rih * rih, 1e-15f));
    float ch = fast_tanh(nh) * rcpf(nh) * rih * cabs;   // hh = ch*h_raw
    float p2 = ch * ch * sh;
    float lam = 2.f * rcpf(fmaxf(1.f - p2, 1e-15f));
    float ntn = sqf(fmaxf(st * rit * rit, 1e-15f));
    float ct = fast_tanh(0.5f * lam * ntn) * rcpf(ntn) * rit;
    float y2 = ct * ct * st, xy = ch * ct * sht;
    float At = 1.f + 2.f * xy + y2, Bt = 1.f - p2;
    float rdt = rcpf(fmaxf(1.f + 2.f * xy + p2 * y2, 1e-15f));
    g_e1 = At * ch * rdt;
    g_e2 = Bt * ct * rdt;
    g_hts2 = g_e1 * g_e1 * sh + 2.f * g_e1 * g_e2 * sht + g_e2 * g_e2 * st;
    float npn = sqf(fmaxf(sp * rip * rip, 1e-15f));
    float cp = fast_tanh(0.5f * lam * npn) * rcpf(npn) * rip;
    float z2 = cp * cp * sp, xz = ch * cp * shp;
    float Ar = 1.f + 2.f * xz + z2;
    float rdr = rcpf(fmaxf(1.f + 2.f * xz + p2 * z2, 1e-15f));
    float f1 = Ar * ch * rdr, f2 = Bt * cp * rdr;       // hr = f1*h + f2*p
    float hr2 = f1 * f1 * sh + 2.f * f1 * f2 * shp + f2 * f2 * sp;
    float n128 = sqf(fmaxf(p2 + hr2, 1e-15f));
    float fq = artanh_clip(n128) * rcpf(n128);
    g_ch = ch;
    g_gh = fq * ch;
    g_q1 = fq * f1;
    g_q2 = fq * f2;
  }

  // P3a: re-read own-wave t/p rows (bf16, packed) before xt overwrites them
  uint tp[16];
#pragma unroll
  for (int mi = 0; mi < 16; ++mi) {
    const int m = m0 + mi;
    uint t16 = regA[OFF_T2 + m * 72 + lane];
    uint p16 = regA[OFF_P2 + m * 72 + lane];
    tp[mi] = t16 | (p16 << 16);
  }
  __syncthreads();

  // P3b: write tang rows (xt) + ht rows (Hts)
#pragma unroll
  for (int mi = 0; mi < 16; ++mi) {
    const int m = m0 + mi;
    float tvf = __uint_as_float((tp[mi] & 0xFFFFu) << 16);
    float pvf = __uint_as_float((tp[mi] >> 16) << 16);
    float ghm = readlane_f(g_gh, m);
    float q1m = readlane_f(g_q1, m);
    float q2m = readlane_f(g_q2, m);
    float e1m = readlane_f(g_e1, m);
    float e2m = readlane_f(g_e2, m);
    regA[m * XS + lane] = f2bf(ghm * hv[mi]);
    regA[m * XS + 64 + lane] = f2bf(q1m * hv[mi] + q2m * pvf);
    regA[OFF_HTS + m * 72 + lane] = f2bf(e1m * hv[mi] + e2m * tvf);
  }
  __syncthreads();

  // P4: MFMA attention MLP on xt
  {
    short8 afr[4];
#pragma unroll
    for (int kt = 0; kt < 4; ++kt)
      afr[kt] = *(const short8*)&regA[(m0 + colq) * XS + kt * 32 + quad * 8];
    float b1v[4], w2v[4];
#pragma unroll
    for (int nt = 0; nt < 4; ++nt) {
      b1v[nt] = b1[nt * 16 + colq];
      w2v[nt] = w2[nt * 16 + colq];
    }
    float cc[4][4];
#pragma unroll
    for (int nt = 0; nt < 4; ++nt) {
      float4v c = {0.f, 0.f, 0.f, 0.f};
#pragma unroll
      for (int kt = 0; kt < 4; ++kt) {
        short8 bfr = *(const short8*)&w1p[(((kt << 2) | nt) * 64 + lane) * 8];
        c = __builtin_amdgcn_mfma_f32_16x16x32_bf16(afr[kt], bfr, c, 0, 0, 0);
      }
#pragma unroll
      for (int i = 0; i < 4; ++i) cc[nt][i] = c[i];
    }
    float b2v = b2[0];
    float sred[4];
#pragma unroll
    for (int i = 0; i < 4; ++i)
      sred[i] = fmaxf(cc[0][i] + b1v[0], 0.f) * w2v[0] +
                fmaxf(cc[1][i] + b1v[1], 0.f) * w2v[1] +
                fmaxf(cc[2][i] + b1v[2], 0.f) * w2v[2] +
                fmaxf(cc[3][i] + b1v[3], 0.f) * w2v[3];
#pragma unroll
    for (int o = 8; o > 0; o >>= 1) {
#pragma unroll
      for (int i = 0; i < 4; ++i) sred[i] += __shfl_xor(sred[i], o, 64);
    }
    if (colq == 0) {
#pragma unroll
      for (int i = 0; i < 4; ++i)
        a_s[m0 + quad * 4 + i] = fast_tanh(sred[i] + b2v);
    }
  }
  __syncthreads();
  if (wave == 0) {
    float v = a_s[lane];
    float mx = wmax(v);
    float e = __expf(v - mx);
    float ssum = wsum(e);
    w_s[lane] = e / ssum;
  }
  __syncthreads();

  // P5: mean_pt = sum_m w[m]*ch[m]*h_raw[m]
  float mp = 0.f;
#pragma unroll
  for (int mi = 0; mi < 16; ++mi) {
    const int m = m0 + mi;
    mp = fmaf(w_s[m] * readlane_f(g_ch, m), hv[mi], mp);
  }
  part[wave][lane] = mp;
  __syncthreads();
  if (wave == 0) {
    float v = part[0][lane] + part[1][lane] + part[2][lane] + part[3][lane];
    meanpt_s[lane] = v;
    float p2m = wsum(v * v);
    if (lane == 0) scal = p2m;
  }
  __syncthreads();

  // P6: dp[m] = meanpt . ht[m] via MFMA (B = meanpt broadcast); write to a_s
  {
    const ushort* pA = &regA[OFF_HTS + (m0 + colq) * 72 + quad * 8];
    short8 a0 = *(const short8*)pA, a1 = *(const short8*)(pA + 32);
    short8 bm0, bm1;
#pragma unroll
    for (int j = 0; j < 8; ++j) {
      bm0[j] = (short)f2bf(meanpt_s[quad * 8 + j]);
      bm1[j] = (short)f2bf(meanpt_s[32 + quad * 8 + j]);
    }
    float4v c = {0.f, 0.f, 0.f, 0.f};
    c = __builtin_amdgcn_mfma_f32_16x16x32_bf16(a0, bm0, c, 0, 0, 0);
    c = __builtin_amdgcn_mfma_f32_16x16x32_bf16(a1, bm1, c, 0, 0, 0);
    if (colq == 0) {
#pragma unroll
      for (int i = 0; i < 4; ++i) a_s[m0 + quad * 4 + i] = c[i];
    }
  }
  __syncthreads();

  // P7: logmap scalars lane-parallel, then per-wave accumulation
  const float p2m = scal;
  const float be = fmaxf(1.f - p2m, 1e-15f);
  float g1, g2;
  {
    const int mm = lane;
    float dpm = a_s[mm];
    float wm = w_s[mm];
    float y2 = wm * wm * g_hts2;
    float xy = -wm * dpm;
    float al = 1.f + 2.f * xy + y2;
    float rd = rcpf(fmaxf(1.f + 2.f * xy + p2m * y2, 1e-15f));
    float md2 = (al * al * p2m - 2.f * al * be * wm * dpm + be * be * y2) * rd * rd;
    float n = sqf(fmaxf(md2, 1e-15f));
    float sm = be * artanh_clip(n) * rcpf(n) * rd;
    g1 = wm * wm * sm * be;
    g2 = wm * sm * al;
  }
  float ovec = 0.f, cA = 0.f;
#pragma unroll
  for (int mi = 0; mi < 16; ++mi) {
    const int m = m0 + mi;
    float htf = bf2f(regA[OFF_HTS + m * 72 + lane]);
    ovec = fmaf(readlane_f(g1, m), htf, ovec);
    cA += readlane_f(g2, m);
  }
  part[wave][lane] = ovec - cA * meanpt_s[lane];
  __syncthreads();
  if (wave == 0)
    out[(size_t)b * ND + lane] = part[0][lane] + part[1][lane] + part[2][lane] + part[3][lane];
}

// ---------------- l2-normalize + bf16 cast (for MFMA lse) ----------------
__global__ __launch_bounds__(256) void l2bf_kernel(
    const float* __restrict__ in, __hip_bfloat16* __restrict__ out) {
  int row = blockIdx.x * 4 + (threadIdx.x >> 6);
  int lane = threadIdx.x & 63;
  size_t off = (size_t)blockIdx.y * STACK + (size_t)row * ND + lane;
  float v = in[off];
  float s = wsum(v * v);
  out[off] = __float2bfloat16(v / fmaxf(sqrtf(s), 1e-12f));
}

// ---------------- positive-pair dots (inline-normalized, fp32) ----------------
__global__ __launch_bounds__(256) void pos_kernel(
    const float* __restrict__ stacks, float* __restrict__ pos) {
  int row = blockIdx.x * 4 + (threadIdx.x >> 6);
  int lane = threadIdx.x & 63;
  int sa = blockIdx.y;
  int sb = sa + 2;
  float a = stacks[(size_t)sa * STACK + (size_t)row * ND + lane];
  float c = stacks[(size_t)sb * STACK + (size_t)row * ND + lane];
  float q0 = a * a, q1 = c * c, q2 = a * c;
#pragma unroll
  for (int o = 32; o > 0; o >>= 1) {
    q0 += __shfl_xor(q0, o, 64);
    q1 += __shfl_xor(q1, o, 64);
    q2 += __shfl_xor(q2, o, 64);
  }
  if (lane == 0)
    pos[blockIdx.y * NROWS + row] =
        q2 / (fmaxf(sqrtf(q0), 1e-12f) * fmaxf(sqrtf(q1), 1e-12f));
}

// ---------------- contrastive denominators via MFMA, LDS-staged Y ----------------
// Y tiles (64 rows x 64 dims, 8 KB contiguous) staged coalesced into padded
// LDS (stride 72 shorts), double-buffered; B-fragments via ds_read_b128.
__global__ __launch_bounds__(256) void lse_mfma_kernel(
    const ushort* __restrict__ nbf, float* __restrict__ Spart) {
  __shared__ __align__(16) ushort ytile[2][64 * 72];   // 36 KB
  const int tid = threadIdx.x;
  const int wave = tid >> 6, lane = tid & 63;
  const int pair = blockIdx.y;
  const int z = blockIdx.z;
  int xi = (pair & 2) ? ((pair & 1) ? 3 : 1) : ((pair & 1) ? 2 : 0);
  int yi = xi ^ 2;
  const ushort* X = nbf + (size_t)xi * STACK;
  const ushort* Y = nbf + (size_t)yi * STACK;
  const int r0 = blockIdx.x * 64 + wave * 16;
  const int row = lane & 15, quad = lane >> 4;

  short8 a0 = *(const short8*)&X[(size_t)(r0 + row) * 64 + quad * 8];
  short8 a1 = *(const short8*)&X[(size_t)(r0 + row) * 64 + 32 + quad * 8];

  // staging: thread t covers bytes [t*32, t*32+32) of the 8 KB tile
  const int srow = tid >> 2, schunk = tid & 3;
  constexpr int NT = (NROWS / NZ) / 64;   // 12 tiles
  const int c0 = z * (NROWS / NZ);
  const ushort* sg = &Y[(size_t)(c0 + srow) * 64 + schunk * 16];
  ushort* sl = &ytile[0][0] + srow * 72 + schunk * 16;

  {
    short8 s0 = *(const short8*)sg;
    short8 s1 = *(const short8*)(sg + 8);
    *(short8*)sl = s0;
    *(short8*)(sl + 8) = s1;
  }
  __syncthreads();

  float rsum[4] = {0.f, 0.f, 0.f, 0.f};
  for (int ct = 0; ct < NT; ++ct) {
    const int cur = ct & 1;
    short8 n0, n1;
    if (ct + 1 < NT) {
      const ushort* src = sg + (size_t)(ct + 1) * 64 * 64;
      n0 = *(const short8*)src;
      n1 = *(const short8*)(src + 8);
    }
#pragma unroll
    for (int nt = 0; nt < 4; ++nt) {
      const ushort* yr = &ytile[cur][(nt * 16 + row) * 72 + quad * 8];
      short8 b0 = *(const short8*)yr;
      short8 b1 = *(const short8*)(yr + 32);
      float4v c = {0.f, 0.f, 0.f, 0.f};
      c = __builtin_amdgcn_mfma_f32_16x16x32_bf16(a0, b0, c, 0, 0, 0);
      c = __builtin_amdgcn_mfma_f32_16x16x32_bf16(a1, b1, c, 0, 0, 0);
#pragma unroll
      for (int i = 0; i < 4; ++i) rsum[i] += __expf(c[i] * 5.f);
    }
    if (ct + 1 < NT) {
      ushort* dst = &ytile[0][0] + ((ct + 1) & 1) * (64 * 72) + srow * 72 + schunk * 16;
      *(short8*)dst = n0;
      *(short8*)(dst + 8) = n1;
      __syncthreads();
    }
  }
#pragma unroll
  for (int i = 0; i < 4; ++i) {
    float v = rsum[i];
    v += __shfl_xor(v, 1, 64);
    v += __shfl_xor(v, 2, 64);
    v += __shfl_xor(v, 4, 64);
    v += __shfl_xor(v, 8, 64);
    if (row == 0)
      Spart[((size_t)z * 4 + pair) * NROWS + r0 + quad * 4 + i] = v;
  }
}

// ---------------- scores ----------------
__global__ __launch_bounds__(256) void scores_kernel(
    const float* __restrict__ stacks, float* __restrict__ out) {
  int b = blockIdx.x * 4 + (threadIdx.x >> 6);
  int lane = threadIdx.x & 63;
  float s = 0.f;
#pragma unroll
  for (int l = 0; l < 3; ++l) {
    size_t o = (size_t)l * NB * ND + (size_t)b * ND + lane;
    s += stacks[0 * (size_t)STACK + o] * stacks[3 * (size_t)STACK + o]
       + stacks[2 * (size_t)STACK + o] * stacks[1 * (size_t)STACK + o];
  }
  s = wsum(s);
  if (lane == 0) out[b] = 1.f / (1.f + __expf(-s));
}

// ---------------- loss: grid-parallel partials + final reduce ----------------
__global__ __launch_bounds__(256) void loss_part_kernel(
    const float* __restrict__ Spart, const float* __restrict__ pos,
    double* __restrict__ lossp) {
  __shared__ double red[256];
  const int t = threadIdx.x, blk = blockIdx.x;
  double acc = 0.0;
#pragma unroll
  for (int r = 0; r < 2; ++r) {
    int i = blk * 512 + r * 256 + t;   // i in [0, 4*NROWS)
    float s = 0.f;
#pragma unroll
    for (int zz = 0; zz < NZ; ++zz) s += Spart[i + zz * 4 * NROWS];
    acc += (double)__logf(s);
  }
  {
    int j = blk * 256 + t;             // j in [0, 2*NROWS)
    acc -= 10.0 * (double)pos[j];
  }
  red[t] = acc;
  __syncthreads();
  for (int s = 128; s > 0; s >>= 1) {
    if (t < s) red[t] += red[t + s];
    __syncthreads();
  }
  if (t == 0) lossp[blk] = red[0];
}

__global__ __launch_bounds__(64) void loss_final_kernel(
    const double* __restrict__ lossp, float* __restrict__ out) {
  int lane = threadIdx.x;
  double v = (lane < 48) ? lossp[lane] : 0.0;
#pragma unroll
  for (int o = 32; o > 0; o >>= 1) v += __shfl_xor(v, o, 64);
  if (lane == 0) out[NB] = (float)(1e-6 * v);
}

extern "C" void kernel_launch(void* const* d_in, const int* in_sizes, int n_in,
                              void* d_out, int out_size, void* d_ws, size_t ws_size,
                              hipStream_t stream) {
  const int* items = (const int*)d_in[0];
  const int* ucf_h = (const int*)d_in[1];
  const int* ucf_r = (const int*)d_in[2];
  const int* ucf_t = (const int*)d_in[3];
  const int* ikg_h = (const int*)d_in[4];
  const int* ikg_r = (const int*)d_in[5];
  const int* ikg_t = (const int*)d_in[6];
  const int* ukg_h = (const int*)d_in[7];
  const int* ukg_r = (const int*)d_in[8];
  const int* ukg_t = (const int*)d_in[9];
  const int* icf_h = (const int*)d_in[10];
  const int* icf_r = (const int*)d_in[11];
  const int* icf_t = (const int*)d_in[12];
  const float* E = (const float*)d_in[13];
  const float* R = (const float*)d_in[14];
  const float* att_w1 = (const float*)d_in[15];
  const float* att_w2 = (const float*)d_in[16];
  const float* a2_w1 = (const float*)d_in[17];
  const float* a2_b1 = (const float*)d_in[18];
  const float* a2_w2 = (const float*)d_in[19];
  const float* a2_b2 = (const float*)d_in[20];
  const float* curv = (const float*)d_in[21];
  float* outp = (float*)d_out;

  float* ws = (float*)d_ws;
  float* stacks = ws;                                    // 4*STACK f32
  float* Spart = stacks + 4 * (size_t)STACK;             // NZ*4*NROWS f32
  float* posarr = Spart + (size_t)NZ * 4 * NROWS;        // 2*NROWS f32
  __hip_bfloat16* nbf = (__hip_bfloat16*)(posarr + 2 * (size_t)NROWS);  // 4*STACK bf16
  ushort* w1p_ed = (ushort*)(nbf + 4 * (size_t)STACK);   // 8192 ushort
  ushort* w1p_hy = w1p_ed + 8192;                        // 8192 ushort
  double* lossp = (double*)(w1p_hy + 8192);              // 48 doubles

  float* ucf = stacks + 0 * (size_t)STACK;
  float* ikg = stacks + 1 * (size_t)STACK;
  float* ukg = stacks + 2 * (size_t)STACK;
  float* icf = stacks + 3 * (size_t)STACK;

  const size_t L = (size_t)NB * ND;

  pack_w1_kernel<<<32, 256, 0, stream>>>(att_w1, w1p_ed);
  pack_w1_kernel<<<32, 256, 0, stream>>>(a2_w1, w1p_hy);

  init_item_kernel<<<NB, 64, 0, stream>>>(E, items, ikg);

  ed_agg_kernel<<<NB, 256, 0, stream>>>(E, R, ucf_h, ucf_r, ucf_t, 0, w1p_ed, att_w2, ucf + 1 * L, ucf);
  ed_agg_kernel<<<NB, 256, 0, stream>>>(E, R, ucf_h, ucf_r, ucf_t, 1, w1p_ed, att_w2, ucf + 2 * L, nullptr);
  ed_agg_kernel<<<NB, 256, 0, stream>>>(E, R, ikg_h, ikg_r, ikg_t, 0, w1p_ed, att_w2, ikg + 1 * L, nullptr);
  ed_agg_kernel<<<NB, 256, 0, stream>>>(E, R, ikg_h, ikg_r, ikg_t, 1, w1p_ed, att_w2, ikg + 2 * L, nullptr);
  hyper_agg_kernel<<<NB, 256, 0, stream>>>(E, R, ukg_h, ukg_r, ukg_t, 0, w1p_hy, a2_b1, a2_w2, a2_b2, curv, ukg + 1 * L, ukg);
  hyper_agg_kernel<<<NB, 256, 0, stream>>>(E, R, ukg_h, ukg_r, ukg_t, 1, w1p_hy, a2_b1, a2_w2, a2_b2, curv, ukg + 2 * L, nullptr);
  hyper_agg_kernel<<<NB, 256, 0, stream>>>(E, R, icf_h, icf_r, icf_t, 0, w1p_hy, a2_b1, a2_w2, a2_b2, curv, icf + 1 * L, icf);
  hyper_agg_kernel<<<NB, 256, 0, stream>>>(E, R, icf_h, icf_r, icf_t, 1, w1p_hy, a2_b1, a2_w2, a2_b2, curv, icf + 2 * L, nullptr);

  l2bf_kernel<<<dim3(NROWS / 4, 4), 256, 0, stream>>>(stacks, nbf);
  pos_kernel<<<dim3(NROWS / 4, 2), 256, 0, stream>>>(stacks, posarr);
  lse_mfma_kernel<<<dim3(NROWS / 64, 4, NZ), 256, 0, stream>>>((const ushort*)nbf, Spart);

  scores_kernel<<<NB / 4, 256, 0, stream>>>(stacks, outp);
  loss_part_kernel<<<48, 256, 0, stream>>>(Spart, posarr, lossp);
  loss_final_kernel<<<1, 64, 0, stream>>>(lossp, outp);
}

// Round 7
// 363.188 us; speedup vs baseline: 5.7240x; 1.2660x over previous
//
#include <hip/hip_runtime.h>
#include <hip/hip_bf16.h>
#include <cstdint>
#include <cstddef>

// Problem constants (match reference)
constexpr int NB = 2048;            // batch
constexpr int NM = 64;              // neighbors M
constexpr int ND = 64;              // dim
constexpr int NBM = NB * NM;        // 131072 (one layer of an index tensor)
constexpr int NROWS = 3 * NB;       // 6144 rows per stack (L+1 = 3)
constexpr int STACK = 3 * NB * ND;  // 393216 floats per stack
constexpr int NZ = 8;               // lse column splits

typedef __attribute__((ext_vector_type(8))) short short8;
typedef __attribute__((ext_vector_type(4))) float float4v;

__device__ __forceinline__ float wsum(float v) {
#pragma unroll
  for (int o = 32; o > 0; o >>= 1) v += __shfl_xor(v, o, 64);
  return v;
}

__device__ __forceinline__ float wmax(float v) {
#pragma unroll
  for (int o = 32; o > 0; o >>= 1) v = fmaxf(v, __shfl_xor(v, o, 64));
  return v;
}

__device__ __forceinline__ float rcpf(float x) { return __builtin_amdgcn_rcpf(x); }
__device__ __forceinline__ float sqf(float x) { return __builtin_amdgcn_sqrtf(x); }

__device__ __forceinline__ float fast_tanh(float x) {
  float t = __expf(2.f * x);
  return (t - 1.f) * rcpf(t + 1.f);
}

// artanh(clip(x, -1+1e-5, 1-1e-5))
__device__ __forceinline__ float artanh_clip(float x) {
  x = fminf(fmaxf(x, -1.f + 1e-5f), 1.f - 1e-5f);
  return 0.5f * __logf((1.f + x) * rcpf(1.f - x));
}

// fp32 -> bf16 (RNE), as raw ushort
__device__ __forceinline__ ushort f2bf(float f) {
  uint u = __float_as_uint(f);
  return (ushort)((u + 0x7FFFu + ((u >> 16) & 1u)) >> 16);
}
__device__ __forceinline__ float bf2f(ushort u) {
  return __uint_as_float((uint)u << 16);
}

// broadcast a float from lane l (wave-uniform l)
__device__ __forceinline__ float readlane_f(float v, int l) {
  return __int_as_float(__builtin_amdgcn_readlane(__float_as_int(v), l));
}

// ---------------- W1 pre-pack into MFMA B-fragment layout ----------------
__global__ __launch_bounds__(256) void pack_w1_kernel(
    const float* __restrict__ w1, ushort* __restrict__ out) {
  int e = blockIdx.x * 256 + threadIdx.x;   // 8192 elements, grid 32
  if (e >= 8192) return;
  int j = e & 7, ln = (e >> 3) & 63, nt = (e >> 9) & 3, kt = e >> 11;
  int n = nt * 16 + (ln & 15), k = kt * 32 + ((ln >> 4) << 3) + j;
  out[e] = f2bf(w1[k * 64 + n]);
}

// ---------------- layer-0 init for ikg (item rows) ----------------
__global__ __launch_bounds__(64) void init_item_kernel(
    const float* __restrict__ E, const int* __restrict__ idx, float* __restrict__ out) {
  int b = blockIdx.x, lane = threadIdx.x;
  out[(size_t)b * ND + lane] = E[(size_t)idx[b] * ND + lane];
}

// ---------------- Euclidean attention agg, BOTH layers fused ----------------
__global__ __launch_bounds__(256) void ed_agg2_kernel(
    const float* __restrict__ E, const float* __restrict__ R,
    const int* __restrict__ h_idx, const int* __restrict__ r_idx,
    const int* __restrict__ t_idx,
    const ushort* __restrict__ w1p, const float* __restrict__ w2,
    float* __restrict__ stack_base, int do_init) {
  __shared__ __align__(16) __hip_bfloat16 xt[64][136];
  __shared__ float a_s[64];
  __shared__ float w_s[64];
  __shared__ float part[4][64];

  const int b = blockIdx.x;
  const int tid = threadIdx.x;
  const int wave = tid >> 6, lane = tid & 63;
  const int m0 = __builtin_amdgcn_readfirstlane(wave) * 16;
  const int colq = lane & 15, quad = lane >> 4;
  const size_t L = (size_t)NB * ND;

  float hd[16], pd[16];

  for (int layer = 0; layer < 2; ++layer) {
    // ---- gather + stage xt ----
    if (layer == 0) {
      float macc = 0.f;
#pragma unroll
      for (int mi = 0; mi < 16; ++mi) {
        const int m = m0 + mi;
        hd[mi] = E[(size_t)h_idx[b * NM + m] * ND + lane];
        pd[mi] = R[(size_t)r_idx[b * NM + m] * ND + lane];
        macc += hd[mi];
        xt[m][lane] = __float2bfloat16(hd[mi]);
        xt[m][64 + lane] = __float2bfloat16(pd[mi]);
      }
      part[wave][lane] = macc;
      __syncthreads();
      if (do_init && wave == 0)
        stack_base[(size_t)b * ND + lane] =
            (part[0][lane] + part[1][lane] + part[2][lane] + part[3][lane]) * (1.f / 64.f);
    } else {
#pragma unroll
      for (int mi = 0; mi < 16; ++mi) {
        const int m = m0 + mi;
        hd[mi] += E[(size_t)h_idx[NBM + b * NM + m] * ND + lane];
        pd[mi] *= R[(size_t)r_idx[NBM + b * NM + m] * ND + lane];
        xt[m][lane] = __float2bfloat16(hd[mi]);
        xt[m][64 + lane] = __float2bfloat16(pd[mi]);
      }
      __syncthreads();
    }

    // ---- MFMA MLP ----
    {
      short8 afr[4];
#pragma unroll
      for (int kt = 0; kt < 4; ++kt)
        afr[kt] = *(const short8*)&xt[m0 + colq][kt * 32 + quad * 8];
      float w2v[4];
#pragma unroll
      for (int nt = 0; nt < 4; ++nt) w2v[nt] = w2[nt * 16 + colq];
      float cc[4][4];
#pragma unroll
      for (int nt = 0; nt < 4; ++nt) {
        float4v c = {0.f, 0.f, 0.f, 0.f};
#pragma unroll
        for (int kt = 0; kt < 4; ++kt) {
          short8 bfr = *(const short8*)&w1p[(((kt << 2) | nt) * 64 + lane) * 8];
          c = __builtin_amdgcn_mfma_f32_16x16x32_bf16(afr[kt], bfr, c, 0, 0, 0);
        }
#pragma unroll
        for (int i = 0; i < 4; ++i) cc[nt][i] = c[i];
      }
      float sred[4];
#pragma unroll
      for (int i = 0; i < 4; ++i)
        sred[i] = fmaxf(cc[0][i], 0.f) * w2v[0] + fmaxf(cc[1][i], 0.f) * w2v[1] +
                  fmaxf(cc[2][i], 0.f) * w2v[2] + fmaxf(cc[3][i], 0.f) * w2v[3];
#pragma unroll
      for (int o = 8; o > 0; o >>= 1) {
#pragma unroll
        for (int i = 0; i < 4; ++i) sred[i] += __shfl_xor(sred[i], o, 64);
      }
      if (colq == 0) {
#pragma unroll
        for (int i = 0; i < 4; ++i)
          a_s[m0 + quad * 4 + i] = 1.f / (1.f + __expf(-sred[i]));
      }
    }
    __syncthreads();
    if (wave == 0) {
      float v = a_s[lane];
      float mx = wmax(v);
      float e = __expf(v - mx);
      float ssum = wsum(e);
      w_s[lane] = e / ssum;
    }
    __syncthreads();

    // ---- weighted t-sum ----
    float o = 0.f;
#pragma unroll
    for (int mi = 0; mi < 16; ++mi) {
      const int m = m0 + mi;
      o = fmaf(w_s[m], E[(size_t)t_idx[(size_t)layer * NBM + b * NM + m] * ND + lane], o);
    }
    part[wave][lane] = o;
    __syncthreads();
    if (wave == 0)
      stack_base[(layer + 1) * L + (size_t)b * ND + lane] =
          part[0][lane] + part[1][lane] + part[2][lane] + part[3][lane];
  }
}

// ---------------- Hyperbolic attention agg, BOTH layers fused ----------------
constexpr int OFF_T2 = 0;
constexpr int OFF_P2 = 64 * 72;        // 4608
constexpr int OFF_H2 = 2 * 64 * 72;    // 9216
constexpr int XS = 152;                // xt stride
constexpr int OFF_HTS = 64 * XS;       // 9728
constexpr int REGA_SZ = OFF_HTS + 64 * 72;  // 14336 elems = 28672 B

__global__ __launch_bounds__(256) void hyper_agg2_kernel(
    const float* __restrict__ E, const float* __restrict__ R,
    const int* __restrict__ h_idx, const int* __restrict__ r_idx,
    const int* __restrict__ t_idx,
    const ushort* __restrict__ w1p, const float* __restrict__ b1,
    const float* __restrict__ w2, const float* __restrict__ b2,
    const float* __restrict__ curv, float* __restrict__ stack_base) {
  __shared__ __align__(16) ushort regA[REGA_SZ];
  __shared__ float dots_s[5][64];
  __shared__ float a_s[64];
  __shared__ float w_s[64];
  __shared__ float meanpt_s[64];
  __shared__ float part[4][64];
  __shared__ float scal;

  const int b = blockIdx.x;
  const int tid = threadIdx.x;
  const int wave = tid >> 6, lane = tid & 63;
  const int m0 = __builtin_amdgcn_readfirstlane(wave) * 16;
  const int colq = lane & 15, quad = lane >> 4;
  const float cabs = fabsf(*curv);
  const size_t L = (size_t)NB * ND;

  float hv[16], pv[16];

  for (int layer = 0; layer < 2; ++layer) {
    // ---- P0: gather + stage bf16 H/P/T ----
    if (layer == 0) {
      float macc = 0.f;
#pragma unroll
      for (int mi = 0; mi < 16; ++mi) {
        const int m = m0 + mi;
        hv[mi] = E[(size_t)h_idx[b * NM + m] * ND + lane];
        pv[mi] = R[(size_t)r_idx[b * NM + m] * ND + lane];
        float td = E[(size_t)t_idx[b * NM + m] * ND + lane];
        macc += hv[mi];
        regA[OFF_H2 + m * 72 + lane] = f2bf(hv[mi]);
        regA[OFF_P2 + m * 72 + lane] = f2bf(pv[mi]);
        regA[OFF_T2 + m * 72 + lane] = f2bf(td);
      }
      part[wave][lane] = macc;
      __syncthreads();
      if (wave == 0)
        stack_base[(size_t)b * ND + lane] =
            (part[0][lane] + part[1][lane] + part[2][lane] + part[3][lane]) * (1.f / 64.f);
    } else {
#pragma unroll
      for (int mi = 0; mi < 16; ++mi) {
        const int m = m0 + mi;
        hv[mi] += E[(size_t)h_idx[NBM + b * NM + m] * ND + lane];
        pv[mi] *= R[(size_t)r_idx[NBM + b * NM + m] * ND + lane];
        float td = E[(size_t)t_idx[(size_t)NBM + b * NM + m] * ND + lane];
        regA[OFF_H2 + m * 72 + lane] = f2bf(hv[mi]);
        regA[OFF_P2 + m * 72 + lane] = f2bf(pv[mi]);
        regA[OFF_T2 + m * 72 + lane] = f2bf(td);
      }
      __syncthreads();
    }

    // ---- P1: 5 dot families via MFMA diagonals ----
    {
      const int fr = m0 + colq;
      const ushort* pH = &regA[OFF_H2 + fr * 72 + quad * 8];
      const ushort* pP = &regA[OFF_P2 + fr * 72 + quad * 8];
      const ushort* pT = &regA[OFF_T2 + fr * 72 + quad * 8];
      short8 h0 = *(const short8*)pH, h1 = *(const short8*)(pH + 32);
      short8 p0 = *(const short8*)pP, p1 = *(const short8*)(pP + 32);
      short8 t0 = *(const short8*)pT, t1 = *(const short8*)(pT + 32);
      const bool dsel = (quad == (colq >> 2));
      const int dr = colq & 3;
#define DIAG_DOT(q, A0, A1, B0, B1)                                         \
      {                                                                      \
        float4v c = {0.f, 0.f, 0.f, 0.f};                                    \
        c = __builtin_amdgcn_mfma_f32_16x16x32_bf16(A0, B0, c, 0, 0, 0);     \
        c = __builtin_amdgcn_mfma_f32_16x16x32_bf16(A1, B1, c, 0, 0, 0);     \
        float dv = (dr & 2) ? ((dr & 1) ? c[3] : c[2])                       \
                            : ((dr & 1) ? c[1] : c[0]);                      \
        if (dsel) dots_s[q][m0 + colq] = dv;                                 \
      }
      DIAG_DOT(0, h0, h1, h0, h1)
      DIAG_DOT(1, p0, p1, p0, p1)
      DIAG_DOT(2, t0, t1, t0, t1)
      DIAG_DOT(3, h0, h1, t0, t1)
      DIAG_DOT(4, h0, h1, p0, p1)
#undef DIAG_DOT
    }
    __syncthreads();

    // ---- P2: geometry, lane-parallel (lane = m) ----
    float g_ch, g_e1, g_e2, g_gh, g_q1, g_q2, g_hts2;
    {
      const int mm = lane;
      float sh = dots_s[0][mm], sp = dots_s[1][mm], st = dots_s[2][mm];
      float sht = dots_s[3][mm], shp = dots_s[4][mm];
      float rih = rcpf(fmaxf(sqf(sh), 1e-12f));
      float rip = rcpf(fmaxf(sqf(sp), 1e-12f));
      float rit = rcpf(fmaxf(sqf(st), 1e-12f));
      float nh = sqf(fmaxf(sh * rih * rih, 1e-15f));
      float ch = fast_tanh(nh) * rcpf(nh) * rih * cabs;   // hh = ch*h_raw
      float p2 = ch * ch * sh;
      float lam = 2.f * rcpf(fmaxf(1.f - p2, 1e-15f));
      float ntn = sqf(fmaxf(st * rit * rit, 1e-15f));
      float ct = fast_tanh(0.5f * lam * ntn) * rcpf(ntn) * rit;
      float y2 = ct * ct * st, xy = ch * ct * sht;
      float At = 1.f + 2.f * xy + y2, Bt = 1.f - p2;
      float rdt = rcpf(fmaxf(1.f + 2.f * xy + p2 * y2, 1e-15f));
      g_e1 = At * ch * rdt;
      g_e2 = Bt * ct * rdt;
      g_hts2 = g_e1 * g_e1 * sh + 2.f * g_e1 * g_e2 * sht + g_e2 * g_e2 * st;
      float npn = sqf(fmaxf(sp * rip * rip, 1e-15f));
      float cp = fast_tanh(0.5f * lam * npn) * rcpf(npn) * rip;
      float z2 = cp * cp * sp, xz = ch * cp * shp;
      float Ar = 1.f + 2.f * xz + z2;
      float rdr = rcpf(fmaxf(1.f + 2.f * xz + p2 * z2, 1e-15f));
      float f1 = Ar * ch * rdr, f2 = Bt * cp * rdr;       // hr = f1*h + f2*p
      float hr2 = f1 * f1 * sh + 2.f * f1 * f2 * shp + f2 * f2 * sp;
      float n128 = sqf(fmaxf(p2 + hr2, 1e-15f));
      float fq = artanh_clip(n128) * rcpf(n128);
      g_ch = ch;
      g_gh = fq * ch;
      g_q1 = fq * f1;
      g_q2 = fq * f2;
    }

    // ---- P3a: re-read own-wave t rows (bf16) before xt overwrites ----
    ushort tr[16];
#pragma unroll
    for (int mi = 0; mi < 16; ++mi)
      tr[mi] = regA[OFF_T2 + (m0 + mi) * 72 + lane];
    __syncthreads();

    // ---- P3b: write tang rows (xt) + ht rows (Hts) ----
#pragma unroll
    for (int mi = 0; mi < 16; ++mi) {
      const int m = m0 + mi;
      float tvf = bf2f(tr[mi]);
      float ghm = readlane_f(g_gh, m);
      float q1m = readlane_f(g_q1, m);
      float q2m = readlane_f(g_q2, m);
      float e1m = readlane_f(g_e1, m);
      float e2m = readlane_f(g_e2, m);
      regA[m * XS + lane] = f2bf(ghm * hv[mi]);
      regA[m * XS + 64 + lane] = f2bf(q1m * hv[mi] + q2m * pv[mi]);
      regA[OFF_HTS + m * 72 + lane] = f2bf(e1m * hv[mi] + e2m * tvf);
    }
    __syncthreads();

    // ---- P4: MFMA attention MLP on xt ----
    {
      short8 afr[4];
#pragma unroll
      for (int kt = 0; kt < 4; ++kt)
        afr[kt] = *(const short8*)&regA[(m0 + colq) * XS + kt * 32 + quad * 8];
      float b1v[4], w2v[4];
#pragma unroll
      for (int nt = 0; nt < 4; ++nt) {
        b1v[nt] = b1[nt * 16 + colq];
        w2v[nt] = w2[nt * 16 + colq];
      }
      float cc[4][4];
#pragma unroll
      for (int nt = 0; nt < 4; ++nt) {
        float4v c = {0.f, 0.f, 0.f, 0.f};
#pragma unroll
        for (int kt = 0; kt < 4; ++kt) {
          short8 bfr = *(const short8*)&w1p[(((kt << 2) | nt) * 64 + lane) * 8];
          c = __builtin_amdgcn_mfma_f32_16x16x32_bf16(afr[kt], bfr, c, 0, 0, 0);
        }
#pragma unroll
        for (int i = 0; i < 4; ++i) cc[nt][i] = c[i];
      }
      float b2v = b2[0];
      float sred[4];
#pragma unroll
      for (int i = 0; i < 4; ++i)
        sred[i] = fmaxf(cc[0][i] + b1v[0], 0.f) * w2v[0] +
                  fmaxf(cc[1][i] + b1v[1], 0.f) * w2v[1] +
                  fmaxf(cc[2][i] + b1v[2], 0.f) * w2v[2] +
                  fmaxf(cc[3][i] + b1v[3], 0.f) * w2v[3];
#pragma unroll
      for (int o = 8; o > 0; o >>= 1) {
#pragma unroll
        for (int i = 0; i < 4; ++i) sred[i] += __shfl_xor(sred[i], o, 64);
      }
      if (colq == 0) {
#pragma unroll
        for (int i = 0; i < 4; ++i)
          a_s[m0 + quad * 4 + i] = fast_tanh(sred[i] + b2v);
      }
    }
    __syncthreads();
    if (wave == 0) {
      float v = a_s[lane];
      float mx = wmax(v);
      float e = __expf(v - mx);
      float ssum = wsum(e);
      w_s[lane] = e / ssum;
    }
    __syncthreads();

    // ---- P5: mean_pt = sum_m w[m]*ch[m]*h_raw[m] ----
    float mp = 0.f;
#pragma unroll
    for (int mi = 0; mi < 16; ++mi) {
      const int m = m0 + mi;
      mp = fmaf(w_s[m] * readlane_f(g_ch, m), hv[mi], mp);
    }
    part[wave][lane] = mp;
    __syncthreads();
    if (wave == 0) {
      float v = part[0][lane] + part[1][lane] + part[2][lane] + part[3][lane];
      meanpt_s[lane] = v;
      float p2m = wsum(v * v);
      if (lane == 0) scal = p2m;
    }
    __syncthreads();

    // ---- P6: dp[m] = meanpt . ht[m] via MFMA ----
    {
      const ushort* pA = &regA[OFF_HTS + (m0 + colq) * 72 + quad * 8];
      short8 a0 = *(const short8*)pA, a1 = *(const short8*)(pA + 32);
      short8 bm0, bm1;
#pragma unroll
      for (int j = 0; j < 8; ++j) {
        bm0[j] = (short)f2bf(meanpt_s[quad * 8 + j]);
        bm1[j] = (short)f2bf(meanpt_s[32 + quad * 8 + j]);
      }
      float4v c = {0.f, 0.f, 0.f, 0.f};
      c = __builtin_amdgcn_mfma_f32_16x16x32_bf16(a0, bm0, c, 0, 0, 0);
      c = __builtin_amdgcn_mfma_f32_16x16x32_bf16(a1, bm1, c, 0, 0, 0);
      if (colq == 0) {
#pragma unroll
        for (int i = 0; i < 4; ++i) a_s[m0 + quad * 4 + i] = c[i];
      }
    }
    __syncthreads();

    // ---- P7: logmap scalars lane-parallel, per-wave accumulation ----
    const float p2m = scal;
    const float be = fmaxf(1.f - p2m, 1e-15f);
    float g1, g2;
    {
      const int mm = lane;
      float dpm = a_s[mm];
      float wm = w_s[mm];
      float y2 = wm * wm * g_hts2;
      float xy = -wm * dpm;
      float al = 1.f + 2.f * xy + y2;
      float rd = rcpf(fmaxf(1.f + 2.f * xy + p2m * y2, 1e-15f));
      float md2 = (al * al * p2m - 2.f * al * be * wm * dpm + be * be * y2) * rd * rd;
      float n = sqf(fmaxf(md2, 1e-15f));
      float sm = be * artanh_clip(n) * rcpf(n) * rd;
      g1 = wm * wm * sm * be;
      g2 = wm * sm * al;
    }
    float ovec = 0.f, cA = 0.f;
#pragma unroll
    for (int mi = 0; mi < 16; ++mi) {
      const int m = m0 + mi;
      float htf = bf2f(regA[OFF_HTS + m * 72 + lane]);
      ovec = fmaf(readlane_f(g1, m), htf, ovec);
      cA += readlane_f(g2, m);
    }
    part[wave][lane] = ovec - cA * meanpt_s[lane];
    __syncthreads();
    if (wave == 0)
      stack_base[(layer + 1) * L + (size_t)b * ND + lane] =
          part[0][lane] + part[1][lane] + part[2][lane] + part[3][lane];
  }
}

// ---------------- fused l2-normalize->bf16 + positive-pair dots ----------------
// blockIdx.y = pair sa in {0,1}: handles stacks sa and sa+2
__global__ __launch_bounds__(256) void l2pos_kernel(
    const float* __restrict__ stacks, __hip_bfloat16* __restrict__ nbf,
    float* __restrict__ pos) {
  int row = blockIdx.x * 4 + (threadIdx.x >> 6);
  int lane = threadIdx.x & 63;
  int sa = blockIdx.y, sb = sa + 2;
  size_t offa = (size_t)sa * STACK + (size_t)row * ND + lane;
  size_t offb = (size_t)sb * STACK + (size_t)row * ND + lane;
  float a = stacks[offa];
  float c = stacks[offb];
  float q0 = a * a, q1 = c * c, q2 = a * c;
#pragma unroll
  for (int o = 32; o > 0; o >>= 1) {
    q0 += __shfl_xor(q0, o, 64);
    q1 += __shfl_xor(q1, o, 64);
    q2 += __shfl_xor(q2, o, 64);
  }
  float ra = rcpf(fmaxf(sqf(q0), 1e-12f));
  float rc = rcpf(fmaxf(sqf(q1), 1e-12f));
  nbf[offa] = __float2bfloat16(a * ra);
  nbf[offb] = __float2bfloat16(c * rc);
  if (lane == 0) pos[sa * NROWS + row] = q2 * ra * rc;
}

// ---------------- contrastive denominators via MFMA, LDS-staged Y ----------------
__global__ __launch_bounds__(256) void lse_mfma_kernel(
    const ushort* __restrict__ nbf, float* __restrict__ Spart) {
  __shared__ __align__(16) ushort ytile[2][64 * 72];   // 36 KB
  const int tid = threadIdx.x;
  const int wave = tid >> 6, lane = tid & 63;
  const int pair = blockIdx.y;
  const int z = blockIdx.z;
  int xi = (pair & 2) ? ((pair & 1) ? 3 : 1) : ((pair & 1) ? 2 : 0);
  int yi = xi ^ 2;
  const ushort* X = nbf + (size_t)xi * STACK;
  const ushort* Y = nbf + (size_t)yi * STACK;
  const int r0 = blockIdx.x * 64 + wave * 16;
  const int row = lane & 15, quad = lane >> 4;

  short8 a0 = *(const short8*)&X[(size_t)(r0 + row) * 64 + quad * 8];
  short8 a1 = *(const short8*)&X[(size_t)(r0 + row) * 64 + 32 + quad * 8];

  const int srow = tid >> 2, schunk = tid & 3;
  constexpr int NT = (NROWS / NZ) / 64;   // 12 tiles
  const int c0 = z * (NROWS / NZ);
  const ushort* sg = &Y[(size_t)(c0 + srow) * 64 + schunk * 16];
  ushort* sl = &ytile[0][0] + srow * 72 + schunk * 16;

  {
    short8 s0 = *(const short8*)sg;
    short8 s1 = *(const short8*)(sg + 8);
    *(short8*)sl = s0;
    *(short8*)(sl + 8) = s1;
  }
  __syncthreads();

  float rsum[4] = {0.f, 0.f, 0.f, 0.f};
  for (int ct = 0; ct < NT; ++ct) {
    const int cur = ct & 1;
    short8 n0, n1;
    if (ct + 1 < NT) {
      const ushort* src = sg + (size_t)(ct + 1) * 64 * 64;
      n0 = *(const short8*)src;
      n1 = *(const short8*)(src + 8);
    }
#pragma unroll
    for (int nt = 0; nt < 4; ++nt) {
      const ushort* yr = &ytile[cur][(nt * 16 + row) * 72 + quad * 8];
      short8 b0 = *(const short8*)yr;
      short8 b1 = *(const short8*)(yr + 32);
      float4v c = {0.f, 0.f, 0.f, 0.f};
      c = __builtin_amdgcn_mfma_f32_16x16x32_bf16(a0, b0, c, 0, 0, 0);
      c = __builtin_amdgcn_mfma_f32_16x16x32_bf16(a1, b1, c, 0, 0, 0);
#pragma unroll
      for (int i = 0; i < 4; ++i) rsum[i] += __expf(c[i] * 5.f);
    }
    if (ct + 1 < NT) {
      ushort* dst = &ytile[0][0] + ((ct + 1) & 1) * (64 * 72) + srow * 72 + schunk * 16;
      *(short8*)dst = n0;
      *(short8*)(dst + 8) = n1;
      __syncthreads();
    }
  }
#pragma unroll
  for (int i = 0; i < 4; ++i) {
    float v = rsum[i];
    v += __shfl_xor(v, 1, 64);
    v += __shfl_xor(v, 2, 64);
    v += __shfl_xor(v, 4, 64);
    v += __shfl_xor(v, 8, 64);
    if (row == 0)
      Spart[((size_t)z * 4 + pair) * NROWS + r0 + quad * 4 + i] = v;
  }
}

// ---------------- scores ----------------
__global__ __launch_bounds__(256) void scores_kernel(
    const float* __restrict__ stacks, float* __restrict__ out) {
  int b = blockIdx.x * 4 + (threadIdx.x >> 6);
  int lane = threadIdx.x & 63;
  float s = 0.f;
#pragma unroll
  for (int l = 0; l < 3; ++l) {
    size_t o = (size_t)l * NB * ND + (size_t)b * ND + lane;
    s += stacks[0 * (size_t)STACK + o] * stacks[3 * (size_t)STACK + o]
       + stacks[2 * (size_t)STACK + o] * stacks[1 * (size_t)STACK + o];
  }
  s = wsum(s);
  if (lane == 0) out[b] = 1.f / (1.f + __expf(-s));
}

// ---------------- loss: grid-parallel partials + final reduce ----------------
__global__ __launch_bounds__(256) void loss_part_kernel(
    const float* __restrict__ Spart, const float* __restrict__ pos,
    double* __restrict__ lossp) {
  __shared__ double red[256];
  const int t = threadIdx.x, blk = blockIdx.x;
  double acc = 0.0;
#pragma unroll
  for (int r = 0; r < 2; ++r) {
    int i = blk * 512 + r * 256 + t;   // i in [0, 4*NROWS)
    float s = 0.f;
#pragma unroll
    for (int zz = 0; zz < NZ; ++zz) s += Spart[i + zz * 4 * NROWS];
    acc += (double)__logf(s);
  }
  {
    int j = blk * 256 + t;             // j in [0, 2*NROWS)
    acc -= 10.0 * (double)pos[j];
  }
  red[t] = acc;
  __syncthreads();
  for (int s = 128; s > 0; s >>= 1) {
    if (t < s) red[t] += red[t + s];
    __syncthreads();
  }
  if (t == 0) lossp[blk] = red[0];
}

__global__ __launch_bounds__(64) void loss_final_kernel(
    const double* __restrict__ lossp, float* __restrict__ out) {
  int lane = threadIdx.x;
  double v = (lane < 48) ? lossp[lane] : 0.0;
#pragma unroll
  for (int o = 32; o > 0; o >>= 1) v += __shfl_xor(v, o, 64);
  if (lane == 0) out[NB] = (float)(1e-6 * v);
}

extern "C" void kernel_launch(void* const* d_in, const int* in_sizes, int n_in,
                              void* d_out, int out_size, void* d_ws, size_t ws_size,
                              hipStream_t stream) {
  const int* items = (const int*)d_in[0];
  const int* ucf_h = (const int*)d_in[1];
  const int* ucf_r = (const int*)d_in[2];
  const int* ucf_t = (const int*)d_in[3];
  const int* ikg_h = (const int*)d_in[4];
  const int* ikg_r = (const int*)d_in[5];
  const int* ikg_t = (const int*)d_in[6];
  const int* ukg_h = (const int*)d_in[7];
  const int* ukg_r = (const int*)d_in[8];
  const int* ukg_t = (const int*)d_in[9];
  const int* icf_h = (const int*)d_in[10];
  const int* icf_r = (const int*)d_in[11];
  const int* icf_t = (const int*)d_in[12];
  const float* E = (const float*)d_in[13];
  const float* R = (const float*)d_in[14];
  const float* att_w1 = (const float*)d_in[15];
  const float* att_w2 = (const float*)d_in[16];
  const float* a2_w1 = (const float*)d_in[17];
  const float* a2_b1 = (const float*)d_in[18];
  const float* a2_w2 = (const float*)d_in[19];
  const float* a2_b2 = (const float*)d_in[20];
  const float* curv = (const float*)d_in[21];
  float* outp = (float*)d_out;

  float* ws = (float*)d_ws;
  float* stacks = ws;                                    // 4*STACK f32
  float* Spart = stacks + 4 * (size_t)STACK;             // NZ*4*NROWS f32
  float* posarr = Spart + (size_t)NZ * 4 * NROWS;        // 2*NROWS f32
  __hip_bfloat16* nbf = (__hip_bfloat16*)(posarr + 2 * (size_t)NROWS);  // 4*STACK bf16
  ushort* w1p_ed = (ushort*)(nbf + 4 * (size_t)STACK);   // 8192 ushort
  ushort* w1p_hy = w1p_ed + 8192;                        // 8192 ushort
  double* lossp = (double*)(w1p_hy + 8192);              // 48 doubles

  float* ucf = stacks + 0 * (size_t)STACK;
  float* ikg = stacks + 1 * (size_t)STACK;
  float* ukg = stacks + 2 * (size_t)STACK;
  float* icf = stacks + 3 * (size_t)STACK;

  pack_w1_kernel<<<32, 256, 0, stream>>>(att_w1, w1p_ed);
  pack_w1_kernel<<<32, 256, 0, stream>>>(a2_w1, w1p_hy);

  init_item_kernel<<<NB, 64, 0, stream>>>(E, items, ikg);

  ed_agg2_kernel<<<NB, 256, 0, stream>>>(E, R, ucf_h, ucf_r, ucf_t, w1p_ed, att_w2, ucf, 1);
  ed_agg2_kernel<<<NB, 256, 0, stream>>>(E, R, ikg_h, ikg_r, ikg_t, w1p_ed, att_w2, ikg, 0);
  hyper_agg2_kernel<<<NB, 256, 0, stream>>>(E, R, ukg_h, ukg_r, ukg_t, w1p_hy, a2_b1, a2_w2, a2_b2, curv, ukg);
  hyper_agg2_kernel<<<NB, 256, 0, stream>>>(E, R, icf_h, icf_r, icf_t, w1p_hy, a2_b1, a2_w2, a2_b2, curv, icf);

  l2pos_kernel<<<dim3(NROWS / 4, 2), 256, 0, stream>>>(stacks, nbf, posarr);
  lse_mfma_kernel<<<dim3(NROWS / 64, 4, NZ), 256, 0, stream>>>((const ushort*)nbf, Spart);

  scores_kernel<<<NB / 4, 256, 0, stream>>>(stacks, outp);
  loss_part_kernel<<<48, 256, 0, stream>>>(Spart, posarr, lossp);
  loss_final_kernel<<<1, 64, 0, stream>>>(lossp, outp);
}